// Round 1
// baseline (1709.285 us; speedup 1.0000x reference)
//
#include <hip/hip_runtime.h>
#include <math.h>

#define NN 50000
#define NE 800000

// ---------- wave helpers (wave64) ----------
static __device__ __forceinline__ float wave_max64(float v){
  #pragma unroll
  for(int off=32;off;off>>=1) v = fmaxf(v, __shfl_xor(v,off));
  return v;
}
static __device__ __forceinline__ float wave_sum64(float v){
  #pragma unroll
  for(int off=32;off;off>>=1) v += __shfl_xor(v,off);
  return v;
}

// ---------- CSR build ----------
__global__ void k_degsum(const int* __restrict__ dst, const float* __restrict__ eattr,
                         int* __restrict__ degi, float* __restrict__ esum, int E){
  int e = blockIdx.x*blockDim.x + threadIdx.x;
  if (e < E){
    int d = dst[e];
    atomicAdd(&degi[d], 1);
    atomicAdd(&esum[d], eattr[e]);
  }
}

// exclusive scan of (deg[i]+1) -> row_ptr[0..n], single workgroup of 1024
__global__ void k_scan(const int* __restrict__ degi, int* __restrict__ row_ptr, int n){
  __shared__ int lds[1024];
  __shared__ int carry;
  int tid = threadIdx.x;
  if (tid==0) carry = 0;
  __syncthreads();
  for (int base=0; base<n; base+=1024){
    int i = base+tid;
    int cnt = (i<n) ? (degi[i]+1) : 0;
    lds[tid] = cnt;
    __syncthreads();
    #pragma unroll
    for (int off=1; off<1024; off<<=1){
      int v = (tid>=off) ? lds[tid-off] : 0;
      __syncthreads();
      lds[tid] += v;
      __syncthreads();
    }
    if (i<n) row_ptr[i] = carry + lds[tid] - cnt;
    int tot = lds[1023];
    __syncthreads();
    if (tid==0) carry += tot;
    __syncthreads();
  }
  if (tid==0) row_ptr[n] = carry;
}

// reserve slot row_ptr[i] for the self loop; loop_attr = esum/max(deg,1)
__global__ void k_selfinit(const int* __restrict__ degi, const float* __restrict__ esum,
                           const int* __restrict__ row_ptr, int* __restrict__ cursor,
                           int* __restrict__ srt_src, float* __restrict__ srt_ea, int n){
  int i = blockIdx.x*blockDim.x + threadIdx.x;
  if (i < n){
    int rp = row_ptr[i];
    cursor[i] = rp + 1;
    srt_src[rp] = i;
    srt_ea[rp] = esum[i] / fmaxf((float)degi[i], 1.0f);
  }
}

__global__ void k_scatter(const int* __restrict__ src, const int* __restrict__ dst,
                          const float* __restrict__ eattr, int* __restrict__ cursor,
                          int* __restrict__ srt_src, float* __restrict__ srt_ea, int E){
  int e = blockIdx.x*blockDim.x + threadIdx.x;
  if (e < E){
    int d = dst[e];
    int pos = atomicAdd(&cursor[d], 1);
    srt_src[pos] = src[e];
    srt_ea[pos] = eattr[e];
  }
}

// ---------- per-layer kernels ----------
// ce = dot(We[0,:], a_e)
__global__ void k_ce(const float* __restrict__ We, const float* __restrict__ ae,
                     float* __restrict__ ce, int fout){
  int l = threadIdx.x;
  float s = 0.f;
  for (int c=l; c<fout; c+=64) s += We[c]*ae[c];
  s = wave_sum64(s);
  if (l==0) *ce = s;
}

// h = x @ W ; W staged in LDS (dynamic size fin*fout*4)
__global__ __launch_bounds__(256) void k_matmul(const float* __restrict__ x,
    const float* __restrict__ W, float* __restrict__ h, int n, int fin, int fout){
  extern __shared__ float Wl[];
  int tid = threadIdx.x;
  for (int i=tid; i<fin*fout; i+=256) Wl[i] = W[i];
  __syncthreads();
  const int ROWS = 64;
  int r0 = blockIdx.x * ROWS;
  int col  = tid % fout;
  int rsub = tid / fout;
  int rstep = 256 / fout;
  int rend = r0 + ROWS; if (rend > n) rend = n;
  for (int r = r0 + rsub; r < rend; r += rstep){
    const float* xr = x + (size_t)r*fin;
    float s = 0.f;
    for (int k=0; k<fin; k++) s += xr[k]*Wl[k*fout+col];
    h[(size_t)r*fout+col] = s;
  }
}

// hs[i] = h[i]·a_src ; hd[i] = h[i]·a_dst  (one wave per node)
__global__ __launch_bounds__(256) void k_hsd(const float* __restrict__ h,
    const float* __restrict__ asrc, const float* __restrict__ adst,
    float* __restrict__ hs, float* __restrict__ hd, int n, int fout){
  int wid  = (int)((blockIdx.x*256 + threadIdx.x) >> 6);
  int lane = threadIdx.x & 63;
  if (wid >= n) return;
  const float* hr = h + (size_t)wid*fout;
  float s = 0.f, d = 0.f;
  for (int c=lane; c<fout; c+=64){ float v = hr[c]; s += v*asrc[c]; d += v*adst[c]; }
  s = wave_sum64(s); d = wave_sum64(d);
  if (lane==0){ hs[wid] = s; hd[wid] = d; }
}

// Per-node fused: alpha -> online softmax -> weighted gather of h[src] -> +b -> ELU
template<int FOUT>
__global__ __launch_bounds__(256) void k_aggregate(const float* __restrict__ h,
    const float* __restrict__ hs, const float* __restrict__ hd,
    const int* __restrict__ srt_src, const float* __restrict__ srt_ea,
    const int* __restrict__ row_ptr, const float* __restrict__ ce_p,
    const float* __restrict__ b, float* __restrict__ xout, int n){
  int wid  = (int)((blockIdx.x*256 + threadIdx.x) >> 6);
  int lane = threadIdx.x & 63;
  if (wid >= n) return;
  float ce  = *ce_p;
  int beg = row_ptr[wid], end = row_ptr[wid+1];
  float hdn = hd[wid];
  float m = -INFINITY, den = 0.f, acc0 = 0.f, acc1 = 0.f;
  for (int base = beg; base < end; base += 64){
    int slot = base + lane;
    float a = -INFINITY; int src = 0;
    if (slot < end){
      src = srt_src[slot];
      a = hs[src] + hdn + srt_ea[slot]*ce;
      a = (a > 0.f) ? a : 0.2f*a;                 // leaky_relu(0.2)
    }
    float cm = wave_max64(a);
    float mnew = fmaxf(m, cm);
    float scale = expf(m - mnew);                 // m==-inf -> 0
    den *= scale; acc0 *= scale; acc1 *= scale;
    float p = expf(a - mnew);                     // invalid lanes -> 0
    den += wave_sum64(p);
    int cnt = end - base; if (cnt > 64) cnt = 64;
    for (int j=0; j<cnt; j++){
      float pj = __shfl(p, j);
      int   sj = __shfl(src, j);
      const float* hr = h + (size_t)sj*FOUT;
      acc0 += pj * hr[lane];
      if (FOUT == 128) acc1 += pj * hr[lane+64];
    }
    m = mnew;
  }
  float inv = 1.f/den;
  {
    float o = acc0*inv + b[lane];
    o = (o > 0.f) ? o : (expf(o) - 1.f);          // ELU
    xout[(size_t)wid*FOUT + lane] = o;
  }
  if (FOUT == 128){
    float o = acc1*inv + b[lane+64];
    o = (o > 0.f) ? o : (expf(o) - 1.f);
    xout[(size_t)wid*FOUT + lane + 64] = o;
  }
}

// column sums of x[n,64] -> gsum[64] (mean done in head)
__global__ void k_colsum(const float* __restrict__ x, float* __restrict__ gsum, int n){
  int lane = threadIdx.x;   // blockDim = 64
  float s = 0.f;
  for (int r = blockIdx.x; r < n; r += gridDim.x) s += x[(size_t)r*64 + lane];
  atomicAdd(&gsum[lane], s);
}

// final MLP head, single block of 128 threads
__global__ void k_head(const float* __restrict__ gs1, const float* __restrict__ gs2,
                       const float* __restrict__ xn1, const float* __restrict__ xn2,
                       const float* __restrict__ Wlin, const float* __restrict__ blin,
                       const float* __restrict__ Wc1, const float* __restrict__ bc1,
                       const float* __restrict__ Wc2, const float* __restrict__ bc2,
                       float* __restrict__ out){
  __shared__ float c1[80], c2[80], xcat[128], hb[16];
  int tid = threadIdx.x;
  const float invn = 1.f/(float)NN;
  if (tid < 64){ c1[tid] = gs1[tid]*invn; c2[tid] = gs2[tid]*invn; }
  else if (tid < 80){ c1[tid] = xn1[tid-64]; c2[tid] = xn2[tid-64]; }
  __syncthreads();
  if (tid < 64){
    float s = blin[tid];
    for (int k=0;k<80;k++) s += c1[k]*Wlin[k*64+tid];
    xcat[tid] = s;
  } else {
    int j = tid - 64;
    float s = blin[j];
    for (int k=0;k<80;k++) s += c2[k]*Wlin[k*64+j];
    xcat[tid] = s;
  }
  __syncthreads();
  if (tid < 16){
    float s = bc1[tid];
    for (int k=0;k<128;k++) s += xcat[k]*Wc1[k*16+tid];
    hb[tid] = fmaxf(s, 0.f);
  }
  __syncthreads();
  if (tid < 3){
    float s = bc2[tid];
    for (int k=0;k<16;k++) s += hb[k]*Wc2[k*3+tid];
    out[tid] = s;
  }
}

extern "C" void kernel_launch(void* const* d_in, const int* in_sizes, int n_in,
                              void* d_out, int out_size, void* d_ws, size_t ws_size,
                              hipStream_t stream){
  const float* x1  = (const float*)d_in[0];
  const float* x2  = (const float*)d_in[1];
  const int*   ei1 = (const int*)d_in[2];
  const int*   ei2 = (const int*)d_in[3];
  const float* xn1 = (const float*)d_in[4];
  const float* xn2 = (const float*)d_in[5];
  const float* ec1 = (const float*)d_in[6];
  const float* ec2 = (const float*)d_in[7];
  const float* W[3]    = {(const float*)d_in[8],  (const float*)d_in[14], (const float*)d_in[20]};
  const float* asrc[3] = {(const float*)d_in[9],  (const float*)d_in[15], (const float*)d_in[21]};
  const float* adst[3] = {(const float*)d_in[10], (const float*)d_in[16], (const float*)d_in[22]};
  const float* We[3]   = {(const float*)d_in[11], (const float*)d_in[17], (const float*)d_in[23]};
  const float* ae[3]   = {(const float*)d_in[12], (const float*)d_in[18], (const float*)d_in[24]};
  const float* bb[3]   = {(const float*)d_in[13], (const float*)d_in[19], (const float*)d_in[25]};
  const float* Wlin = (const float*)d_in[26];
  const float* blin = (const float*)d_in[27];
  const float* Wc1  = (const float*)d_in[28];
  const float* bc1  = (const float*)d_in[29];
  const float* Wc2  = (const float*)d_in[30];
  const float* bc2  = (const float*)d_in[31];
  float* out = (float*)d_out;

  // workspace partition (floats)
  float* ws   = (float*)d_ws;
  float* bufX = ws;                         // 50000*128
  float* bufH = bufX + (size_t)NN*128;      // 50000*128
  float* hs   = bufH + (size_t)NN*128;      // NN
  float* hd   = hs + NN;                    // NN
  float* esum = hd + NN;                    // NN
  int*   degi = (int*)(esum + NN);          // NN
  int*   row_ptr = degi + NN;               // NN+1
  int*   cursor  = row_ptr + NN + 1;        // NN
  int*   srt_src = cursor + NN;             // NE+NN
  float* srt_ea  = (float*)(srt_src + NE + NN); // NE+NN
  float* ce   = srt_ea + NE + NN;           // 1
  float* gsum = ce + 1;                     // 128 (2 x 64)

  hipMemsetAsync(gsum, 0, 128*sizeof(float), stream);

  const int fin_arr[3]  = {7, 128, 128};
  const int fout_arr[3] = {128, 128, 64};

  for (int g = 0; g < 2; ++g){
    const int* ei = g ? ei2 : ei1;
    const float* ecol = g ? ec2 : ec1;
    const float* x0 = g ? x2 : x1;
    const int* srcp = ei;
    const int* dstp = ei + NE;

    // CSR build (dst-sorted, self-loop slot first in each segment)
    hipMemsetAsync(degi, 0, NN*sizeof(int), stream);
    hipMemsetAsync(esum, 0, NN*sizeof(float), stream);
    k_degsum<<<(NE+255)/256, 256, 0, stream>>>(dstp, ecol, degi, esum, NE);
    k_scan<<<1, 1024, 0, stream>>>(degi, row_ptr, NN);
    k_selfinit<<<(NN+255)/256, 256, 0, stream>>>(degi, esum, row_ptr, cursor, srt_src, srt_ea, NN);
    k_scatter<<<(NE+255)/256, 256, 0, stream>>>(srcp, dstp, ecol, cursor, srt_src, srt_ea, NE);

    for (int L = 0; L < 3; ++L){
      int fin = fin_arr[L], fout = fout_arr[L];
      const float* xin = (L == 0) ? x0 : bufX;
      k_ce<<<1, 64, 0, stream>>>(We[L], ae[L], ce, fout);
      k_matmul<<<(NN+63)/64, 256, fin*fout*4, stream>>>(xin, W[L], bufH, NN, fin, fout);
      k_hsd<<<(NN+3)/4, 256, 0, stream>>>(bufH, asrc[L], adst[L], hs, hd, NN, fout);
      if (fout == 128)
        k_aggregate<128><<<(NN+3)/4, 256, 0, stream>>>(bufH, hs, hd, srt_src, srt_ea, row_ptr, ce, bb[L], bufX, NN);
      else
        k_aggregate<64><<<(NN+3)/4, 256, 0, stream>>>(bufH, hs, hd, srt_src, srt_ea, row_ptr, ce, bb[L], bufX, NN);
    }
    k_colsum<<<256, 64, 0, stream>>>(bufX, gsum + g*64, NN);
  }

  k_head<<<1, 128, 0, stream>>>(gsum, gsum+64, xn1, xn2, Wlin, blin, Wc1, bc1, Wc2, bc2, out);
}

// Round 2
// 1267.930 us; speedup vs baseline: 1.3481x; 1.3481x over previous
//
#include <hip/hip_runtime.h>
#include <math.h>

#define NN 50000
#define NE 800000

// ---------- wave helpers (wave64) ----------
static __device__ __forceinline__ float wave_max64(float v){
  #pragma unroll
  for(int off=32;off;off>>=1) v = fmaxf(v, __shfl_xor(v,off));
  return v;
}
static __device__ __forceinline__ float wave_sum64(float v){
  #pragma unroll
  for(int off=32;off;off>>=1) v += __shfl_xor(v,off);
  return v;
}

// ---------- CSR build ----------
__global__ void k_degsum(const int* __restrict__ dst, const float* __restrict__ eattr,
                         int* __restrict__ degi, float* __restrict__ esum, int E){
  int e = blockIdx.x*blockDim.x + threadIdx.x;
  if (e < E){
    int d = dst[e];
    atomicAdd(&degi[d], 1);
    atomicAdd(&esum[d], eattr[e]);
  }
}

// exclusive scan of (deg[i]+1) -> row_ptr[0..n], single workgroup of 1024
__global__ void k_scan(const int* __restrict__ degi, int* __restrict__ row_ptr, int n){
  __shared__ int lds[1024];
  __shared__ int carry;
  int tid = threadIdx.x;
  if (tid==0) carry = 0;
  __syncthreads();
  for (int base=0; base<n; base+=1024){
    int i = base+tid;
    int cnt = (i<n) ? (degi[i]+1) : 0;
    lds[tid] = cnt;
    __syncthreads();
    #pragma unroll
    for (int off=1; off<1024; off<<=1){
      int v = (tid>=off) ? lds[tid-off] : 0;
      __syncthreads();
      lds[tid] += v;
      __syncthreads();
    }
    if (i<n) row_ptr[i] = carry + lds[tid] - cnt;
    int tot = lds[1023];
    __syncthreads();
    if (tid==0) carry += tot;
    __syncthreads();
  }
  if (tid==0) row_ptr[n] = carry;
}

// reserve slot row_ptr[i] for the self loop; loop_attr = esum/max(deg,1)
__global__ void k_selfinit(const int* __restrict__ degi, const float* __restrict__ esum,
                           const int* __restrict__ row_ptr, int* __restrict__ cursor,
                           int* __restrict__ srt_src, float* __restrict__ srt_ea, int n){
  int i = blockIdx.x*blockDim.x + threadIdx.x;
  if (i < n){
    int rp = row_ptr[i];
    cursor[i] = rp + 1;
    srt_src[rp] = i;
    srt_ea[rp] = esum[i] / fmaxf((float)degi[i], 1.0f);
  }
}

__global__ void k_scatter(const int* __restrict__ src, const int* __restrict__ dst,
                          const float* __restrict__ eattr, int* __restrict__ cursor,
                          int* __restrict__ srt_src, float* __restrict__ srt_ea, int E){
  int e = blockIdx.x*blockDim.x + threadIdx.x;
  if (e < E){
    int d = dst[e];
    int pos = atomicAdd(&cursor[d], 1);
    srt_src[pos] = src[e];
    srt_ea[pos] = eattr[e];
  }
}

// ---------- per-layer kernels ----------
// ce = dot(We[0,:], a_e)
__global__ void k_ce(const float* __restrict__ We, const float* __restrict__ ae,
                     float* __restrict__ ce, int fout){
  int l = threadIdx.x;
  float s = 0.f;
  for (int c=l; c<fout; c+=64) s += We[c]*ae[c];
  s = wave_sum64(s);
  if (l==0) *ce = s;
}

// ---- register-tiled GEMM: h[M,N] = x[M,K] @ W[K,N], K % 32 == 0 ----
// block tile: 64 rows x N cols, 256 threads
template<int K, int N>
__global__ __launch_bounds__(256) void k_gemm(const float* __restrict__ x,
    const float* __restrict__ W, float* __restrict__ h, int n){
  constexpr int KB  = 32;
  constexpr int CG  = N/4;        // col groups of 4
  constexpr int TY  = 256/CG;     // row groups
  constexpr int RPT = 64/TY;      // rows per thread (8 for N=128, 4 for N=64)
  __shared__ float Wl[KB][N];
  __shared__ float Xt[KB][64];    // transposed x chunk
  int tid = threadIdx.x;
  int tx = tid % CG, ty = tid / CG;
  int r0 = blockIdx.x * 64;
  float acc[RPT][4] = {};
  for (int k0 = 0; k0 < K; k0 += KB){
    // stage W chunk (rows k0..k0+31 are contiguous in global): coalesced float4
    {
      const float4* src = (const float4*)(W + (size_t)k0*N);
      float4* dst = (float4*)(&Wl[0][0]);
      #pragma unroll
      for (int i = 0; i < KB*N/1024; ++i) dst[tid + i*256] = src[tid + i*256];
    }
    // stage x chunk transposed: Xt[kk][r] = x[r0+r][k0+kk]
    {
      int rr = tid >> 3, kk0 = (tid & 7) * 4;
      #pragma unroll
      for (int it = 0; it < 2; ++it){
        int r = rr + it*32;
        int gr = r0 + r;
        float4 v = (gr < n) ? *(const float4*)(x + (size_t)gr*K + k0 + kk0)
                            : make_float4(0.f,0.f,0.f,0.f);
        Xt[kk0+0][r] = v.x; Xt[kk0+1][r] = v.y; Xt[kk0+2][r] = v.z; Xt[kk0+3][r] = v.w;
      }
    }
    __syncthreads();
    #pragma unroll
    for (int kk = 0; kk < KB; ++kk){
      float4 wv = *(const float4*)(&Wl[kk][tx*4]);
      float xv[RPT];
      #pragma unroll
      for (int i = 0; i < RPT/4; ++i)
        *(float4*)&xv[i*4] = *(const float4*)(&Xt[kk][ty*RPT + i*4]);
      #pragma unroll
      for (int i=0;i<RPT;i++){
        acc[i][0] += xv[i]*wv.x; acc[i][1] += xv[i]*wv.y;
        acc[i][2] += xv[i]*wv.z; acc[i][3] += xv[i]*wv.w;
      }
    }
    __syncthreads();
  }
  #pragma unroll
  for (int i=0;i<RPT;i++){
    int gr = r0 + ty*RPT + i;
    if (gr < n) *(float4*)(h + (size_t)gr*N + tx*4) = *(float4*)&acc[i][0];
  }
}

// layer-1 GEMM: K=7, N=128. 8 rows per block.
__global__ __launch_bounds__(256) void k_gemm7(const float* __restrict__ x,
    const float* __restrict__ W, float* __restrict__ h, int n){
  __shared__ float Wl[7][128];
  int tid = threadIdx.x;
  for (int i = tid; i < 7*128; i += 256) ((float*)Wl)[i] = W[i];
  __syncthreads();
  int tx = tid & 31, ty = tid >> 5;
  int r = blockIdx.x*8 + ty;
  if (r >= n) return;
  const float* xr = x + (size_t)r*7;
  float xv[7];
  #pragma unroll
  for (int k=0;k<7;k++) xv[k] = xr[k];
  float4 s = make_float4(0.f,0.f,0.f,0.f);
  #pragma unroll
  for (int k=0;k<7;k++){
    float4 wv = *(const float4*)(&Wl[k][tx*4]);
    s.x += xv[k]*wv.x; s.y += xv[k]*wv.y; s.z += xv[k]*wv.z; s.w += xv[k]*wv.w;
  }
  *(float4*)(h + (size_t)r*128 + tx*4) = s;
}

// hs[i] = h[i]·a_src ; hd[i] = h[i]·a_dst  (one wave per node)
__global__ __launch_bounds__(256) void k_hsd(const float* __restrict__ h,
    const float* __restrict__ asrc, const float* __restrict__ adst,
    float* __restrict__ hs, float* __restrict__ hd, int n, int fout){
  int wid  = (int)((blockIdx.x*256 + threadIdx.x) >> 6);
  int lane = threadIdx.x & 63;
  if (wid >= n) return;
  const float* hr = h + (size_t)wid*fout;
  float s = 0.f, d = 0.f;
  for (int c=lane; c<fout; c+=64){ float v = hr[c]; s += v*asrc[c]; d += v*adst[c]; }
  s = wave_sum64(s); d = wave_sum64(d);
  if (lane==0){ hs[wid] = s; hd[wid] = d; }
}

// Per-node fused: alpha -> online softmax -> weighted gather of h[src] -> +b -> ELU
template<int FOUT>
__global__ __launch_bounds__(256) void k_aggregate(const float* __restrict__ h,
    const float* __restrict__ hs, const float* __restrict__ hd,
    const int* __restrict__ srt_src, const float* __restrict__ srt_ea,
    const int* __restrict__ row_ptr, const float* __restrict__ ce_p,
    const float* __restrict__ b, float* __restrict__ xout, int n){
  int wid  = (int)((blockIdx.x*256 + threadIdx.x) >> 6);
  int lane = threadIdx.x & 63;
  if (wid >= n) return;
  float ce  = *ce_p;
  int beg = row_ptr[wid], end = row_ptr[wid+1];
  float hdn = hd[wid];
  float m = -INFINITY, den = 0.f, acc0 = 0.f, acc1 = 0.f;
  for (int base = beg; base < end; base += 64){
    int slot = base + lane;
    float a = -INFINITY; int src = 0;
    if (slot < end){
      src = srt_src[slot];
      a = hs[src] + hdn + srt_ea[slot]*ce;
      a = (a > 0.f) ? a : 0.2f*a;                 // leaky_relu(0.2)
    }
    float cm = wave_max64(a);
    float mnew = fmaxf(m, cm);
    float scale = expf(m - mnew);                 // m==-inf -> 0
    den *= scale; acc0 *= scale; acc1 *= scale;
    float p = expf(a - mnew);                     // invalid lanes -> 0
    den += wave_sum64(p);
    int cnt = end - base; if (cnt > 64) cnt = 64;
    for (int j=0; j<cnt; j++){
      float pj = __shfl(p, j);
      int   sj = __shfl(src, j);
      const float* hr = h + (size_t)sj*FOUT;
      acc0 += pj * hr[lane];
      if (FOUT == 128) acc1 += pj * hr[lane+64];
    }
    m = mnew;
  }
  float inv = 1.f/den;
  {
    float o = acc0*inv + b[lane];
    o = (o > 0.f) ? o : (expf(o) - 1.f);          // ELU
    xout[(size_t)wid*FOUT + lane] = o;
  }
  if (FOUT == 128){
    float o = acc1*inv + b[lane+64];
    o = (o > 0.f) ? o : (expf(o) - 1.f);
    xout[(size_t)wid*FOUT + lane + 64] = o;
  }
}

// column sums of x[n,64] -> gsum[64] (mean done in head)
__global__ void k_colsum(const float* __restrict__ x, float* __restrict__ gsum, int n){
  int lane = threadIdx.x;   // blockDim = 64
  float s = 0.f;
  for (int r = blockIdx.x; r < n; r += gridDim.x) s += x[(size_t)r*64 + lane];
  atomicAdd(&gsum[lane], s);
}

// final MLP head, single block of 128 threads
__global__ void k_head(const float* __restrict__ gs1, const float* __restrict__ gs2,
                       const float* __restrict__ xn1, const float* __restrict__ xn2,
                       const float* __restrict__ Wlin, const float* __restrict__ blin,
                       const float* __restrict__ Wc1, const float* __restrict__ bc1,
                       const float* __restrict__ Wc2, const float* __restrict__ bc2,
                       float* __restrict__ out){
  __shared__ float c1[80], c2[80], xcat[128], hb[16];
  int tid = threadIdx.x;
  const float invn = 1.f/(float)NN;
  if (tid < 64){ c1[tid] = gs1[tid]*invn; c2[tid] = gs2[tid]*invn; }
  else if (tid < 80){ c1[tid] = xn1[tid-64]; c2[tid] = xn2[tid-64]; }
  __syncthreads();
  if (tid < 64){
    float s = blin[tid];
    for (int k=0;k<80;k++) s += c1[k]*Wlin[k*64+tid];
    xcat[tid] = s;
  } else {
    int j = tid - 64;
    float s = blin[j];
    for (int k=0;k<80;k++) s += c2[k]*Wlin[k*64+j];
    xcat[tid] = s;
  }
  __syncthreads();
  if (tid < 16){
    float s = bc1[tid];
    for (int k=0;k<128;k++) s += xcat[k]*Wc1[k*16+tid];
    hb[tid] = fmaxf(s, 0.f);
  }
  __syncthreads();
  if (tid < 3){
    float s = bc2[tid];
    for (int k=0;k<16;k++) s += hb[k]*Wc2[k*3+tid];
    out[tid] = s;
  }
}

extern "C" void kernel_launch(void* const* d_in, const int* in_sizes, int n_in,
                              void* d_out, int out_size, void* d_ws, size_t ws_size,
                              hipStream_t stream){
  const float* x1  = (const float*)d_in[0];
  const float* x2  = (const float*)d_in[1];
  const int*   ei1 = (const int*)d_in[2];
  const int*   ei2 = (const int*)d_in[3];
  const float* xn1 = (const float*)d_in[4];
  const float* xn2 = (const float*)d_in[5];
  const float* ec1 = (const float*)d_in[6];
  const float* ec2 = (const float*)d_in[7];
  const float* W[3]    = {(const float*)d_in[8],  (const float*)d_in[14], (const float*)d_in[20]};
  const float* asrc[3] = {(const float*)d_in[9],  (const float*)d_in[15], (const float*)d_in[21]};
  const float* adst[3] = {(const float*)d_in[10], (const float*)d_in[16], (const float*)d_in[22]};
  const float* We[3]   = {(const float*)d_in[11], (const float*)d_in[17], (const float*)d_in[23]};
  const float* ae[3]   = {(const float*)d_in[12], (const float*)d_in[18], (const float*)d_in[24]};
  const float* bb[3]   = {(const float*)d_in[13], (const float*)d_in[19], (const float*)d_in[25]};
  const float* Wlin = (const float*)d_in[26];
  const float* blin = (const float*)d_in[27];
  const float* Wc1  = (const float*)d_in[28];
  const float* bc1  = (const float*)d_in[29];
  const float* Wc2  = (const float*)d_in[30];
  const float* bc2  = (const float*)d_in[31];
  float* out = (float*)d_out;

  // workspace partition (floats)
  float* ws   = (float*)d_ws;
  float* bufX = ws;                         // 50000*128
  float* bufH = bufX + (size_t)NN*128;      // 50000*128
  float* hs   = bufH + (size_t)NN*128;      // NN
  float* hd   = hs + NN;                    // NN
  float* esum = hd + NN;                    // NN
  int*   degi = (int*)(esum + NN);          // NN
  int*   row_ptr = degi + NN;               // NN+1
  int*   cursor  = row_ptr + NN + 1;        // NN
  int*   srt_src = cursor + NN;             // NE+NN
  float* srt_ea  = (float*)(srt_src + NE + NN); // NE+NN
  float* ce   = srt_ea + NE + NN;           // 1
  float* gsum = ce + 1;                     // 128 (2 x 64)

  hipMemsetAsync(gsum, 0, 128*sizeof(float), stream);

  for (int g = 0; g < 2; ++g){
    const int* ei = g ? ei2 : ei1;
    const float* ecol = g ? ec2 : ec1;
    const float* x0 = g ? x2 : x1;
    const int* srcp = ei;
    const int* dstp = ei + NE;

    // CSR build (dst-sorted, self-loop slot first in each segment)
    hipMemsetAsync(degi, 0, NN*sizeof(int), stream);
    hipMemsetAsync(esum, 0, NN*sizeof(float), stream);
    k_degsum<<<(NE+255)/256, 256, 0, stream>>>(dstp, ecol, degi, esum, NE);
    k_scan<<<1, 1024, 0, stream>>>(degi, row_ptr, NN);
    k_selfinit<<<(NN+255)/256, 256, 0, stream>>>(degi, esum, row_ptr, cursor, srt_src, srt_ea, NN);
    k_scatter<<<(NE+255)/256, 256, 0, stream>>>(srcp, dstp, ecol, cursor, srt_src, srt_ea, NE);

    for (int L = 0; L < 3; ++L){
      const float* xin = (L == 0) ? x0 : bufX;
      k_ce<<<1, 64, 0, stream>>>(We[L], ae[L], ce, (L==2)?64:128);
      if (L == 0)
        k_gemm7<<<(NN+7)/8, 256, 0, stream>>>(xin, W[0], bufH, NN);
      else if (L == 1)
        k_gemm<128,128><<<(NN+63)/64, 256, 0, stream>>>(xin, W[1], bufH, NN);
      else
        k_gemm<128,64><<<(NN+63)/64, 256, 0, stream>>>(xin, W[2], bufH, NN);
      int fout = (L==2) ? 64 : 128;
      k_hsd<<<(NN+3)/4, 256, 0, stream>>>(bufH, asrc[L], adst[L], hs, hd, NN, fout);
      if (fout == 128)
        k_aggregate<128><<<(NN+3)/4, 256, 0, stream>>>(bufH, hs, hd, srt_src, srt_ea, row_ptr, ce, bb[L], bufX, NN);
      else
        k_aggregate<64><<<(NN+3)/4, 256, 0, stream>>>(bufH, hs, hd, srt_src, srt_ea, row_ptr, ce, bb[L], bufX, NN);
    }
    k_colsum<<<256, 64, 0, stream>>>(bufX, gsum + g*64, NN);
  }

  k_head<<<1, 128, 0, stream>>>(gsum, gsum+64, xn1, xn2, Wlin, blin, Wc1, bc1, Wc2, bc2, out);
}

// Round 3
// 1012.275 us; speedup vs baseline: 1.6886x; 1.2526x over previous
//
#include <hip/hip_runtime.h>
#include <math.h>

#define NN 50000
#define NE 800000
#define SCAN_GRID ((NN + 1023) / 1024)

// ---------- wave helpers (wave64) ----------
static __device__ __forceinline__ float wave_max64(float v){
  #pragma unroll
  for(int off=32;off;off>>=1) v = fmaxf(v, __shfl_xor(v,off));
  return v;
}
static __device__ __forceinline__ float wave_sum64(float v){
  #pragma unroll
  for(int off=32;off;off>>=1) v += __shfl_xor(v,off);
  return v;
}

// ---------- CSR build ----------
__global__ void k_degsum(const int* __restrict__ dst, const float* __restrict__ eattr,
                         int* __restrict__ degi, float* __restrict__ esum, int E){
  int e = blockIdx.x*blockDim.x + threadIdx.x;
  if (e < E){
    int d = dst[e];
    atomicAdd(&degi[d], 1);
    atomicAdd(&esum[d], eattr[e]);
  }
}

// ---- device-wide exclusive scan of (deg[i]+1) -> row_ptr, 3 kernels ----
// pass A: per-block (1024 elems) local exclusive scan into row_ptr, block sums out
__global__ __launch_bounds__(256) void k_scan_a(const int* __restrict__ degi,
    int* __restrict__ row_ptr, int* __restrict__ blksum, int n){
  int tid = threadIdx.x, lane = tid & 63, wv = tid >> 6;
  int i0 = blockIdx.x*1024 + tid*4;
  int v0=0,v1=0,v2=0,v3=0;
  if (i0+3 < n){
    int4 t = *(const int4*)(degi+i0);
    v0=t.x+1; v1=t.y+1; v2=t.z+1; v3=t.w+1;
  } else {
    if(i0  <n) v0=degi[i0  ]+1;
    if(i0+1<n) v1=degi[i0+1]+1;
    if(i0+2<n) v2=degi[i0+2]+1;
    if(i0+3<n) v3=degi[i0+3]+1;
  }
  int ts = v0+v1+v2+v3;
  int inc = ts;
  #pragma unroll
  for (int off=1; off<64; off<<=1){
    int u = __shfl_up(inc, off);
    if (lane >= off) inc += u;
  }
  __shared__ int wsum[4];
  if (lane==63) wsum[wv] = inc;
  __syncthreads();
  int woff = 0;
  #pragma unroll
  for (int w=0; w<4; ++w) if (w < wv) woff += wsum[w];
  int excl = woff + inc - ts;
  if (i0   < n) row_ptr[i0  ] = excl;
  if (i0+1 < n) row_ptr[i0+1] = excl+v0;
  if (i0+2 < n) row_ptr[i0+2] = excl+v0+v1;
  if (i0+3 < n) row_ptr[i0+3] = excl+v0+v1+v2;
  if (tid==255) blksum[blockIdx.x] = woff + inc;
}

// pass B: exclusive scan of block sums (nb <= 64), single wave
__global__ void k_scan_b(int* __restrict__ blksum, int nb){
  int lane = threadIdx.x;
  int v = (lane < nb) ? blksum[lane] : 0;
  int inc = v;
  #pragma unroll
  for (int off=1; off<64; off<<=1){
    int u = __shfl_up(inc, off);
    if (lane >= off) inc += u;
  }
  if (lane < nb) blksum[lane] = inc - v;
}

// pass C: add block offsets in place; write row_ptr[n] (total is the constant E+N)
__global__ __launch_bounds__(256) void k_scan_c(int* __restrict__ row_ptr,
    const int* __restrict__ blksum, int n){
  int i0 = blockIdx.x*1024 + threadIdx.x*4;
  int off = blksum[blockIdx.x];
  if (i0+3 < n){
    int4 t = *(const int4*)(row_ptr+i0);
    t.x+=off; t.y+=off; t.z+=off; t.w+=off;
    *(int4*)(row_ptr+i0) = t;
  } else {
    if(i0  <n) row_ptr[i0  ] += off;
    if(i0+1<n) row_ptr[i0+1] += off;
    if(i0+2<n) row_ptr[i0+2] += off;
    if(i0+3<n) row_ptr[i0+3] += off;
  }
  if (i0==0 && blockIdx.x==0) row_ptr[n] = NE + NN;
}

// reserve slot row_ptr[i] for the self loop; loop_attr = esum/max(deg,1)
__global__ void k_selfinit(const int* __restrict__ degi, const float* __restrict__ esum,
                           const int* __restrict__ row_ptr, int* __restrict__ cursor,
                           int* __restrict__ srt_src, float* __restrict__ srt_ea, int n){
  int i = blockIdx.x*blockDim.x + threadIdx.x;
  if (i < n){
    int rp = row_ptr[i];
    cursor[i] = rp + 1;
    srt_src[rp] = i;
    srt_ea[rp] = esum[i] / fmaxf((float)degi[i], 1.0f);
  }
}

__global__ void k_scatter(const int* __restrict__ src, const int* __restrict__ dst,
                          const float* __restrict__ eattr, int* __restrict__ cursor,
                          int* __restrict__ srt_src, float* __restrict__ srt_ea, int E){
  int e = blockIdx.x*blockDim.x + threadIdx.x;
  if (e < E){
    int d = dst[e];
    int pos = atomicAdd(&cursor[d], 1);
    srt_src[pos] = src[e];
    srt_ea[pos] = eattr[e];
  }
}

// ---------- per-layer kernels ----------
// ce = dot(We[0,:], a_e)
__global__ void k_ce(const float* __restrict__ We, const float* __restrict__ ae,
                     float* __restrict__ ce, int fout){
  int l = threadIdx.x;
  float s = 0.f;
  for (int c=l; c<fout; c+=64) s += We[c]*ae[c];
  s = wave_sum64(s);
  if (l==0) *ce = s;
}

// ---- register-tiled GEMM: h[M,N] = x[M,K] @ W[K,N], K % 32 == 0 ----
template<int K, int N>
__global__ __launch_bounds__(256) void k_gemm(const float* __restrict__ x,
    const float* __restrict__ W, float* __restrict__ h, int n){
  constexpr int KB  = 32;
  constexpr int CG  = N/4;        // col groups of 4
  constexpr int TY  = 256/CG;     // row groups
  constexpr int RPT = 64/TY;      // rows per thread (8 for N=128, 4 for N=64)
  __shared__ float Wl[KB][N];
  __shared__ float Xt[KB][64];    // transposed x chunk
  int tid = threadIdx.x;
  int tx = tid % CG, ty = tid / CG;
  int r0 = blockIdx.x * 64;
  float acc[RPT][4] = {};
  for (int k0 = 0; k0 < K; k0 += KB){
    {
      const float4* src = (const float4*)(W + (size_t)k0*N);
      float4* dst = (float4*)(&Wl[0][0]);
      #pragma unroll
      for (int i = 0; i < KB*N/1024; ++i) dst[tid + i*256] = src[tid + i*256];
    }
    {
      int rr = tid >> 3, kk0 = (tid & 7) * 4;
      #pragma unroll
      for (int it = 0; it < 2; ++it){
        int r = rr + it*32;
        int gr = r0 + r;
        float4 v = (gr < n) ? *(const float4*)(x + (size_t)gr*K + k0 + kk0)
                            : make_float4(0.f,0.f,0.f,0.f);
        Xt[kk0+0][r] = v.x; Xt[kk0+1][r] = v.y; Xt[kk0+2][r] = v.z; Xt[kk0+3][r] = v.w;
      }
    }
    __syncthreads();
    #pragma unroll
    for (int kk = 0; kk < KB; ++kk){
      float4 wv = *(const float4*)(&Wl[kk][tx*4]);
      float xv[RPT];
      #pragma unroll
      for (int i = 0; i < RPT/4; ++i)
        *(float4*)&xv[i*4] = *(const float4*)(&Xt[kk][ty*RPT + i*4]);
      #pragma unroll
      for (int i=0;i<RPT;i++){
        acc[i][0] += xv[i]*wv.x; acc[i][1] += xv[i]*wv.y;
        acc[i][2] += xv[i]*wv.z; acc[i][3] += xv[i]*wv.w;
      }
    }
    __syncthreads();
  }
  #pragma unroll
  for (int i=0;i<RPT;i++){
    int gr = r0 + ty*RPT + i;
    if (gr < n) *(float4*)(h + (size_t)gr*N + tx*4) = *(float4*)&acc[i][0];
  }
}

// layer-1 GEMM: K=7, N=128. 8 rows per block.
__global__ __launch_bounds__(256) void k_gemm7(const float* __restrict__ x,
    const float* __restrict__ W, float* __restrict__ h, int n){
  __shared__ float Wl[7][128];
  int tid = threadIdx.x;
  for (int i = tid; i < 7*128; i += 256) ((float*)Wl)[i] = W[i];
  __syncthreads();
  int tx = tid & 31, ty = tid >> 5;
  int r = blockIdx.x*8 + ty;
  if (r >= n) return;
  const float* xr = x + (size_t)r*7;
  float xv[7];
  #pragma unroll
  for (int k=0;k<7;k++) xv[k] = xr[k];
  float4 s = make_float4(0.f,0.f,0.f,0.f);
  #pragma unroll
  for (int k=0;k<7;k++){
    float4 wv = *(const float4*)(&Wl[k][tx*4]);
    s.x += xv[k]*wv.x; s.y += xv[k]*wv.y; s.z += xv[k]*wv.z; s.w += xv[k]*wv.w;
  }
  *(float4*)(h + (size_t)r*128 + tx*4) = s;
}

// hs[i] = h[i]·a_src ; hd[i] = h[i]·a_dst  (one wave per node)
__global__ __launch_bounds__(256) void k_hsd(const float* __restrict__ h,
    const float* __restrict__ asrc, const float* __restrict__ adst,
    float* __restrict__ hs, float* __restrict__ hd, int n, int fout){
  int wid  = (int)((blockIdx.x*256 + threadIdx.x) >> 6);
  int lane = threadIdx.x & 63;
  if (wid >= n) return;
  const float* hr = h + (size_t)wid*fout;
  float s = 0.f, d = 0.f;
  for (int c=lane; c<fout; c+=64){ float v = hr[c]; s += v*asrc[c]; d += v*adst[c]; }
  s = wave_sum64(s); d = wave_sum64(d);
  if (lane==0){ hs[wid] = s; hd[wid] = d; }
}

// Per-node fused: alpha -> online softmax -> weighted gather of h[src] -> +b -> ELU
// LDS-staged p/src per wave (broadcast reads), gather unrolled x4 for MLP.
template<int FOUT>
__global__ __launch_bounds__(256) void k_aggregate(const float* __restrict__ h,
    const float* __restrict__ hs, const float* __restrict__ hd,
    const int* __restrict__ srt_src, const float* __restrict__ srt_ea,
    const int* __restrict__ row_ptr, const float* __restrict__ ce_p,
    const float* __restrict__ b, float* __restrict__ xout, int n){
  __shared__ float s_p[4][64];
  __shared__ int   s_s[4][64];
  int tid = threadIdx.x;
  int wv = tid >> 6, lane = tid & 63;
  int wid = (int)((blockIdx.x*256 + tid) >> 6);
  if (wid >= n) return;                 // uniform per wave
  float ce  = *ce_p;
  int beg = row_ptr[wid], end = row_ptr[wid+1];
  float hdn = hd[wid];
  float m = -INFINITY, den = 0.f, acc0 = 0.f, acc1 = 0.f;
  for (int base = beg; base < end; base += 64){
    int slot = base + lane;
    float a = -INFINITY; int src = 0;
    if (slot < end){
      src = srt_src[slot];
      a = hs[src] + hdn + srt_ea[slot]*ce;
      a = (a > 0.f) ? a : 0.2f*a;                 // leaky_relu(0.2)
    }
    float cm = wave_max64(a);
    float mnew = fmaxf(m, cm);
    float scale = __expf(m - mnew);               // m==-inf -> 0
    den *= scale; acc0 *= scale; acc1 *= scale;
    float p = __expf(a - mnew);                   // invalid lanes -> 0
    den += wave_sum64(p);
    s_p[wv][lane] = p; s_s[wv][lane] = src;
    asm volatile("s_waitcnt lgkmcnt(0)" ::: "memory");  // intra-wave LDS RAW fence
    int cnt = end - base; if (cnt > 64) cnt = 64;
    int j = 0;
    for (; j + 4 <= cnt; j += 4){
      float p0=s_p[wv][j+0], p1=s_p[wv][j+1], p2=s_p[wv][j+2], p3=s_p[wv][j+3];
      const float* r0 = h + (size_t)s_s[wv][j+0]*FOUT;
      const float* r1 = h + (size_t)s_s[wv][j+1]*FOUT;
      const float* r2 = h + (size_t)s_s[wv][j+2]*FOUT;
      const float* r3 = h + (size_t)s_s[wv][j+3]*FOUT;
      float a0=r0[lane], a1=r1[lane], a2=r2[lane], a3=r3[lane];
      acc0 += p0*a0; acc0 += p1*a1; acc0 += p2*a2; acc0 += p3*a3;
      if (FOUT == 128){
        float b0=r0[lane+64], b1=r1[lane+64], b2=r2[lane+64], b3=r3[lane+64];
        acc1 += p0*b0; acc1 += p1*b1; acc1 += p2*b2; acc1 += p3*b3;
      }
    }
    for (; j < cnt; ++j){
      float pj = s_p[wv][j];
      const float* hr = h + (size_t)s_s[wv][j]*FOUT;
      acc0 += pj * hr[lane];
      if (FOUT == 128) acc1 += pj * hr[lane+64];
    }
    m = mnew;
  }
  float inv = 1.f/den;
  {
    float o = acc0*inv + b[lane];
    o = (o > 0.f) ? o : (__expf(o) - 1.f);        // ELU
    xout[(size_t)wid*FOUT + lane] = o;
  }
  if (FOUT == 128){
    float o = acc1*inv + b[lane+64];
    o = (o > 0.f) ? o : (__expf(o) - 1.f);
    xout[(size_t)wid*FOUT + lane + 64] = o;
  }
}

// column sums of x[n,64] -> gsum[64] (mean done in head)
__global__ void k_colsum(const float* __restrict__ x, float* __restrict__ gsum, int n){
  int lane = threadIdx.x;   // blockDim = 64
  float s = 0.f;
  for (int r = blockIdx.x; r < n; r += gridDim.x) s += x[(size_t)r*64 + lane];
  atomicAdd(&gsum[lane], s);
}

// final MLP head, single block of 128 threads
__global__ void k_head(const float* __restrict__ gs1, const float* __restrict__ gs2,
                       const float* __restrict__ xn1, const float* __restrict__ xn2,
                       const float* __restrict__ Wlin, const float* __restrict__ blin,
                       const float* __restrict__ Wc1, const float* __restrict__ bc1,
                       const float* __restrict__ Wc2, const float* __restrict__ bc2,
                       float* __restrict__ out){
  __shared__ float c1[80], c2[80], xcat[128], hb[16];
  int tid = threadIdx.x;
  const float invn = 1.f/(float)NN;
  if (tid < 64){ c1[tid] = gs1[tid]*invn; c2[tid] = gs2[tid]*invn; }
  else if (tid < 80){ c1[tid] = xn1[tid-64]; c2[tid] = xn2[tid-64]; }
  __syncthreads();
  if (tid < 64){
    float s = blin[tid];
    for (int k=0;k<80;k++) s += c1[k]*Wlin[k*64+tid];
    xcat[tid] = s;
  } else {
    int j = tid - 64;
    float s = blin[j];
    for (int k=0;k<80;k++) s += c2[k]*Wlin[k*64+j];
    xcat[tid] = s;
  }
  __syncthreads();
  if (tid < 16){
    float s = bc1[tid];
    for (int k=0;k<128;k++) s += xcat[k]*Wc1[k*16+tid];
    hb[tid] = fmaxf(s, 0.f);
  }
  __syncthreads();
  if (tid < 3){
    float s = bc2[tid];
    for (int k=0;k<16;k++) s += hb[k]*Wc2[k*3+tid];
    out[tid] = s;
  }
}

extern "C" void kernel_launch(void* const* d_in, const int* in_sizes, int n_in,
                              void* d_out, int out_size, void* d_ws, size_t ws_size,
                              hipStream_t stream){
  const float* x1  = (const float*)d_in[0];
  const float* x2  = (const float*)d_in[1];
  const int*   ei1 = (const int*)d_in[2];
  const int*   ei2 = (const int*)d_in[3];
  const float* xn1 = (const float*)d_in[4];
  const float* xn2 = (const float*)d_in[5];
  const float* ec1 = (const float*)d_in[6];
  const float* ec2 = (const float*)d_in[7];
  const float* W[3]    = {(const float*)d_in[8],  (const float*)d_in[14], (const float*)d_in[20]};
  const float* asrc[3] = {(const float*)d_in[9],  (const float*)d_in[15], (const float*)d_in[21]};
  const float* adst[3] = {(const float*)d_in[10], (const float*)d_in[16], (const float*)d_in[22]};
  const float* We[3]   = {(const float*)d_in[11], (const float*)d_in[17], (const float*)d_in[23]};
  const float* ae[3]   = {(const float*)d_in[12], (const float*)d_in[18], (const float*)d_in[24]};
  const float* bb[3]   = {(const float*)d_in[13], (const float*)d_in[19], (const float*)d_in[25]};
  const float* Wlin = (const float*)d_in[26];
  const float* blin = (const float*)d_in[27];
  const float* Wc1  = (const float*)d_in[28];
  const float* bc1  = (const float*)d_in[29];
  const float* Wc2  = (const float*)d_in[30];
  const float* bc2  = (const float*)d_in[31];
  float* out = (float*)d_out;

  // workspace partition (floats)
  float* ws   = (float*)d_ws;
  float* bufX = ws;                         // 50000*128
  float* bufH = bufX + (size_t)NN*128;      // 50000*128
  float* hs   = bufH + (size_t)NN*128;      // NN
  float* hd   = hs + NN;                    // NN
  float* esum = hd + NN;                    // NN
  int*   degi = (int*)(esum + NN);          // NN
  int*   row_ptr = degi + NN;               // NN+1
  int*   cursor  = row_ptr + NN + 1;        // NN
  int*   srt_src = cursor + NN;             // NE+NN
  float* srt_ea  = (float*)(srt_src + NE + NN); // NE+NN
  float* ce   = srt_ea + NE + NN;           // 1
  float* gsum = ce + 1;                     // 128 (2 x 64)
  int*   blksum = (int*)(gsum + 128);       // 64

  hipMemsetAsync(gsum, 0, 128*sizeof(float), stream);

  for (int g = 0; g < 2; ++g){
    const int* ei = g ? ei2 : ei1;
    const float* ecol = g ? ec2 : ec1;
    const float* x0 = g ? x2 : x1;
    const int* srcp = ei;
    const int* dstp = ei + NE;

    // CSR build (dst-sorted, self-loop slot first in each segment)
    hipMemsetAsync(degi, 0, NN*sizeof(int), stream);
    hipMemsetAsync(esum, 0, NN*sizeof(float), stream);
    k_degsum<<<(NE+255)/256, 256, 0, stream>>>(dstp, ecol, degi, esum, NE);
    k_scan_a<<<SCAN_GRID, 256, 0, stream>>>(degi, row_ptr, blksum, NN);
    k_scan_b<<<1, 64, 0, stream>>>(blksum, SCAN_GRID);
    k_scan_c<<<SCAN_GRID, 256, 0, stream>>>(row_ptr, blksum, NN);
    k_selfinit<<<(NN+255)/256, 256, 0, stream>>>(degi, esum, row_ptr, cursor, srt_src, srt_ea, NN);
    k_scatter<<<(NE+255)/256, 256, 0, stream>>>(srcp, dstp, ecol, cursor, srt_src, srt_ea, NE);

    for (int L = 0; L < 3; ++L){
      const float* xin = (L == 0) ? x0 : bufX;
      k_ce<<<1, 64, 0, stream>>>(We[L], ae[L], ce, (L==2)?64:128);
      if (L == 0)
        k_gemm7<<<(NN+7)/8, 256, 0, stream>>>(xin, W[0], bufH, NN);
      else if (L == 1)
        k_gemm<128,128><<<(NN+63)/64, 256, 0, stream>>>(xin, W[1], bufH, NN);
      else
        k_gemm<128,64><<<(NN+63)/64, 256, 0, stream>>>(xin, W[2], bufH, NN);
      int fout = (L==2) ? 64 : 128;
      k_hsd<<<(NN+3)/4, 256, 0, stream>>>(bufH, asrc[L], adst[L], hs, hd, NN, fout);
      if (fout == 128)
        k_aggregate<128><<<(NN+3)/4, 256, 0, stream>>>(bufH, hs, hd, srt_src, srt_ea, row_ptr, ce, bb[L], bufX, NN);
      else
        k_aggregate<64><<<(NN+3)/4, 256, 0, stream>>>(bufH, hs, hd, srt_src, srt_ea, row_ptr, ce, bb[L], bufX, NN);
    }
    k_colsum<<<256, 64, 0, stream>>>(bufX, gsum + g*64, NN);
  }

  k_head<<<1, 128, 0, stream>>>(gsum, gsum+64, xn1, xn2, Wlin, blin, Wc1, bc1, Wc2, bc2, out);
}

// Round 4
// 873.992 us; speedup vs baseline: 1.9557x; 1.1582x over previous
//
#include <hip/hip_runtime.h>
#include <math.h>

#define NN 50000
#define NE 800000
#define SCAN_GRID ((NN + 1023) / 1024)

// ---------- wave helpers (wave64) ----------
static __device__ __forceinline__ float wave_max64(float v){
  #pragma unroll
  for(int off=32;off;off>>=1) v = fmaxf(v, __shfl_xor(v,off));
  return v;
}
static __device__ __forceinline__ float wave_sum64(float v){
  #pragma unroll
  for(int off=32;off;off>>=1) v += __shfl_xor(v,off);
  return v;
}

// ---------- CSR build ----------
// degree histogram only (esum handled post-scatter by k_selfea)
__global__ void k_deg(const int* __restrict__ dst, int* __restrict__ degi, int E){
  int e0 = (blockIdx.x*blockDim.x + threadIdx.x)*4;
  if (e0+3 < E){
    int4 d = *(const int4*)(dst+e0);
    atomicAdd(&degi[d.x],1); atomicAdd(&degi[d.y],1);
    atomicAdd(&degi[d.z],1); atomicAdd(&degi[d.w],1);
  } else {
    for (int e=e0; e<E; ++e) atomicAdd(&degi[dst[e]],1);
  }
}

// pass A: per-block (1024 elems) local exclusive scan of (deg+1) -> row_ptr, block sums
__global__ __launch_bounds__(256) void k_scan_a(const int* __restrict__ degi,
    int* __restrict__ row_ptr, int* __restrict__ blksum, int n){
  int tid = threadIdx.x, lane = tid & 63, wv = tid >> 6;
  int i0 = blockIdx.x*1024 + tid*4;
  int v0=0,v1=0,v2=0,v3=0;
  if (i0+3 < n){
    int4 t = *(const int4*)(degi+i0);
    v0=t.x+1; v1=t.y+1; v2=t.z+1; v3=t.w+1;
  } else {
    if(i0  <n) v0=degi[i0  ]+1;
    if(i0+1<n) v1=degi[i0+1]+1;
    if(i0+2<n) v2=degi[i0+2]+1;
    if(i0+3<n) v3=degi[i0+3]+1;
  }
  int ts = v0+v1+v2+v3;
  int inc = ts;
  #pragma unroll
  for (int off=1; off<64; off<<=1){
    int u = __shfl_up(inc, off);
    if (lane >= off) inc += u;
  }
  __shared__ int wsum[4];
  if (lane==63) wsum[wv] = inc;
  __syncthreads();
  int woff = 0;
  #pragma unroll
  for (int w=0; w<4; ++w) if (w < wv) woff += wsum[w];
  int excl = woff + inc - ts;
  if (i0   < n) row_ptr[i0  ] = excl;
  if (i0+1 < n) row_ptr[i0+1] = excl+v0;
  if (i0+2 < n) row_ptr[i0+2] = excl+v0+v1;
  if (i0+3 < n) row_ptr[i0+3] = excl+v0+v1+v2;
  if (tid==255) blksum[blockIdx.x] = woff + inc;
}

// pass C: add block offset (computed in-kernel from blksum), finalize row_ptr,
// init cursor, reserve self-loop src slot. SCAN_GRID <= 64.
__global__ __launch_bounds__(256) void k_scan_c(int* __restrict__ row_ptr,
    const int* __restrict__ blksum, int* __restrict__ cursor,
    int2* __restrict__ srt, int n){
  __shared__ int s_off;
  int tid = threadIdx.x;
  if (tid < 64){
    int v = (tid < blockIdx.x) ? blksum[tid] : 0;
    #pragma unroll
    for (int off=32; off; off>>=1) v += __shfl_xor(v, off);
    if (tid==0) s_off = v;
  }
  __syncthreads();
  int off = s_off;
  int i0 = blockIdx.x*1024 + tid*4;
  #pragma unroll
  for (int u=0; u<4; ++u){
    int i = i0+u;
    if (i < n){
      int rp = row_ptr[i] + off;
      row_ptr[i] = rp;
      cursor[i] = rp + 1;
      srt[rp].x = i;            // self-loop src; .y filled by k_selfea
    }
  }
  if (tid==0 && blockIdx.x==0) row_ptr[n] = NE + NN;
}

__global__ void k_scatter(const int* __restrict__ src, const int* __restrict__ dst,
                          const float* __restrict__ eattr, int* __restrict__ cursor,
                          int2* __restrict__ srt, int E){
  int e = blockIdx.x*blockDim.x + threadIdx.x;
  if (e < E){
    int d = dst[e];
    int pos = atomicAdd(&cursor[d], 1);
    srt[pos] = make_int2(src[e], __float_as_int(eattr[e]));
  }
}

// self-loop attr = mean of segment's edge attrs (excluding the self slot)
__global__ void k_selfea(const int* __restrict__ row_ptr, int2* __restrict__ srt, int n){
  int i = blockIdx.x*blockDim.x + threadIdx.x;
  if (i < n){
    int beg = row_ptr[i], end = row_ptr[i+1];
    int deg = end - beg - 1;
    float s = 0.f;
    for (int j = beg+1; j < end; ++j) s += __int_as_float(srt[j].y);
    srt[beg].y = __float_as_int(s / fmaxf((float)deg, 1.f));
  }
}

// ---------- per-layer kernels ----------
// ce[L] = dot(We_L[0,:], a_e_L) for all 3 layers, one launch
__global__ void k_ce3(const float* __restrict__ We0, const float* __restrict__ ae0,
                      const float* __restrict__ We1, const float* __restrict__ ae1,
                      const float* __restrict__ We2, const float* __restrict__ ae2,
                      float* __restrict__ ce3){
  int l = threadIdx.x;
  const float* We[3] = {We0, We1, We2};
  const float* ae[3] = {ae0, ae1, ae2};
  const int fo[3] = {128, 128, 64};
  for (int L = 0; L < 3; ++L){
    float s = 0.f;
    for (int c = l; c < fo[L]; c += 64) s += We[L][c]*ae[L][c];
    s = wave_sum64(s);
    if (l == 0) ce3[L] = s;
  }
}

// ---- register-tiled GEMM + fused hs/hd epilogue ----
// h[M,N] = x[M,K] @ W[K,N]; hs = h@a_src, hd = h@a_dst
template<int K, int N>
__global__ __launch_bounds__(256) void k_gemm(const float* __restrict__ x,
    const float* __restrict__ W, const float* __restrict__ a_src,
    const float* __restrict__ a_dst, float* __restrict__ h,
    float* __restrict__ hs, float* __restrict__ hd, int n){
  constexpr int KB  = 32;
  constexpr int CG  = N/4;        // col groups of 4
  constexpr int TY  = 256/CG;     // row groups
  constexpr int RPT = 64/TY;      // rows per thread
  __shared__ float Wl[KB][N];
  __shared__ float Xt[KB][64];
  int tid = threadIdx.x;
  int tx = tid % CG, ty = tid / CG;
  int r0 = blockIdx.x * 64;
  float acc[RPT][4] = {};
  for (int k0 = 0; k0 < K; k0 += KB){
    {
      const float4* src = (const float4*)(W + (size_t)k0*N);
      float4* dst = (float4*)(&Wl[0][0]);
      #pragma unroll
      for (int i = 0; i < KB*N/1024; ++i) dst[tid + i*256] = src[tid + i*256];
    }
    {
      int rr = tid >> 3, kk0 = (tid & 7) * 4;
      #pragma unroll
      for (int it = 0; it < 2; ++it){
        int r = rr + it*32;
        int gr = r0 + r;
        float4 v = (gr < n) ? *(const float4*)(x + (size_t)gr*K + k0 + kk0)
                            : make_float4(0.f,0.f,0.f,0.f);
        Xt[kk0+0][r] = v.x; Xt[kk0+1][r] = v.y; Xt[kk0+2][r] = v.z; Xt[kk0+3][r] = v.w;
      }
    }
    __syncthreads();
    #pragma unroll
    for (int kk = 0; kk < KB; ++kk){
      float4 wv = *(const float4*)(&Wl[kk][tx*4]);
      float xv[RPT];
      #pragma unroll
      for (int i = 0; i < RPT/4; ++i)
        *(float4*)&xv[i*4] = *(const float4*)(&Xt[kk][ty*RPT + i*4]);
      #pragma unroll
      for (int i=0;i<RPT;i++){
        acc[i][0] += xv[i]*wv.x; acc[i][1] += xv[i]*wv.y;
        acc[i][2] += xv[i]*wv.z; acc[i][3] += xv[i]*wv.w;
      }
    }
    __syncthreads();
  }
  // write h
  #pragma unroll
  for (int i=0;i<RPT;i++){
    int gr = r0 + ty*RPT + i;
    if (gr < n) *(float4*)(h + (size_t)gr*N + tx*4) = *(float4*)&acc[i][0];
  }
  // fused hs/hd: per-row dot, reduce across the CG threads (consecutive,
  // CG-aligned lane group) via xor shuffle
  float as4[4], ad4[4];
  #pragma unroll
  for (int j=0;j<4;j++){ as4[j] = a_src[tx*4+j]; ad4[j] = a_dst[tx*4+j]; }
  #pragma unroll
  for (int i=0;i<RPT;i++){
    float ps = acc[i][0]*as4[0] + acc[i][1]*as4[1] + acc[i][2]*as4[2] + acc[i][3]*as4[3];
    float pd = acc[i][0]*ad4[0] + acc[i][1]*ad4[1] + acc[i][2]*ad4[2] + acc[i][3]*ad4[3];
    #pragma unroll
    for (int off=CG/2; off; off>>=1){ ps += __shfl_xor(ps, off); pd += __shfl_xor(pd, off); }
    int gr = r0 + ty*RPT + i;
    if (tx==0 && gr < n){ hs[gr] = ps; hd[gr] = pd; }
  }
}

// layer-1 GEMM: K=7, N=128, fused hs/hd. 8 rows per block.
__global__ __launch_bounds__(256) void k_gemm7(const float* __restrict__ x,
    const float* __restrict__ W, const float* __restrict__ a_src,
    const float* __restrict__ a_dst, float* __restrict__ h,
    float* __restrict__ hs, float* __restrict__ hd, int n){
  __shared__ float Wl[7][128];
  int tid = threadIdx.x;
  for (int i = tid; i < 7*128; i += 256) ((float*)Wl)[i] = W[i];
  __syncthreads();
  int tx = tid & 31, ty = tid >> 5;
  int r = blockIdx.x*8 + ty;
  if (r >= n) return;
  const float* xr = x + (size_t)r*7;
  float xv[7];
  #pragma unroll
  for (int k=0;k<7;k++) xv[k] = xr[k];
  float4 s = make_float4(0.f,0.f,0.f,0.f);
  #pragma unroll
  for (int k=0;k<7;k++){
    float4 wv = *(const float4*)(&Wl[k][tx*4]);
    s.x += xv[k]*wv.x; s.y += xv[k]*wv.y; s.z += xv[k]*wv.z; s.w += xv[k]*wv.w;
  }
  *(float4*)(h + (size_t)r*128 + tx*4) = s;
  float ps = s.x*a_src[tx*4] + s.y*a_src[tx*4+1] + s.z*a_src[tx*4+2] + s.w*a_src[tx*4+3];
  float pd = s.x*a_dst[tx*4] + s.y*a_dst[tx*4+1] + s.z*a_dst[tx*4+2] + s.w*a_dst[tx*4+3];
  #pragma unroll
  for (int off=16; off; off>>=1){ ps += __shfl_xor(ps, off); pd += __shfl_xor(pd, off); }
  if (tx==0){ hs[r] = ps; hd[r] = pd; }
}

// Per-node fused: alpha -> online softmax -> weighted gather of h[src] -> +b -> ELU
template<int FOUT>
__global__ __launch_bounds__(256) void k_aggregate(const float* __restrict__ h,
    const float* __restrict__ hs, const float* __restrict__ hd,
    const int2* __restrict__ srt, const int* __restrict__ row_ptr,
    const float* __restrict__ ce_p, const float* __restrict__ b,
    float* __restrict__ xout, int n){
  __shared__ float s_p[4][64];
  __shared__ int   s_s[4][64];
  int tid = threadIdx.x;
  int wv = tid >> 6, lane = tid & 63;
  int wid = (int)((blockIdx.x*256 + tid) >> 6);
  if (wid >= n) return;                 // uniform per wave
  float ce  = *ce_p;
  int beg = row_ptr[wid], end = row_ptr[wid+1];
  float hdn = hd[wid];
  float m = -INFINITY, den = 0.f, acc0 = 0.f, acc1 = 0.f;
  for (int base = beg; base < end; base += 64){
    int slot = base + lane;
    float a = -INFINITY; int src = 0;
    if (slot < end){
      int2 pk = srt[slot];
      src = pk.x;
      a = hs[src] + hdn + __int_as_float(pk.y)*ce;
      a = (a > 0.f) ? a : 0.2f*a;                 // leaky_relu(0.2)
    }
    float cm = wave_max64(a);
    float mnew = fmaxf(m, cm);
    float scale = __expf(m - mnew);               // m==-inf -> 0
    den *= scale; acc0 *= scale; acc1 *= scale;
    float p = __expf(a - mnew);                   // invalid lanes -> 0
    den += wave_sum64(p);
    s_p[wv][lane] = p; s_s[wv][lane] = src;
    asm volatile("s_waitcnt lgkmcnt(0)" ::: "memory");  // intra-wave LDS RAW fence
    int cnt = end - base; if (cnt > 64) cnt = 64;
    int j = 0;
    for (; j + 8 <= cnt; j += 8){
      float pp[8]; const float* rr[8];
      #pragma unroll
      for (int u=0;u<8;u++){ pp[u]=s_p[wv][j+u]; rr[u]=h+(size_t)s_s[wv][j+u]*FOUT; }
      #pragma unroll
      for (int u=0;u<8;u++) acc0 += pp[u]*rr[u][lane];
      if (FOUT == 128){
        #pragma unroll
        for (int u=0;u<8;u++) acc1 += pp[u]*rr[u][lane+64];
      }
    }
    for (; j < cnt; ++j){
      float pj = s_p[wv][j];
      const float* hr = h + (size_t)s_s[wv][j]*FOUT;
      acc0 += pj * hr[lane];
      if (FOUT == 128) acc1 += pj * hr[lane+64];
    }
    m = mnew;
  }
  float inv = 1.f/den;
  {
    float o = acc0*inv + b[lane];
    o = (o > 0.f) ? o : (__expf(o) - 1.f);        // ELU
    xout[(size_t)wid*FOUT + lane] = o;
  }
  if (FOUT == 128){
    float o = acc1*inv + b[lane+64];
    o = (o > 0.f) ? o : (__expf(o) - 1.f);
    xout[(size_t)wid*FOUT + lane + 64] = o;
  }
}

// column sums of x[n,64] -> gsum[64] (mean done in head)
__global__ void k_colsum(const float* __restrict__ x, float* __restrict__ gsum, int n){
  int lane = threadIdx.x;   // blockDim = 64
  float s = 0.f;
  for (int r = blockIdx.x; r < n; r += gridDim.x) s += x[(size_t)r*64 + lane];
  atomicAdd(&gsum[lane], s);
}

// final MLP head, single block of 128 threads
__global__ void k_head(const float* __restrict__ gs1, const float* __restrict__ gs2,
                       const float* __restrict__ xn1, const float* __restrict__ xn2,
                       const float* __restrict__ Wlin, const float* __restrict__ blin,
                       const float* __restrict__ Wc1, const float* __restrict__ bc1,
                       const float* __restrict__ Wc2, const float* __restrict__ bc2,
                       float* __restrict__ out){
  __shared__ float c1[80], c2[80], xcat[128], hb[16];
  int tid = threadIdx.x;
  const float invn = 1.f/(float)NN;
  if (tid < 64){ c1[tid] = gs1[tid]*invn; c2[tid] = gs2[tid]*invn; }
  else if (tid < 80){ c1[tid] = xn1[tid-64]; c2[tid] = xn2[tid-64]; }
  __syncthreads();
  if (tid < 64){
    float s = blin[tid];
    for (int k=0;k<80;k++) s += c1[k]*Wlin[k*64+tid];
    xcat[tid] = s;
  } else {
    int j = tid - 64;
    float s = blin[j];
    for (int k=0;k<80;k++) s += c2[k]*Wlin[k*64+j];
    xcat[tid] = s;
  }
  __syncthreads();
  if (tid < 16){
    float s = bc1[tid];
    for (int k=0;k<128;k++) s += xcat[k]*Wc1[k*16+tid];
    hb[tid] = fmaxf(s, 0.f);
  }
  __syncthreads();
  if (tid < 3){
    float s = bc2[tid];
    for (int k=0;k<16;k++) s += hb[k]*Wc2[k*3+tid];
    out[tid] = s;
  }
}

extern "C" void kernel_launch(void* const* d_in, const int* in_sizes, int n_in,
                              void* d_out, int out_size, void* d_ws, size_t ws_size,
                              hipStream_t stream){
  const float* x1  = (const float*)d_in[0];
  const float* x2  = (const float*)d_in[1];
  const int*   ei1 = (const int*)d_in[2];
  const int*   ei2 = (const int*)d_in[3];
  const float* xn1 = (const float*)d_in[4];
  const float* xn2 = (const float*)d_in[5];
  const float* ec1 = (const float*)d_in[6];
  const float* ec2 = (const float*)d_in[7];
  const float* W[3]    = {(const float*)d_in[8],  (const float*)d_in[14], (const float*)d_in[20]};
  const float* asrc[3] = {(const float*)d_in[9],  (const float*)d_in[15], (const float*)d_in[21]};
  const float* adst[3] = {(const float*)d_in[10], (const float*)d_in[16], (const float*)d_in[22]};
  const float* We[3]   = {(const float*)d_in[11], (const float*)d_in[17], (const float*)d_in[23]};
  const float* ae[3]   = {(const float*)d_in[12], (const float*)d_in[18], (const float*)d_in[24]};
  const float* bb[3]   = {(const float*)d_in[13], (const float*)d_in[19], (const float*)d_in[25]};
  const float* Wlin = (const float*)d_in[26];
  const float* blin = (const float*)d_in[27];
  const float* Wc1  = (const float*)d_in[28];
  const float* bc1  = (const float*)d_in[29];
  const float* Wc2  = (const float*)d_in[30];
  const float* bc2  = (const float*)d_in[31];
  float* out = (float*)d_out;

  // workspace partition (floats; srt right after bufH keeps int2 8B-aligned)
  float* ws   = (float*)d_ws;
  float* bufX = ws;                               // NN*128
  float* bufH = bufX + (size_t)NN*128;            // NN*128
  int2*  srt  = (int2*)(bufH + (size_t)NN*128);   // NE+NN packed (src, ea)
  float* hs   = (float*)(srt + NE + NN);          // NN
  float* hd   = hs + NN;                          // NN
  int*   degi = (int*)(hd + NN);                  // NN
  int*   row_ptr = degi + NN;                     // NN+1
  int*   cursor  = row_ptr + NN + 1;              // NN
  float* ce3  = (float*)(cursor + NN);            // 4
  float* gsum = ce3 + 4;                          // 128
  int*   blksum = (int*)(gsum + 128);             // 64

  hipMemsetAsync(gsum, 0, 128*sizeof(float), stream);
  k_ce3<<<1, 64, 0, stream>>>(We[0], ae[0], We[1], ae[1], We[2], ae[2], ce3);

  for (int g = 0; g < 2; ++g){
    const int* ei = g ? ei2 : ei1;
    const float* ecol = g ? ec2 : ec1;
    const float* x0 = g ? x2 : x1;
    const int* srcp = ei;
    const int* dstp = ei + NE;

    // CSR build (dst-sorted, self-loop slot first in each segment)
    hipMemsetAsync(degi, 0, NN*sizeof(int), stream);
    k_deg<<<(NE/4+255)/256, 256, 0, stream>>>(dstp, degi, NE);
    k_scan_a<<<SCAN_GRID, 256, 0, stream>>>(degi, row_ptr, blksum, NN);
    k_scan_c<<<SCAN_GRID, 256, 0, stream>>>(row_ptr, blksum, cursor, srt, NN);
    k_scatter<<<(NE+255)/256, 256, 0, stream>>>(srcp, dstp, ecol, cursor, srt, NE);
    k_selfea<<<(NN+255)/256, 256, 0, stream>>>(row_ptr, srt, NN);

    for (int L = 0; L < 3; ++L){
      const float* xin = (L == 0) ? x0 : bufX;
      if (L == 0)
        k_gemm7<<<(NN+7)/8, 256, 0, stream>>>(xin, W[0], asrc[0], adst[0], bufH, hs, hd, NN);
      else if (L == 1)
        k_gemm<128,128><<<(NN+63)/64, 256, 0, stream>>>(xin, W[1], asrc[1], adst[1], bufH, hs, hd, NN);
      else
        k_gemm<128,64><<<(NN+63)/64, 256, 0, stream>>>(xin, W[2], asrc[2], adst[2], bufH, hs, hd, NN);
      int fout = (L==2) ? 64 : 128;
      if (fout == 128)
        k_aggregate<128><<<(NN+3)/4, 256, 0, stream>>>(bufH, hs, hd, srt, row_ptr, ce3+L, bb[L], bufX, NN);
      else
        k_aggregate<64><<<(NN+3)/4, 256, 0, stream>>>(bufH, hs, hd, srt, row_ptr, ce3+L, bb[L], bufX, NN);
    }
    k_colsum<<<256, 64, 0, stream>>>(bufX, gsum + g*64, NN);
  }

  k_head<<<1, 128, 0, stream>>>(gsum, gsum+64, xn1, xn2, Wlin, blin, Wc1, bc1, Wc2, bc2, out);
}

// Round 5
// 744.681 us; speedup vs baseline: 2.2953x; 1.1736x over previous
//
#include <hip/hip_runtime.h>
#include <math.h>

#define NN 50000
#define NE 800000
#define NT 100000           // merged nodes (two graphs)
#define ET (2*NE + NT)      // merged CSR entries incl self loops
#define SCAN_GRID ((NT + 2047) / 2048)   // 49 <= 64

// ---------- helpers ----------
static __device__ __forceinline__ float wave_max64(float v){
  #pragma unroll
  for(int off=32;off;off>>=1) v = fmaxf(v, __shfl_xor(v,off));
  return v;
}
static __device__ __forceinline__ float wave_sum64(float v){
  #pragma unroll
  for(int off=32;off;off>>=1) v += __shfl_xor(v,off);
  return v;
}
// bf16 pack/unpack (RNE)
static __device__ __forceinline__ unsigned short f2bf(float f){
  unsigned u = __float_as_uint(f);
  return (unsigned short)((u + 0x7FFFu + ((u>>16)&1u)) >> 16);
}
static __device__ __forceinline__ float bflo(unsigned v){ return __uint_as_float(v<<16); }
static __device__ __forceinline__ float bfhi(unsigned v){ return __uint_as_float(v & 0xFFFF0000u); }

// ---------- CSR build (merged: g2 node i -> i+NN) ----------
__global__ void k_deg(const int* __restrict__ d1, const int* __restrict__ d2,
                      int* __restrict__ degi, int E){
  int e0 = (blockIdx.x*blockDim.x + threadIdx.x)*4;
  if (e0 >= E) return;
  int4 a = *(const int4*)(d1+e0);
  atomicAdd(&degi[a.x],1); atomicAdd(&degi[a.y],1);
  atomicAdd(&degi[a.z],1); atomicAdd(&degi[a.w],1);
  int4 b = *(const int4*)(d2+e0);
  atomicAdd(&degi[b.x+NN],1); atomicAdd(&degi[b.y+NN],1);
  atomicAdd(&degi[b.z+NN],1); atomicAdd(&degi[b.w+NN],1);
}

// pass A: per-block (2048 elems) local exclusive scan of (deg+1), block sums
__global__ __launch_bounds__(256) void k_scan_a(const int* __restrict__ degi,
    int* __restrict__ row_ptr, int* __restrict__ blksum, int n){
  int tid = threadIdx.x, lane = tid & 63, wv = tid >> 6;
  int i0 = blockIdx.x*2048 + tid*8;
  int v[8];
  if (i0+7 < n){
    int4 a = *(const int4*)(degi+i0);
    int4 b = *(const int4*)(degi+i0+4);
    v[0]=a.x+1; v[1]=a.y+1; v[2]=a.z+1; v[3]=a.w+1;
    v[4]=b.x+1; v[5]=b.y+1; v[6]=b.z+1; v[7]=b.w+1;
  } else {
    #pragma unroll
    for (int u=0;u<8;u++) v[u] = (i0+u<n) ? degi[i0+u]+1 : 0;
  }
  int ts = 0;
  #pragma unroll
  for (int u=0;u<8;u++) ts += v[u];
  int inc = ts;
  #pragma unroll
  for (int off=1; off<64; off<<=1){
    int u = __shfl_up(inc, off);
    if (lane >= off) inc += u;
  }
  __shared__ int wsum[4];
  if (lane==63) wsum[wv] = inc;
  __syncthreads();
  int woff = 0;
  #pragma unroll
  for (int w=0; w<4; ++w) if (w < wv) woff += wsum[w];
  int run = woff + inc - ts;
  #pragma unroll
  for (int u=0;u<8;u++){ if (i0+u<n) row_ptr[i0+u] = run; run += v[u]; }
  if (tid==255) blksum[blockIdx.x] = woff + inc;
}

// pass C: add block offset, init cursor, reserve self-loop slot
__global__ __launch_bounds__(256) void k_scan_c(int* __restrict__ row_ptr,
    const int* __restrict__ blksum, int* __restrict__ cursor,
    int2* __restrict__ srt, int n){
  __shared__ int s_off;
  int tid = threadIdx.x;
  if (tid < 64){
    int v = (tid < blockIdx.x) ? blksum[tid] : 0;
    #pragma unroll
    for (int off=32; off; off>>=1) v += __shfl_xor(v, off);
    if (tid==0) s_off = v;
  }
  __syncthreads();
  int off = s_off;
  int i0 = blockIdx.x*2048 + tid*8;
  #pragma unroll
  for (int u=0; u<8; ++u){
    int i = i0+u;
    if (i < n){
      int rp = row_ptr[i] + off;
      row_ptr[i] = rp;
      cursor[i] = rp + 1;
      srt[rp] = make_int2(i, 0);     // self-loop src; .y filled by k_selfea
    }
  }
  if (tid==0 && blockIdx.x==0) row_ptr[n] = ET;
}

__global__ void k_scatter(const int* __restrict__ s1, const int* __restrict__ d1,
                          const float* __restrict__ e1,
                          const int* __restrict__ s2, const int* __restrict__ d2,
                          const float* __restrict__ e2,
                          int* __restrict__ cursor, int2* __restrict__ srt, int E){
  int e = blockIdx.x*blockDim.x + threadIdx.x;
  if (e < E){
    int da = d1[e];
    int pa = atomicAdd(&cursor[da], 1);
    srt[pa] = make_int2(s1[e], __float_as_int(e1[e]));
    int db = d2[e] + NN;
    int pb = atomicAdd(&cursor[db], 1);
    srt[pb] = make_int2(s2[e] + NN, __float_as_int(e2[e]));
  }
}

// self-loop attr = mean of segment's edge attrs (excluding the self slot)
__global__ void k_selfea(const int* __restrict__ row_ptr, int2* __restrict__ srt, int n){
  int i = blockIdx.x*blockDim.x + threadIdx.x;
  if (i < n){
    int beg = row_ptr[i], end = row_ptr[i+1];
    int deg = end - beg - 1;
    float s = 0.f;
    for (int j = beg+1; j < end; ++j) s += __int_as_float(srt[j].y);
    srt[beg].y = __float_as_int(s / fmaxf((float)deg, 1.f));
  }
}

// ce[L] = dot(We_L[0,:], a_e_L), one launch
__global__ void k_ce3(const float* __restrict__ We0, const float* __restrict__ ae0,
                      const float* __restrict__ We1, const float* __restrict__ ae1,
                      const float* __restrict__ We2, const float* __restrict__ ae2,
                      float* __restrict__ ce3){
  int l = threadIdx.x;
  const float* We[3] = {We0, We1, We2};
  const float* ae[3] = {ae0, ae1, ae2};
  const int fo[3] = {128, 128, 64};
  for (int L = 0; L < 3; ++L){
    float s = 0.f;
    for (int c = l; c < fo[L]; c += 64) s += We[L][c]*ae[L][c];
    s = wave_sum64(s);
    if (l == 0) ce3[L] = s;
  }
}

// ---- register-tiled GEMM, h written as bf16, fused hs/hd epilogue ----
template<int K, int N>
__global__ __launch_bounds__(256) void k_gemm(const float* __restrict__ x,
    const float* __restrict__ W, const float* __restrict__ a_src,
    const float* __restrict__ a_dst, unsigned short* __restrict__ h16,
    float* __restrict__ hs, float* __restrict__ hd, int n){
  constexpr int KB  = 32;
  constexpr int CG  = N/4;
  constexpr int TY  = 256/CG;
  constexpr int RPT = 64/TY;
  __shared__ float Wl[KB][N];
  __shared__ float Xt[KB][64];
  int tid = threadIdx.x;
  int tx = tid % CG, ty = tid / CG;
  int r0 = blockIdx.x * 64;
  float acc[RPT][4] = {};
  for (int k0 = 0; k0 < K; k0 += KB){
    {
      const float4* src = (const float4*)(W + (size_t)k0*N);
      float4* dst = (float4*)(&Wl[0][0]);
      #pragma unroll
      for (int i = 0; i < KB*N/1024; ++i) dst[tid + i*256] = src[tid + i*256];
    }
    {
      int rr = tid >> 3, kk0 = (tid & 7) * 4;
      #pragma unroll
      for (int it = 0; it < 2; ++it){
        int r = rr + it*32;
        int gr = r0 + r;
        float4 v = (gr < n) ? *(const float4*)(x + (size_t)gr*K + k0 + kk0)
                            : make_float4(0.f,0.f,0.f,0.f);
        Xt[kk0+0][r] = v.x; Xt[kk0+1][r] = v.y; Xt[kk0+2][r] = v.z; Xt[kk0+3][r] = v.w;
      }
    }
    __syncthreads();
    #pragma unroll
    for (int kk = 0; kk < KB; ++kk){
      float4 wv = *(const float4*)(&Wl[kk][tx*4]);
      float xv[RPT];
      #pragma unroll
      for (int i = 0; i < RPT/4; ++i)
        *(float4*)&xv[i*4] = *(const float4*)(&Xt[kk][ty*RPT + i*4]);
      #pragma unroll
      for (int i=0;i<RPT;i++){
        acc[i][0] += xv[i]*wv.x; acc[i][1] += xv[i]*wv.y;
        acc[i][2] += xv[i]*wv.z; acc[i][3] += xv[i]*wv.w;
      }
    }
    __syncthreads();
  }
  #pragma unroll
  for (int i=0;i<RPT;i++){
    int gr = r0 + ty*RPT + i;
    if (gr < n){
      unsigned r0p = (unsigned)f2bf(acc[i][0]) | ((unsigned)f2bf(acc[i][1])<<16);
      unsigned r1p = (unsigned)f2bf(acc[i][2]) | ((unsigned)f2bf(acc[i][3])<<16);
      *(uint2*)(h16 + (size_t)gr*N + tx*4) = make_uint2(r0p, r1p);
    }
  }
  float as4[4], ad4[4];
  #pragma unroll
  for (int j=0;j<4;j++){ as4[j] = a_src[tx*4+j]; ad4[j] = a_dst[tx*4+j]; }
  #pragma unroll
  for (int i=0;i<RPT;i++){
    float ps = acc[i][0]*as4[0] + acc[i][1]*as4[1] + acc[i][2]*as4[2] + acc[i][3]*as4[3];
    float pd = acc[i][0]*ad4[0] + acc[i][1]*ad4[1] + acc[i][2]*ad4[2] + acc[i][3]*ad4[3];
    #pragma unroll
    for (int off=CG/2; off; off>>=1){ ps += __shfl_xor(ps, off); pd += __shfl_xor(pd, off); }
    int gr = r0 + ty*RPT + i;
    if (tx==0 && gr < n){ hs[gr] = ps; hd[gr] = pd; }
  }
}

// layer-1 GEMM: K=7, N=128, rows from x1 (r<NN) or x2
__global__ __launch_bounds__(256) void k_gemm7(const float* __restrict__ x1,
    const float* __restrict__ x2, const float* __restrict__ W,
    const float* __restrict__ a_src, const float* __restrict__ a_dst,
    unsigned short* __restrict__ h16, float* __restrict__ hs,
    float* __restrict__ hd, int n){
  __shared__ float Wl[7][128];
  int tid = threadIdx.x;
  for (int i = tid; i < 7*128; i += 256) ((float*)Wl)[i] = W[i];
  __syncthreads();
  int tx = tid & 31, ty = tid >> 5;
  int r = blockIdx.x*8 + ty;
  if (r >= n) return;
  const float* xr = (r < NN) ? (x1 + (size_t)r*7) : (x2 + (size_t)(r-NN)*7);
  float xv[7];
  #pragma unroll
  for (int k=0;k<7;k++) xv[k] = xr[k];
  float4 s = make_float4(0.f,0.f,0.f,0.f);
  #pragma unroll
  for (int k=0;k<7;k++){
    float4 wv = *(const float4*)(&Wl[k][tx*4]);
    s.x += xv[k]*wv.x; s.y += xv[k]*wv.y; s.z += xv[k]*wv.z; s.w += xv[k]*wv.w;
  }
  unsigned r0p = (unsigned)f2bf(s.x) | ((unsigned)f2bf(s.y)<<16);
  unsigned r1p = (unsigned)f2bf(s.z) | ((unsigned)f2bf(s.w)<<16);
  *(uint2*)(h16 + (size_t)r*128 + tx*4) = make_uint2(r0p, r1p);
  float ps = s.x*a_src[tx*4] + s.y*a_src[tx*4+1] + s.z*a_src[tx*4+2] + s.w*a_src[tx*4+3];
  float pd = s.x*a_dst[tx*4] + s.y*a_dst[tx*4+1] + s.z*a_dst[tx*4+2] + s.w*a_dst[tx*4+3];
  #pragma unroll
  for (int off=16; off; off>>=1){ ps += __shfl_xor(ps, off); pd += __shfl_xor(pd, off); }
  if (tx==0){ hs[r] = ps; hd[r] = pd; }
}

// Per-node fused: alpha -> online softmax -> bf16 gather -> +b -> ELU
template<int FOUT>
__global__ __launch_bounds__(256) void k_aggregate(const unsigned short* __restrict__ h16,
    const float* __restrict__ hs, const float* __restrict__ hd,
    const int2* __restrict__ srt, const int* __restrict__ row_ptr,
    const float* __restrict__ ce_p, const float* __restrict__ b,
    float* __restrict__ xout, int n){
  __shared__ float s_p[4][64];
  __shared__ int   s_s[4][64];
  int tid = threadIdx.x;
  int wv = tid >> 6, lane = tid & 63;
  int wid = (int)((blockIdx.x*256 + tid) >> 6);
  if (wid >= n) return;                 // uniform per wave
  float ce  = *ce_p;
  int beg = row_ptr[wid], end = row_ptr[wid+1];
  float hdn = hd[wid];
  int l5 = lane & 31, half = lane >> 5;
  int d128 = 2*lane;                    // FOUT==128 column pair
  int d64  = 2*l5;                      // FOUT==64 column pair
  float m = -INFINITY, den = 0.f;
  float2 acc = make_float2(0.f, 0.f);
  for (int base = beg; base < end; base += 64){
    int slot = base + lane;
    float a = -INFINITY; int src = 0;
    if (slot < end){
      int2 pk = srt[slot];
      src = pk.x;
      a = hs[src] + hdn + __int_as_float(pk.y)*ce;
      a = (a > 0.f) ? a : 0.2f*a;                 // leaky_relu(0.2)
    }
    float cm = wave_max64(a);
    float mnew = fmaxf(m, cm);
    float scale = __expf(m - mnew);               // m==-inf -> 0
    den *= scale; acc.x *= scale; acc.y *= scale;
    float p = __expf(a - mnew);                   // invalid lanes -> 0
    den += wave_sum64(p);
    s_p[wv][lane] = p; s_s[wv][lane] = src;
    asm volatile("s_waitcnt lgkmcnt(0)" ::: "memory");  // intra-wave LDS RAW fence
    int cnt = end - base; if (cnt > 64) cnt = 64;
    if (FOUT == 128){
      int j = 0;
      for (; j + 8 <= cnt; j += 8){
        float pp[8]; unsigned hv[8];
        #pragma unroll
        for (int u=0;u<8;u++){
          pp[u]=s_p[wv][j+u];
          hv[u]=*(const unsigned*)(h16 + (size_t)s_s[wv][j+u]*128 + d128);
        }
        #pragma unroll
        for (int u=0;u<8;u++){ acc.x += pp[u]*bflo(hv[u]); acc.y += pp[u]*bfhi(hv[u]); }
      }
      for (; j < cnt; ++j){
        float p2 = s_p[wv][j];
        unsigned hv = *(const unsigned*)(h16 + (size_t)s_s[wv][j]*128 + d128);
        acc.x += p2*bflo(hv); acc.y += p2*bfhi(hv);
      }
    } else {
      int j = 0;
      for (; j + 8 <= cnt; j += 8){           // 4 steps x 2 edges
        #pragma unroll
        for (int u=0;u<4;u++){
          int jj = j + 2*u + half;
          float p2 = s_p[wv][jj];
          unsigned hv = *(const unsigned*)(h16 + (size_t)s_s[wv][jj]*64 + d64);
          acc.x += p2*bflo(hv); acc.y += p2*bfhi(hv);
        }
      }
      for (; j < cnt; j += 2){
        int jj = j + half;
        if (jj < cnt){
          float p2 = s_p[wv][jj];
          unsigned hv = *(const unsigned*)(h16 + (size_t)s_s[wv][jj]*64 + d64);
          acc.x += p2*bflo(hv); acc.y += p2*bfhi(hv);
        }
      }
    }
    m = mnew;
  }
  float inv = 1.f/den;
  if (FOUT == 128){
    float2 b2 = ((const float2*)b)[lane];
    float ox = acc.x*inv + b2.x;  ox = (ox > 0.f) ? ox : (__expf(ox) - 1.f);
    float oy = acc.y*inv + b2.y;  oy = (oy > 0.f) ? oy : (__expf(oy) - 1.f);
    ((float2*)(xout + (size_t)wid*128))[lane] = make_float2(ox, oy);
  } else {
    acc.x += __shfl_xor(acc.x, 32);
    acc.y += __shfl_xor(acc.y, 32);
    if (lane < 32){
      float2 b2 = ((const float2*)b)[l5];
      float ox = acc.x*inv + b2.x;  ox = (ox > 0.f) ? ox : (__expf(ox) - 1.f);
      float oy = acc.y*inv + b2.y;  oy = (oy > 0.f) ? oy : (__expf(oy) - 1.f);
      ((float2*)(xout + (size_t)wid*64))[l5] = make_float2(ox, oy);
    }
  }
}

// column sums over merged x[n,64]: rows<NN -> gsum[0:64], else gsum[64:128]
__global__ void k_colsum2(const float* __restrict__ x, float* __restrict__ gsum, int n){
  int lane = threadIdx.x;   // blockDim = 64
  float s1 = 0.f, s2 = 0.f;
  for (int r = blockIdx.x; r < n; r += gridDim.x){
    float v = x[(size_t)r*64 + lane];
    if (r < NN) s1 += v; else s2 += v;
  }
  atomicAdd(&gsum[lane], s1);
  atomicAdd(&gsum[64+lane], s2);
}

// final MLP head, single block of 128 threads
__global__ void k_head(const float* __restrict__ gs1, const float* __restrict__ gs2,
                       const float* __restrict__ xn1, const float* __restrict__ xn2,
                       const float* __restrict__ Wlin, const float* __restrict__ blin,
                       const float* __restrict__ Wc1, const float* __restrict__ bc1,
                       const float* __restrict__ Wc2, const float* __restrict__ bc2,
                       float* __restrict__ out){
  __shared__ float c1[80], c2[80], xcat[128], hb[16];
  int tid = threadIdx.x;
  const float invn = 1.f/(float)NN;
  if (tid < 64){ c1[tid] = gs1[tid]*invn; c2[tid] = gs2[tid]*invn; }
  else if (tid < 80){ c1[tid] = xn1[tid-64]; c2[tid] = xn2[tid-64]; }
  __syncthreads();
  if (tid < 64){
    float s = blin[tid];
    for (int k=0;k<80;k++) s += c1[k]*Wlin[k*64+tid];
    xcat[tid] = s;
  } else {
    int j = tid - 64;
    float s = blin[j];
    for (int k=0;k<80;k++) s += c2[k]*Wlin[k*64+j];
    xcat[tid] = s;
  }
  __syncthreads();
  if (tid < 16){
    float s = bc1[tid];
    for (int k=0;k<128;k++) s += xcat[k]*Wc1[k*16+tid];
    hb[tid] = fmaxf(s, 0.f);
  }
  __syncthreads();
  if (tid < 3){
    float s = bc2[tid];
    for (int k=0;k<16;k++) s += hb[k]*Wc2[k*3+tid];
    out[tid] = s;
  }
}

extern "C" void kernel_launch(void* const* d_in, const int* in_sizes, int n_in,
                              void* d_out, int out_size, void* d_ws, size_t ws_size,
                              hipStream_t stream){
  const float* x1  = (const float*)d_in[0];
  const float* x2  = (const float*)d_in[1];
  const int*   ei1 = (const int*)d_in[2];
  const int*   ei2 = (const int*)d_in[3];
  const float* xn1 = (const float*)d_in[4];
  const float* xn2 = (const float*)d_in[5];
  const float* ec1 = (const float*)d_in[6];
  const float* ec2 = (const float*)d_in[7];
  const float* W[3]    = {(const float*)d_in[8],  (const float*)d_in[14], (const float*)d_in[20]};
  const float* asrc[3] = {(const float*)d_in[9],  (const float*)d_in[15], (const float*)d_in[21]};
  const float* adst[3] = {(const float*)d_in[10], (const float*)d_in[16], (const float*)d_in[22]};
  const float* We[3]   = {(const float*)d_in[11], (const float*)d_in[17], (const float*)d_in[23]};
  const float* ae[3]   = {(const float*)d_in[12], (const float*)d_in[18], (const float*)d_in[24]};
  const float* bb[3]   = {(const float*)d_in[13], (const float*)d_in[19], (const float*)d_in[25]};
  const float* Wlin = (const float*)d_in[26];
  const float* blin = (const float*)d_in[27];
  const float* Wc1  = (const float*)d_in[28];
  const float* bc1  = (const float*)d_in[29];
  const float* Wc2  = (const float*)d_in[30];
  const float* bc2  = (const float*)d_in[31];
  float* out = (float*)d_out;

  // workspace (bytes): bufX fp32 [NT*128] | h16 bf16 [NT*128] | srt int2 [ET] | small
  char* wsb = (char*)d_ws;
  float*          bufX = (float*)wsb;                          // 51.2 MB
  unsigned short* h16  = (unsigned short*)(wsb + (size_t)NT*128*4);        // 25.6 MB
  int2*           srt  = (int2*)(wsb + (size_t)NT*128*4 + (size_t)NT*128*2); // 13.6 MB
  float* hs   = (float*)(srt + ET);               // NT
  float* hd   = hs + NT;                          // NT
  int*   degi = (int*)(hd + NT);                  // NT
  int*   row_ptr = degi + NT;                     // NT+1
  int*   cursor  = row_ptr + NT + 1;              // NT
  float* ce3  = (float*)(cursor + NT);            // 4
  float* gsum = ce3 + 4;                          // 128
  int*   blksum = (int*)(gsum + 128);             // 64

  const int* s1 = ei1,      * d1 = ei1 + NE;
  const int* s2 = ei2,      * d2 = ei2 + NE;

  hipMemsetAsync(gsum, 0, 128*sizeof(float), stream);
  k_ce3<<<1, 64, 0, stream>>>(We[0], ae[0], We[1], ae[1], We[2], ae[2], ce3);

  // merged CSR build
  hipMemsetAsync(degi, 0, NT*sizeof(int), stream);
  k_deg<<<(NE/4+255)/256, 256, 0, stream>>>(d1, d2, degi, NE);
  k_scan_a<<<SCAN_GRID, 256, 0, stream>>>(degi, row_ptr, blksum, NT);
  k_scan_c<<<SCAN_GRID, 256, 0, stream>>>(row_ptr, blksum, cursor, srt, NT);
  k_scatter<<<(NE+255)/256, 256, 0, stream>>>(s1, d1, ec1, s2, d2, ec2, cursor, srt, NE);
  k_selfea<<<(NT+255)/256, 256, 0, stream>>>(row_ptr, srt, NT);

  // layer 0
  k_gemm7<<<(NT+7)/8, 256, 0, stream>>>(x1, x2, W[0], asrc[0], adst[0], h16, hs, hd, NT);
  k_aggregate<128><<<(NT+3)/4, 256, 0, stream>>>(h16, hs, hd, srt, row_ptr, ce3+0, bb[0], bufX, NT);
  // layer 1
  k_gemm<128,128><<<(NT+63)/64, 256, 0, stream>>>(bufX, W[1], asrc[1], adst[1], h16, hs, hd, NT);
  k_aggregate<128><<<(NT+3)/4, 256, 0, stream>>>(h16, hs, hd, srt, row_ptr, ce3+1, bb[1], bufX, NT);
  // layer 2
  k_gemm<128,64><<<(NT+63)/64, 256, 0, stream>>>(bufX, W[2], asrc[2], adst[2], h16, hs, hd, NT);
  k_aggregate<64><<<(NT+3)/4, 256, 0, stream>>>(h16, hs, hd, srt, row_ptr, ce3+2, bb[2], bufX, NT);

  k_colsum2<<<256, 64, 0, stream>>>(bufX, gsum, NT);
  k_head<<<1, 128, 0, stream>>>(gsum, gsum+64, xn1, xn2, Wlin, blin, Wc1, bc1, Wc2, bc2, out);
}

// Round 7
// 590.073 us; speedup vs baseline: 2.8967x; 1.2620x over previous
//
#include <hip/hip_runtime.h>
#include <math.h>

#define NN 50000
#define NE 800000
#define NT 100000           // merged nodes (two graphs)
#define ET (2*NE + NT)      // merged CSR entries incl self loops
#define NPB 256             // nodes per bucket
#define NB 391              // ceil(NT/NPB)
#define BCH 4096            // edges per k_bin chunk
#define BCAP 5120           // k_bucket LDS edge capacity (mean 4096, sigma 64)

// ---------- helpers ----------
static __device__ __forceinline__ float wave_max64(float v){
  #pragma unroll
  for(int off=32;off;off>>=1) v = fmaxf(v, __shfl_xor(v,off));
  return v;
}
static __device__ __forceinline__ float wave_sum64(float v){
  #pragma unroll
  for(int off=32;off;off>>=1) v += __shfl_xor(v,off);
  return v;
}
// bf16 pack/unpack (RNE)
static __device__ __forceinline__ unsigned short f2bf(float f){
  unsigned u = __float_as_uint(f);
  return (unsigned short)((u + 0x7FFFu + ((u>>16)&1u)) >> 16);
}
static __device__ __forceinline__ float bflo(unsigned v){ return __uint_as_float(v<<16); }
static __device__ __forceinline__ float bfhi(unsigned v){ return __uint_as_float(v & 0xFFFF0000u); }

// ---------- bucketed CSR build ----------
// pass 1: per-bucket edge histogram (LDS-privatized)
__global__ __launch_bounds__(256) void k_hist(const int* __restrict__ d1,
    const int* __restrict__ d2, int* __restrict__ bcnt){
  __shared__ int h[512];
  int t = threadIdx.x;
  h[t] = 0; h[t+256] = 0;
  __syncthreads();
  int stride = gridDim.x*256;
  for (int e = blockIdx.x*256 + t; e < NE; e += stride){
    atomicAdd(&h[d1[e]>>8], 1);
    atomicAdd(&h[(d2[e]+NN)>>8], 1);
  }
  __syncthreads();
  if (h[t])     atomicAdd(&bcnt[t],     h[t]);
  if (h[t+256]) atomicAdd(&bcnt[t+256], h[t+256]);
}

// pass 2: exclusive scan of bcnt[512] -> hbase; also row_ptr[NT]=ET
__global__ void k_hscan(const int* __restrict__ bcnt, int* __restrict__ hbase,
                        int* __restrict__ row_ptr){
  int t = threadIdx.x;           // 256 threads, each owns entries 2t,2t+1
  int a = bcnt[2*t], b2 = bcnt[2*t+1];
  int s = a + b2;
  int lane = t & 63, wv = t >> 6;
  int inc = s;
  #pragma unroll
  for (int off=1; off<64; off<<=1){ int u = __shfl_up(inc, off); if (lane>=off) inc += u; }
  __shared__ int wsum[4];
  if (lane==63) wsum[wv] = inc;
  __syncthreads();
  int woff = 0;
  #pragma unroll
  for (int w=0; w<4; ++w) if (w < wv) woff += wsum[w];
  int excl = woff + inc - s;
  hbase[2*t] = excl; hbase[2*t+1] = excl + a;
  if (t==0) row_ptr[NT] = ET;
}

// pass 3: block-local counting sort of 4096-edge chunks, coalesced flush to
// bucket-partitioned staging. pack = src | (dst&255)<<17
__global__ __launch_bounds__(256) void k_bin(const int* __restrict__ s1,
    const int* __restrict__ d1, const float* __restrict__ e1,
    const int* __restrict__ s2, const int* __restrict__ d2,
    const float* __restrict__ e2, const int* __restrict__ hbase,
    int* __restrict__ gcur, uint2* __restrict__ gstage){
  __shared__ int cnt[512], loff[512], cur[512], gbase_sh[512];
  __shared__ uint2 sdata[BCH];
  __shared__ unsigned short sbkt[BCH];
  __shared__ int wsum[4];
  int tid = threadIdx.x;
  int e0 = blockIdx.x*BCH;
  unsigned pack[16], eab[16];
  unsigned short bk[16];
  cnt[tid] = 0; cnt[tid+256] = 0; cur[tid] = 0; cur[tid+256] = 0;
  __syncthreads();
  #pragma unroll
  for (int u=0; u<16; ++u){
    int e = e0 + u*256 + tid;
    int b = NB; unsigned p = 0, ea = 0;
    if (e < 2*NE){
      int src, dst; float eav;
      if (e < NE){ src = s1[e]; dst = d1[e]; eav = e1[e]; }
      else { int e2i = e - NE; src = s2[e2i] + NN; dst = d2[e2i] + NN; eav = e2[e2i]; }
      b = dst >> 8;
      p = (unsigned)src | ((unsigned)(dst & 255) << 17);
      ea = __float_as_uint(eav);
    }
    bk[u] = (unsigned short)b; pack[u] = p; eab[u] = ea;
    atomicAdd(&cnt[b], 1);
  }
  __syncthreads();
  // exclusive scan cnt[512] -> loff[512]
  {
    int a = cnt[2*tid], b2 = cnt[2*tid+1];
    int s = a + b2;
    int lane = tid & 63, wv = tid >> 6;
    int inc = s;
    #pragma unroll
    for (int off=1; off<64; off<<=1){ int u = __shfl_up(inc, off); if (lane>=off) inc += u; }
    if (lane==63) wsum[wv] = inc;
    __syncthreads();
    int woff = 0;
    #pragma unroll
    for (int w=0; w<4; ++w) if (w < wv) woff += wsum[w];
    int excl = woff + inc - s;
    loff[2*tid] = excl; loff[2*tid+1] = excl + a;
  }
  // reserve global staging ranges (cnt is stable)
  if (tid < NB && cnt[tid] > 0)
    gbase_sh[tid] = hbase[tid] + atomicAdd(&gcur[tid], cnt[tid]);
  if (tid+256 < NB && cnt[tid+256] > 0)
    gbase_sh[tid+256] = hbase[tid+256] + atomicAdd(&gcur[tid+256], cnt[tid+256]);
  __syncthreads();
  // place into LDS, bucket-sorted
  #pragma unroll
  for (int u=0; u<16; ++u){
    int b = bk[u];
    int p = loff[b] + atomicAdd(&cur[b], 1);
    sdata[p] = make_uint2(pack[u], eab[u]);
    sbkt[p] = (unsigned short)b;
  }
  __syncthreads();
  // coalesced flush (runs per bucket are contiguous in LDS and in global)
  for (int k = tid; k < BCH; k += 256){
    int b = sbkt[k];
    if (b < NB) gstage[gbase_sh[b] + (k - loff[b])] = sdata[k];
  }
}

// pass 4: one block per bucket -> final CSR (row_ptr, srt incl self loops)
__global__ __launch_bounds__(256) void k_bucket(const uint2* __restrict__ gstage,
    const int* __restrict__ hbase, int2* __restrict__ srt, int* __restrict__ row_ptr){
  __shared__ uint2 sd[BCAP];
  __shared__ int deg[256], rbase[256], cur[256];
  __shared__ float easum[256];
  __shared__ int wsum[4];
  int b = blockIdx.x, t = threadIdx.x;
  int lo = b*NPB;
  int nloc = min(NPB, NT - lo);
  int est = hbase[b], ecnt = hbase[b+1] - est;
  bool inlds = (ecnt <= BCAP);
  deg[t] = 0; easum[t] = 0.f;
  __syncthreads();
  for (int k = t; k < ecnt; k += 256){
    uint2 v = gstage[est + k];
    if (inlds) sd[k] = v;
    int dl = v.x >> 17;
    atomicAdd(&deg[dl], 1);
    atomicAdd(&easum[dl], __uint_as_float(v.y));
  }
  __syncthreads();
  // exclusive scan of (deg+1) over nloc entries -> final CSR bases
  int dv = (t < nloc) ? deg[t] + 1 : 0;
  int lane = t & 63, wv = t >> 6;
  int inc = dv;
  #pragma unroll
  for (int off=1; off<64; off<<=1){ int u = __shfl_up(inc, off); if (lane>=off) inc += u; }
  if (lane==63) wsum[wv] = inc;
  __syncthreads();
  int woff = 0;
  #pragma unroll
  for (int w=0; w<4; ++w) if (w < wv) woff += wsum[w];
  int gb = est + lo + (woff + inc - dv);   // hbase[b] edges + lo self slots before
  if (t < nloc){
    row_ptr[lo + t] = gb;
    rbase[t] = gb;
    cur[t] = 1;
    float se = easum[t] / fmaxf((float)deg[t], 1.f);
    srt[gb] = make_int2(lo + t, __float_as_int(se));   // self loop
  }
  __syncthreads();
  for (int k = t; k < ecnt; k += 256){
    uint2 v = inlds ? sd[k] : gstage[est + k];
    int dl = v.x >> 17;
    int pos = rbase[dl] + atomicAdd(&cur[dl], 1);
    srt[pos] = make_int2((int)(v.x & 0x1FFFFu), (int)v.y);
  }
}

// ce[L] = dot(We_L[0,:], a_e_L), one launch
__global__ void k_ce3(const float* __restrict__ We0, const float* __restrict__ ae0,
                      const float* __restrict__ We1, const float* __restrict__ ae1,
                      const float* __restrict__ We2, const float* __restrict__ ae2,
                      float* __restrict__ ce3){
  int l = threadIdx.x;
  const float* We[3] = {We0, We1, We2};
  const float* ae[3] = {ae0, ae1, ae2};
  const int fo[3] = {128, 128, 64};
  for (int L = 0; L < 3; ++L){
    float s = 0.f;
    for (int c = l; c < fo[L]; c += 64) s += We[L][c]*ae[L][c];
    s = wave_sum64(s);
    if (l == 0) ce3[L] = s;
  }
}

// ---- register-tiled GEMM, h written as bf16, fused hs/hd epilogue ----
template<int K, int N>
__global__ __launch_bounds__(256) void k_gemm(const float* __restrict__ x,
    const float* __restrict__ W, const float* __restrict__ a_src,
    const float* __restrict__ a_dst, unsigned short* __restrict__ h16,
    float* __restrict__ hs, float* __restrict__ hd, int n){
  constexpr int KB  = 32;
  constexpr int CG  = N/4;
  constexpr int TY  = 256/CG;
  constexpr int RPT = 64/TY;
  __shared__ float Wl[KB][N];
  __shared__ float Xt[KB][64];
  int tid = threadIdx.x;
  int tx = tid % CG, ty = tid / CG;
  int r0 = blockIdx.x * 64;
  float acc[RPT][4] = {};
  for (int k0 = 0; k0 < K; k0 += KB){
    {
      const float4* src = (const float4*)(W + (size_t)k0*N);
      float4* dst = (float4*)(&Wl[0][0]);
      #pragma unroll
      for (int i = 0; i < KB*N/1024; ++i) dst[tid + i*256] = src[tid + i*256];
    }
    {
      int rr = tid >> 3, kk0 = (tid & 7) * 4;
      #pragma unroll
      for (int it = 0; it < 2; ++it){
        int r = rr + it*32;
        int gr = r0 + r;
        float4 v = (gr < n) ? *(const float4*)(x + (size_t)gr*K + k0 + kk0)
                            : make_float4(0.f,0.f,0.f,0.f);
        Xt[kk0+0][r] = v.x; Xt[kk0+1][r] = v.y; Xt[kk0+2][r] = v.z; Xt[kk0+3][r] = v.w;
      }
    }
    __syncthreads();
    #pragma unroll
    for (int kk = 0; kk < KB; ++kk){
      float4 wv = *(const float4*)(&Wl[kk][tx*4]);
      float xv[RPT];
      #pragma unroll
      for (int i = 0; i < RPT/4; ++i)
        *(float4*)&xv[i*4] = *(const float4*)(&Xt[kk][ty*RPT + i*4]);
      #pragma unroll
      for (int i=0;i<RPT;i++){
        acc[i][0] += xv[i]*wv.x; acc[i][1] += xv[i]*wv.y;
        acc[i][2] += xv[i]*wv.z; acc[i][3] += xv[i]*wv.w;
      }
    }
    __syncthreads();
  }
  #pragma unroll
  for (int i=0;i<RPT;i++){
    int gr = r0 + ty*RPT + i;
    if (gr < n){
      unsigned r0p = (unsigned)f2bf(acc[i][0]) | ((unsigned)f2bf(acc[i][1])<<16);
      unsigned r1p = (unsigned)f2bf(acc[i][2]) | ((unsigned)f2bf(acc[i][3])<<16);
      *(uint2*)(h16 + (size_t)gr*N + tx*4) = make_uint2(r0p, r1p);
    }
  }
  float as4[4], ad4[4];
  #pragma unroll
  for (int j=0;j<4;j++){ as4[j] = a_src[tx*4+j]; ad4[j] = a_dst[tx*4+j]; }
  #pragma unroll
  for (int i=0;i<RPT;i++){
    float ps = acc[i][0]*as4[0] + acc[i][1]*as4[1] + acc[i][2]*as4[2] + acc[i][3]*as4[3];
    float pd = acc[i][0]*ad4[0] + acc[i][1]*ad4[1] + acc[i][2]*ad4[2] + acc[i][3]*ad4[3];
    #pragma unroll
    for (int off=CG/2; off; off>>=1){ ps += __shfl_xor(ps, off); pd += __shfl_xor(pd, off); }
    int gr = r0 + ty*RPT + i;
    if (tx==0 && gr < n){ hs[gr] = ps; hd[gr] = pd; }
  }
}

// layer-1 GEMM: K=7, N=128, rows from x1 (r<NN) or x2
__global__ __launch_bounds__(256) void k_gemm7(const float* __restrict__ x1,
    const float* __restrict__ x2, const float* __restrict__ W,
    const float* __restrict__ a_src, const float* __restrict__ a_dst,
    unsigned short* __restrict__ h16, float* __restrict__ hs,
    float* __restrict__ hd, int n){
  __shared__ float Wl[7][128];
  int tid = threadIdx.x;
  for (int i = tid; i < 7*128; i += 256) ((float*)Wl)[i] = W[i];
  __syncthreads();
  int tx = tid & 31, ty = tid >> 5;
  int r = blockIdx.x*8 + ty;
  if (r >= n) return;
  const float* xr = (r < NN) ? (x1 + (size_t)r*7) : (x2 + (size_t)(r-NN)*7);
  float xv[7];
  #pragma unroll
  for (int k=0;k<7;k++) xv[k] = xr[k];
  float4 s = make_float4(0.f,0.f,0.f,0.f);
  #pragma unroll
  for (int k=0;k<7;k++){
    float4 wv = *(const float4*)(&Wl[k][tx*4]);
    s.x += xv[k]*wv.x; s.y += xv[k]*wv.y; s.z += xv[k]*wv.z; s.w += xv[k]*wv.w;
  }
  unsigned r0p = (unsigned)f2bf(s.x) | ((unsigned)f2bf(s.y)<<16);
  unsigned r1p = (unsigned)f2bf(s.z) | ((unsigned)f2bf(s.w)<<16);
  *(uint2*)(h16 + (size_t)r*128 + tx*4) = make_uint2(r0p, r1p);
  float ps = s.x*a_src[tx*4] + s.y*a_src[tx*4+1] + s.z*a_src[tx*4+2] + s.w*a_src[tx*4+3];
  float pd = s.x*a_dst[tx*4] + s.y*a_dst[tx*4+1] + s.z*a_dst[tx*4+2] + s.w*a_dst[tx*4+3];
  #pragma unroll
  for (int off=16; off; off>>=1){ ps += __shfl_xor(ps, off); pd += __shfl_xor(pd, off); }
  if (tx==0){ hs[r] = ps; hd[r] = pd; }
}

// Per-node fused: alpha -> online softmax -> bf16 gather -> +b -> ELU
template<int FOUT>
__global__ __launch_bounds__(256) void k_aggregate(const unsigned short* __restrict__ h16,
    const float* __restrict__ hs, const float* __restrict__ hd,
    const int2* __restrict__ srt, const int* __restrict__ row_ptr,
    const float* __restrict__ ce_p, const float* __restrict__ b,
    float* __restrict__ xout, int n){
  __shared__ float s_p[4][64];
  __shared__ int   s_s[4][64];
  int tid = threadIdx.x;
  int wv = tid >> 6, lane = tid & 63;
  int wid = (int)((blockIdx.x*256 + tid) >> 6);
  if (wid >= n) return;                 // uniform per wave
  float ce  = *ce_p;
  int beg = row_ptr[wid], end = row_ptr[wid+1];
  float hdn = hd[wid];
  int l5 = lane & 31, half = lane >> 5;
  int d128 = 2*lane;
  int d64  = 2*l5;
  float m = -INFINITY, den = 0.f;
  float2 acc = make_float2(0.f, 0.f);
  for (int base = beg; base < end; base += 64){
    int slot = base + lane;
    float a = -INFINITY; int src = 0;
    if (slot < end){
      int2 pk = srt[slot];
      src = pk.x;
      a = hs[src] + hdn + __int_as_float(pk.y)*ce;
      a = (a > 0.f) ? a : 0.2f*a;                 // leaky_relu(0.2)
    }
    float cm = wave_max64(a);
    float mnew = fmaxf(m, cm);
    float scale = __expf(m - mnew);               // m==-inf -> 0
    den *= scale; acc.x *= scale; acc.y *= scale;
    float p = __expf(a - mnew);                   // invalid lanes -> 0
    den += wave_sum64(p);
    s_p[wv][lane] = p; s_s[wv][lane] = src;
    asm volatile("s_waitcnt lgkmcnt(0)" ::: "memory");  // intra-wave LDS RAW fence
    int cnt = end - base; if (cnt > 64) cnt = 64;
    if (FOUT == 128){
      int j = 0;
      for (; j + 8 <= cnt; j += 8){
        float pp[8]; unsigned hv[8];
        #pragma unroll
        for (int u=0;u<8;u++){
          pp[u]=s_p[wv][j+u];
          hv[u]=*(const unsigned*)(h16 + (size_t)s_s[wv][j+u]*128 + d128);
        }
        #pragma unroll
        for (int u=0;u<8;u++){ acc.x += pp[u]*bflo(hv[u]); acc.y += pp[u]*bfhi(hv[u]); }
      }
      for (; j < cnt; ++j){
        float p2 = s_p[wv][j];
        unsigned hv = *(const unsigned*)(h16 + (size_t)s_s[wv][j]*128 + d128);
        acc.x += p2*bflo(hv); acc.y += p2*bfhi(hv);
      }
    } else {
      int j = 0;
      for (; j + 8 <= cnt; j += 8){
        #pragma unroll
        for (int u=0;u<4;u++){
          int jj = j + 2*u + half;
          float p2 = s_p[wv][jj];
          unsigned hv = *(const unsigned*)(h16 + (size_t)s_s[wv][jj]*64 + d64);
          acc.x += p2*bflo(hv); acc.y += p2*bfhi(hv);
        }
      }
      for (; j < cnt; j += 2){
        int jj = j + half;
        if (jj < cnt){
          float p2 = s_p[wv][jj];
          unsigned hv = *(const unsigned*)(h16 + (size_t)s_s[wv][jj]*64 + d64);
          acc.x += p2*bflo(hv); acc.y += p2*bfhi(hv);
        }
      }
    }
    m = mnew;
  }
  float inv = 1.f/den;
  if (FOUT == 128){
    float2 b2 = ((const float2*)b)[lane];
    float ox = acc.x*inv + b2.x;  ox = (ox > 0.f) ? ox : (__expf(ox) - 1.f);
    float oy = acc.y*inv + b2.y;  oy = (oy > 0.f) ? oy : (__expf(oy) - 1.f);
    ((float2*)(xout + (size_t)wid*128))[lane] = make_float2(ox, oy);
  } else {
    acc.x += __shfl_xor(acc.x, 32);
    acc.y += __shfl_xor(acc.y, 32);
    if (lane < 32){
      float2 b2 = ((const float2*)b)[l5];
      float ox = acc.x*inv + b2.x;  ox = (ox > 0.f) ? ox : (__expf(ox) - 1.f);
      float oy = acc.y*inv + b2.y;  oy = (oy > 0.f) ? oy : (__expf(oy) - 1.f);
      ((float2*)(xout + (size_t)wid*64))[l5] = make_float2(ox, oy);
    }
  }
}

// column sums over merged x[n,64]: rows<NN -> gsum[0:64], else gsum[64:128]
__global__ void k_colsum2(const float* __restrict__ x, float* __restrict__ gsum, int n){
  int lane = threadIdx.x;   // blockDim = 64
  float s1 = 0.f, s2 = 0.f;
  for (int r = blockIdx.x; r < n; r += gridDim.x){
    float v = x[(size_t)r*64 + lane];
    if (r < NN) s1 += v; else s2 += v;
  }
  atomicAdd(&gsum[lane], s1);
  atomicAdd(&gsum[64+lane], s2);
}

// final MLP head, single block of 128 threads
__global__ void k_head(const float* __restrict__ gs1, const float* __restrict__ gs2,
                       const float* __restrict__ xn1, const float* __restrict__ xn2,
                       const float* __restrict__ Wlin, const float* __restrict__ blin,
                       const float* __restrict__ Wc1, const float* __restrict__ bc1,
                       const float* __restrict__ Wc2, const float* __restrict__ bc2,
                       float* __restrict__ out){
  __shared__ float c1[80], c2[80], xcat[128], hb[16];
  int tid = threadIdx.x;
  const float invn = 1.f/(float)NN;
  if (tid < 64){ c1[tid] = gs1[tid]*invn; c2[tid] = gs2[tid]*invn; }
  else if (tid < 80){ c1[tid] = xn1[tid-64]; c2[tid] = xn2[tid-64]; }
  __syncthreads();
  if (tid < 64){
    float s = blin[tid];
    for (int k=0;k<80;k++) s += c1[k]*Wlin[k*64+tid];
    xcat[tid] = s;
  } else {
    int j = tid - 64;
    float s = blin[j];
    for (int k=0;k<80;k++) s += c2[k]*Wlin[k*64+j];
    xcat[tid] = s;
  }
  __syncthreads();
  if (tid < 16){
    float s = bc1[tid];
    for (int k=0;k<128;k++) s += xcat[k]*Wc1[k*16+tid];
    hb[tid] = fmaxf(s, 0.f);
  }
  __syncthreads();
  if (tid < 3){
    float s = bc2[tid];
    for (int k=0;k<16;k++) s += hb[k]*Wc2[k*3+tid];
    out[tid] = s;
  }
}

extern "C" void kernel_launch(void* const* d_in, const int* in_sizes, int n_in,
                              void* d_out, int out_size, void* d_ws, size_t ws_size,
                              hipStream_t stream){
  const float* x1  = (const float*)d_in[0];
  const float* x2  = (const float*)d_in[1];
  const int*   ei1 = (const int*)d_in[2];
  const int*   ei2 = (const int*)d_in[3];
  const float* xn1 = (const float*)d_in[4];
  const float* xn2 = (const float*)d_in[5];
  const float* ec1 = (const float*)d_in[6];
  const float* ec2 = (const float*)d_in[7];
  const float* W[3]    = {(const float*)d_in[8],  (const float*)d_in[14], (const float*)d_in[20]};
  const float* asrc[3] = {(const float*)d_in[9],  (const float*)d_in[15], (const float*)d_in[21]};
  const float* adst[3] = {(const float*)d_in[10], (const float*)d_in[16], (const float*)d_in[22]};
  const float* We[3]   = {(const float*)d_in[11], (const float*)d_in[17], (const float*)d_in[23]};
  const float* ae[3]   = {(const float*)d_in[12], (const float*)d_in[18], (const float*)d_in[24]};
  const float* bb[3]   = {(const float*)d_in[13], (const float*)d_in[19], (const float*)d_in[25]};
  const float* Wlin = (const float*)d_in[26];
  const float* blin = (const float*)d_in[27];
  const float* Wc1  = (const float*)d_in[28];
  const float* bc1  = (const float*)d_in[29];
  const float* Wc2  = (const float*)d_in[30];
  const float* bc2  = (const float*)d_in[31];
  float* out = (float*)d_out;

  // workspace: bufX fp32 [NT*128] (aliased as gstage during CSR build) |
  //            h16 bf16 [NT*128] | srt int2 [ET] | small
  char* wsb = (char*)d_ws;
  float*          bufX = (float*)wsb;                                        // 51.2 MB
  uint2*          gstage = (uint2*)wsb;                                      // 12.8 MB alias
  unsigned short* h16  = (unsigned short*)(wsb + (size_t)NT*128*4);          // 25.6 MB
  int2*           srt  = (int2*)(wsb + (size_t)NT*128*4 + (size_t)NT*128*2); // 13.6 MB
  float* hs   = (float*)(srt + ET);               // NT
  float* hd   = hs + NT;                          // NT
  int*   row_ptr = (int*)(hd + NT);               // NT+1
  int*   bcnt  = row_ptr + NT + 2;                // 512 (zeroed)
  int*   gcur  = bcnt + 512;                      // 512 (zeroed)
  float* gsum  = (float*)(gcur + 512);            // 128 (zeroed)
  int*   hbase = (int*)(gsum + 128);              // 513
  float* ce3   = (float*)(hbase + 513);           // 4

  const int* s1 = ei1, * d1 = ei1 + NE;
  const int* s2 = ei2, * d2 = ei2 + NE;

  hipMemsetAsync(bcnt, 0, (512+512+128)*sizeof(int), stream);  // bcnt|gcur|gsum
  k_ce3<<<1, 64, 0, stream>>>(We[0], ae[0], We[1], ae[1], We[2], ae[2], ce3);

  // bucketed CSR build
  k_hist<<<256, 256, 0, stream>>>(d1, d2, bcnt);
  k_hscan<<<1, 256, 0, stream>>>(bcnt, hbase, row_ptr);
  k_bin<<<(2*NE + BCH - 1)/BCH, 256, 0, stream>>>(s1, d1, ec1, s2, d2, ec2, hbase, gcur, gstage);
  k_bucket<<<NB, 256, 0, stream>>>(gstage, hbase, srt, row_ptr);

  // layer 0
  k_gemm7<<<(NT+7)/8, 256, 0, stream>>>(x1, x2, W[0], asrc[0], adst[0], h16, hs, hd, NT);
  k_aggregate<128><<<(NT+3)/4, 256, 0, stream>>>(h16, hs, hd, srt, row_ptr, ce3+0, bb[0], bufX, NT);
  // layer 1
  k_gemm<128,128><<<(NT+63)/64, 256, 0, stream>>>(bufX, W[1], asrc[1], adst[1], h16, hs, hd, NT);
  k_aggregate<128><<<(NT+3)/4, 256, 0, stream>>>(h16, hs, hd, srt, row_ptr, ce3+1, bb[1], bufX, NT);
  // layer 2
  k_gemm<128,64><<<(NT+63)/64, 256, 0, stream>>>(bufX, W[2], asrc[2], adst[2], h16, hs, hd, NT);
  k_aggregate<64><<<(NT+3)/4, 256, 0, stream>>>(h16, hs, hd, srt, row_ptr, ce3+2, bb[2], bufX, NT);

  k_colsum2<<<256, 64, 0, stream>>>(bufX, gsum, NT);
  k_head<<<1, 128, 0, stream>>>(gsum, gsum+64, xn1, xn2, Wlin, blin, Wc1, bc1, Wc2, bc2, out);
}

// Round 8
// 520.629 us; speedup vs baseline: 3.2831x; 1.1334x over previous
//
#include <hip/hip_runtime.h>
#include <math.h>

#define NN 50000
#define NE 800000
#define NT 100000           // merged nodes (two graphs)
#define ET (2*NE + NT)      // merged CSR entries incl self loops
#define NPB 256             // nodes per bucket
#define NB 391              // ceil(NT/NPB)
#define BCH 4096            // edges per k_bin chunk
#define BCAP 5120           // k_bucket LDS edge capacity (mean 4096, sigma 64)

// ---------- helpers ----------
static __device__ __forceinline__ float wave_max64(float v){
  #pragma unroll
  for(int off=32;off;off>>=1) v = fmaxf(v, __shfl_xor(v,off));
  return v;
}
static __device__ __forceinline__ float wave_sum64(float v){
  #pragma unroll
  for(int off=32;off;off>>=1) v += __shfl_xor(v,off);
  return v;
}
// bf16 pack/unpack (RNE)
static __device__ __forceinline__ unsigned short f2bf(float f){
  unsigned u = __float_as_uint(f);
  return (unsigned short)((u + 0x7FFFu + ((u>>16)&1u)) >> 16);
}
static __device__ __forceinline__ float bflo(unsigned v){ return __uint_as_float(v<<16); }
static __device__ __forceinline__ float bfhi(unsigned v){ return __uint_as_float(v & 0xFFFF0000u); }

// ---------- bucketed CSR build ----------
// pass 1: per-bucket edge histogram (LDS-privatized)
__global__ __launch_bounds__(256) void k_hist(const int* __restrict__ d1,
    const int* __restrict__ d2, int* __restrict__ bcnt){
  __shared__ int h[512];
  int t = threadIdx.x;
  h[t] = 0; h[t+256] = 0;
  __syncthreads();
  int stride = gridDim.x*256;
  for (int e = blockIdx.x*256 + t; e < NE; e += stride){
    atomicAdd(&h[d1[e]>>8], 1);
    atomicAdd(&h[(d2[e]+NN)>>8], 1);
  }
  __syncthreads();
  if (h[t])     atomicAdd(&bcnt[t],     h[t]);
  if (h[t+256]) atomicAdd(&bcnt[t+256], h[t+256]);
}

// pass 2: exclusive scan of bcnt[512] -> hbase; also row_ptr[NT]=ET
__global__ void k_hscan(const int* __restrict__ bcnt, int* __restrict__ hbase,
                        int* __restrict__ row_ptr){
  int t = threadIdx.x;           // 256 threads, each owns entries 2t,2t+1
  int a = bcnt[2*t], b2 = bcnt[2*t+1];
  int s = a + b2;
  int lane = t & 63, wv = t >> 6;
  int inc = s;
  #pragma unroll
  for (int off=1; off<64; off<<=1){ int u = __shfl_up(inc, off); if (lane>=off) inc += u; }
  __shared__ int wsum[4];
  if (lane==63) wsum[wv] = inc;
  __syncthreads();
  int woff = 0;
  #pragma unroll
  for (int w=0; w<4; ++w) if (w < wv) woff += wsum[w];
  int excl = woff + inc - s;
  hbase[2*t] = excl; hbase[2*t+1] = excl + a;
  if (t==0) row_ptr[NT] = ET;
}

// pass 3: block-local counting sort of 4096-edge chunks, coalesced flush to
// bucket-partitioned staging. pack = src | (dst&255)<<17
__global__ __launch_bounds__(256) void k_bin(const int* __restrict__ s1,
    const int* __restrict__ d1, const float* __restrict__ e1,
    const int* __restrict__ s2, const int* __restrict__ d2,
    const float* __restrict__ e2, const int* __restrict__ hbase,
    int* __restrict__ gcur, uint2* __restrict__ gstage){
  __shared__ int cnt[512], loff[512], cur[512], gbase_sh[512];
  __shared__ uint2 sdata[BCH];
  __shared__ unsigned short sbkt[BCH];
  __shared__ int wsum[4];
  int tid = threadIdx.x;
  int e0 = blockIdx.x*BCH;
  unsigned pack[16], eab[16];
  unsigned short bk[16];
  cnt[tid] = 0; cnt[tid+256] = 0; cur[tid] = 0; cur[tid+256] = 0;
  __syncthreads();
  #pragma unroll
  for (int u=0; u<16; ++u){
    int e = e0 + u*256 + tid;
    int b = NB; unsigned p = 0, ea = 0;
    if (e < 2*NE){
      int src, dst; float eav;
      if (e < NE){ src = s1[e]; dst = d1[e]; eav = e1[e]; }
      else { int e2i = e - NE; src = s2[e2i] + NN; dst = d2[e2i] + NN; eav = e2[e2i]; }
      b = dst >> 8;
      p = (unsigned)src | ((unsigned)(dst & 255) << 17);
      ea = __float_as_uint(eav);
    }
    bk[u] = (unsigned short)b; pack[u] = p; eab[u] = ea;
    atomicAdd(&cnt[b], 1);
  }
  __syncthreads();
  // exclusive scan cnt[512] -> loff[512]
  {
    int a = cnt[2*tid], b2 = cnt[2*tid+1];
    int s = a + b2;
    int lane = tid & 63, wv = tid >> 6;
    int inc = s;
    #pragma unroll
    for (int off=1; off<64; off<<=1){ int u = __shfl_up(inc, off); if (lane>=off) inc += u; }
    if (lane==63) wsum[wv] = inc;
    __syncthreads();
    int woff = 0;
    #pragma unroll
    for (int w=0; w<4; ++w) if (w < wv) woff += wsum[w];
    int excl = woff + inc - s;
    loff[2*tid] = excl; loff[2*tid+1] = excl + a;
  }
  // reserve global staging ranges (cnt is stable)
  if (tid < NB && cnt[tid] > 0)
    gbase_sh[tid] = hbase[tid] + atomicAdd(&gcur[tid], cnt[tid]);
  if (tid+256 < NB && cnt[tid+256] > 0)
    gbase_sh[tid+256] = hbase[tid+256] + atomicAdd(&gcur[tid+256], cnt[tid+256]);
  __syncthreads();
  // place into LDS, bucket-sorted
  #pragma unroll
  for (int u=0; u<16; ++u){
    int b = bk[u];
    int p = loff[b] + atomicAdd(&cur[b], 1);
    sdata[p] = make_uint2(pack[u], eab[u]);
    sbkt[p] = (unsigned short)b;
  }
  __syncthreads();
  // coalesced flush (runs per bucket are contiguous in LDS and in global)
  for (int k = tid; k < BCH; k += 256){
    int b = sbkt[k];
    if (b < NB) gstage[gbase_sh[b] + (k - loff[b])] = sdata[k];
  }
}

// pass 4: one block per bucket -> final CSR (row_ptr, srt incl self loops)
__global__ __launch_bounds__(256) void k_bucket(const uint2* __restrict__ gstage,
    const int* __restrict__ hbase, int2* __restrict__ srt, int* __restrict__ row_ptr){
  __shared__ uint2 sd[BCAP];
  __shared__ int deg[256], rbase[256], cur[256];
  __shared__ float easum[256];
  __shared__ int wsum[4];
  int b = blockIdx.x, t = threadIdx.x;
  int lo = b*NPB;
  int nloc = min(NPB, NT - lo);
  int est = hbase[b], ecnt = hbase[b+1] - est;
  bool inlds = (ecnt <= BCAP);
  deg[t] = 0; easum[t] = 0.f;
  __syncthreads();
  for (int k = t; k < ecnt; k += 256){
    uint2 v = gstage[est + k];
    if (inlds) sd[k] = v;
    int dl = v.x >> 17;
    atomicAdd(&deg[dl], 1);
    atomicAdd(&easum[dl], __uint_as_float(v.y));
  }
  __syncthreads();
  // exclusive scan of (deg+1) over nloc entries -> final CSR bases
  int dv = (t < nloc) ? deg[t] + 1 : 0;
  int lane = t & 63, wv = t >> 6;
  int inc = dv;
  #pragma unroll
  for (int off=1; off<64; off<<=1){ int u = __shfl_up(inc, off); if (lane>=off) inc += u; }
  if (lane==63) wsum[wv] = inc;
  __syncthreads();
  int woff = 0;
  #pragma unroll
  for (int w=0; w<4; ++w) if (w < wv) woff += wsum[w];
  int gb = est + lo + (woff + inc - dv);   // hbase[b] edges + lo self slots before
  if (t < nloc){
    row_ptr[lo + t] = gb;
    rbase[t] = gb;
    cur[t] = 1;
    float se = easum[t] / fmaxf((float)deg[t], 1.f);
    srt[gb] = make_int2(lo + t, __float_as_int(se));   // self loop
  }
  __syncthreads();
  for (int k = t; k < ecnt; k += 256){
    uint2 v = inlds ? sd[k] : gstage[est + k];
    int dl = v.x >> 17;
    int pos = rbase[dl] + atomicAdd(&cur[dl], 1);
    srt[pos] = make_int2((int)(v.x & 0x1FFFFu), (int)v.y);
  }
}

// ce[L] = dot(We_L[0,:], a_e_L), one launch
__global__ void k_ce3(const float* __restrict__ We0, const float* __restrict__ ae0,
                      const float* __restrict__ We1, const float* __restrict__ ae1,
                      const float* __restrict__ We2, const float* __restrict__ ae2,
                      float* __restrict__ ce3){
  int l = threadIdx.x;
  const float* We[3] = {We0, We1, We2};
  const float* ae[3] = {ae0, ae1, ae2};
  const int fo[3] = {128, 128, 64};
  for (int L = 0; L < 3; ++L){
    float s = 0.f;
    for (int c = l; c < fo[L]; c += 64) s += We[L][c]*ae[L][c];
    s = wave_sum64(s);
    if (l == 0) ce3[L] = s;
  }
}

// ---- register-tiled GEMM, h written as bf16, fused hs/hd epilogue ----
template<int K, int N>
__global__ __launch_bounds__(256) void k_gemm(const float* __restrict__ x,
    const float* __restrict__ W, const float* __restrict__ a_src,
    const float* __restrict__ a_dst, unsigned short* __restrict__ h16,
    float* __restrict__ hs, float* __restrict__ hd, int n){
  constexpr int KB  = 32;
  constexpr int CG  = N/4;
  constexpr int TY  = 256/CG;
  constexpr int RPT = 64/TY;
  __shared__ float Wl[KB][N];
  __shared__ float Xt[KB][64];
  int tid = threadIdx.x;
  int tx = tid % CG, ty = tid / CG;
  int r0 = blockIdx.x * 64;
  float acc[RPT][4] = {};
  for (int k0 = 0; k0 < K; k0 += KB){
    {
      const float4* src = (const float4*)(W + (size_t)k0*N);
      float4* dst = (float4*)(&Wl[0][0]);
      #pragma unroll
      for (int i = 0; i < KB*N/1024; ++i) dst[tid + i*256] = src[tid + i*256];
    }
    {
      int rr = tid >> 3, kk0 = (tid & 7) * 4;
      #pragma unroll
      for (int it = 0; it < 2; ++it){
        int r = rr + it*32;
        int gr = r0 + r;
        float4 v = (gr < n) ? *(const float4*)(x + (size_t)gr*K + k0 + kk0)
                            : make_float4(0.f,0.f,0.f,0.f);
        Xt[kk0+0][r] = v.x; Xt[kk0+1][r] = v.y; Xt[kk0+2][r] = v.z; Xt[kk0+3][r] = v.w;
      }
    }
    __syncthreads();
    #pragma unroll
    for (int kk = 0; kk < KB; ++kk){
      float4 wv = *(const float4*)(&Wl[kk][tx*4]);
      float xv[RPT];
      #pragma unroll
      for (int i = 0; i < RPT/4; ++i)
        *(float4*)&xv[i*4] = *(const float4*)(&Xt[kk][ty*RPT + i*4]);
      #pragma unroll
      for (int i=0;i<RPT;i++){
        acc[i][0] += xv[i]*wv.x; acc[i][1] += xv[i]*wv.y;
        acc[i][2] += xv[i]*wv.z; acc[i][3] += xv[i]*wv.w;
      }
    }
    __syncthreads();
  }
  #pragma unroll
  for (int i=0;i<RPT;i++){
    int gr = r0 + ty*RPT + i;
    if (gr < n){
      unsigned r0p = (unsigned)f2bf(acc[i][0]) | ((unsigned)f2bf(acc[i][1])<<16);
      unsigned r1p = (unsigned)f2bf(acc[i][2]) | ((unsigned)f2bf(acc[i][3])<<16);
      *(uint2*)(h16 + (size_t)gr*N + tx*4) = make_uint2(r0p, r1p);
    }
  }
  float as4[4], ad4[4];
  #pragma unroll
  for (int j=0;j<4;j++){ as4[j] = a_src[tx*4+j]; ad4[j] = a_dst[tx*4+j]; }
  #pragma unroll
  for (int i=0;i<RPT;i++){
    float ps = acc[i][0]*as4[0] + acc[i][1]*as4[1] + acc[i][2]*as4[2] + acc[i][3]*as4[3];
    float pd = acc[i][0]*ad4[0] + acc[i][1]*ad4[1] + acc[i][2]*ad4[2] + acc[i][3]*ad4[3];
    #pragma unroll
    for (int off=CG/2; off; off>>=1){ ps += __shfl_xor(ps, off); pd += __shfl_xor(pd, off); }
    int gr = r0 + ty*RPT + i;
    if (tx==0 && gr < n){ hs[gr] = ps; hd[gr] = pd; }
  }
}

// layer-1 GEMM: K=7, N=128, rows from x1 (r<NN) or x2
__global__ __launch_bounds__(256) void k_gemm7(const float* __restrict__ x1,
    const float* __restrict__ x2, const float* __restrict__ W,
    const float* __restrict__ a_src, const float* __restrict__ a_dst,
    unsigned short* __restrict__ h16, float* __restrict__ hs,
    float* __restrict__ hd, int n){
  __shared__ float Wl[7][128];
  int tid = threadIdx.x;
  for (int i = tid; i < 7*128; i += 256) ((float*)Wl)[i] = W[i];
  __syncthreads();
  int tx = tid & 31, ty = tid >> 5;
  int r = blockIdx.x*8 + ty;
  if (r >= n) return;
  const float* xr = (r < NN) ? (x1 + (size_t)r*7) : (x2 + (size_t)(r-NN)*7);
  float xv[7];
  #pragma unroll
  for (int k=0;k<7;k++) xv[k] = xr[k];
  float4 s = make_float4(0.f,0.f,0.f,0.f);
  #pragma unroll
  for (int k=0;k<7;k++){
    float4 wv = *(const float4*)(&Wl[k][tx*4]);
    s.x += xv[k]*wv.x; s.y += xv[k]*wv.y; s.z += xv[k]*wv.z; s.w += xv[k]*wv.w;
  }
  unsigned r0p = (unsigned)f2bf(s.x) | ((unsigned)f2bf(s.y)<<16);
  unsigned r1p = (unsigned)f2bf(s.z) | ((unsigned)f2bf(s.w)<<16);
  *(uint2*)(h16 + (size_t)r*128 + tx*4) = make_uint2(r0p, r1p);
  float ps = s.x*a_src[tx*4] + s.y*a_src[tx*4+1] + s.z*a_src[tx*4+2] + s.w*a_src[tx*4+3];
  float pd = s.x*a_dst[tx*4] + s.y*a_dst[tx*4+1] + s.z*a_dst[tx*4+2] + s.w*a_dst[tx*4+3];
  #pragma unroll
  for (int off=16; off; off>>=1){ ps += __shfl_xor(ps, off); pd += __shfl_xor(pd, off); }
  if (tx==0){ hs[r] = ps; hd[r] = pd; }
}

// Per-node fused: alpha -> online softmax -> bf16 gather -> +b -> ELU
template<int FOUT>
__global__ __launch_bounds__(256) void k_aggregate(const unsigned short* __restrict__ h16,
    const float* __restrict__ hs, const float* __restrict__ hd,
    const int2* __restrict__ srt, const int* __restrict__ row_ptr,
    const float* __restrict__ ce_p, const float* __restrict__ b,
    float* __restrict__ xout, int n){
  __shared__ float s_p[4][64];
  __shared__ int   s_s[4][64];
  int tid = threadIdx.x;
  int wv = tid >> 6, lane = tid & 63;
  int wid = (int)((blockIdx.x*256 + tid) >> 6);
  if (wid >= n) return;                 // uniform per wave
  float ce  = *ce_p;
  int beg = row_ptr[wid], end = row_ptr[wid+1];
  float hdn = hd[wid];
  int l5 = lane & 31, half = lane >> 5;
  int d128 = 2*lane;
  int d64  = 2*l5;
  float m = -INFINITY, den = 0.f;
  float2 acc = make_float2(0.f, 0.f);
  for (int base = beg; base < end; base += 64){
    int slot = base + lane;
    float a = -INFINITY; int src = 0;
    if (slot < end){
      int2 pk = srt[slot];
      src = pk.x;
      a = hs[src] + hdn + __int_as_float(pk.y)*ce;
      a = (a > 0.f) ? a : 0.2f*a;                 // leaky_relu(0.2)
    }
    float cm = wave_max64(a);
    float mnew = fmaxf(m, cm);
    float scale = __expf(m - mnew);               // m==-inf -> 0
    den *= scale; acc.x *= scale; acc.y *= scale;
    float p = __expf(a - mnew);                   // invalid lanes -> 0
    den += wave_sum64(p);
    s_p[wv][lane] = p; s_s[wv][lane] = src;
    asm volatile("s_waitcnt lgkmcnt(0)" ::: "memory");  // intra-wave LDS RAW fence
    int cnt = end - base; if (cnt > 64) cnt = 64;
    if (FOUT == 128){
      int j = 0;
      for (; j + 8 <= cnt; j += 8){
        float pp[8]; unsigned hv[8];
        #pragma unroll
        for (int u=0;u<8;u++){
          pp[u]=s_p[wv][j+u];
          hv[u]=*(const unsigned*)(h16 + (size_t)s_s[wv][j+u]*128 + d128);
        }
        #pragma unroll
        for (int u=0;u<8;u++){ acc.x += pp[u]*bflo(hv[u]); acc.y += pp[u]*bfhi(hv[u]); }
      }
      for (; j < cnt; ++j){
        float p2 = s_p[wv][j];
        unsigned hv = *(const unsigned*)(h16 + (size_t)s_s[wv][j]*128 + d128);
        acc.x += p2*bflo(hv); acc.y += p2*bfhi(hv);
      }
    } else {
      int j = 0;
      for (; j + 8 <= cnt; j += 8){
        #pragma unroll
        for (int u=0;u<4;u++){
          int jj = j + 2*u + half;
          float p2 = s_p[wv][jj];
          unsigned hv = *(const unsigned*)(h16 + (size_t)s_s[wv][jj]*64 + d64);
          acc.x += p2*bflo(hv); acc.y += p2*bfhi(hv);
        }
      }
      for (; j < cnt; j += 2){
        int jj = j + half;
        if (jj < cnt){
          float p2 = s_p[wv][jj];
          unsigned hv = *(const unsigned*)(h16 + (size_t)s_s[wv][jj]*64 + d64);
          acc.x += p2*bflo(hv); acc.y += p2*bfhi(hv);
        }
      }
    }
    m = mnew;
  }
  float inv = 1.f/den;
  if (FOUT == 128){
    float2 b2 = ((const float2*)b)[lane];
    float ox = acc.x*inv + b2.x;  ox = (ox > 0.f) ? ox : (__expf(ox) - 1.f);
    float oy = acc.y*inv + b2.y;  oy = (oy > 0.f) ? oy : (__expf(oy) - 1.f);
    ((float2*)(xout + (size_t)wid*128))[lane] = make_float2(ox, oy);
  } else {
    acc.x += __shfl_xor(acc.x, 32);
    acc.y += __shfl_xor(acc.y, 32);
    if (lane < 32){
      float2 b2 = ((const float2*)b)[l5];
      float ox = acc.x*inv + b2.x;  ox = (ox > 0.f) ? ox : (__expf(ox) - 1.f);
      float oy = acc.y*inv + b2.y;  oy = (oy > 0.f) ? oy : (__expf(oy) - 1.f);
      ((float2*)(xout + (size_t)wid*64))[l5] = make_float2(ox, oy);
    }
  }
}

// column sums over merged x[n,64]: rows<NN -> gsum[0:64], else gsum[64:128]
// 256 threads: thread owns 4 cols (c4 = (t&15)*4), 16 rows per block-iter.
__global__ __launch_bounds__(256) void k_colsum2(const float* __restrict__ x,
    float* __restrict__ gsum, int n){
  __shared__ float ls[128];
  int t = threadIdx.x;
  if (t < 128) ls[t] = 0.f;
  __syncthreads();
  int c4 = (t & 15) * 4;
  int rsub = t >> 4;
  float4 s1 = make_float4(0.f,0.f,0.f,0.f), s2 = make_float4(0.f,0.f,0.f,0.f);
  for (int r = blockIdx.x*16 + rsub; r < n; r += gridDim.x*16){
    float4 v = *(const float4*)(x + (size_t)r*64 + c4);
    if (r < NN){ s1.x+=v.x; s1.y+=v.y; s1.z+=v.z; s1.w+=v.w; }
    else       { s2.x+=v.x; s2.y+=v.y; s2.z+=v.z; s2.w+=v.w; }
  }
  atomicAdd(&ls[c4+0], s1.x); atomicAdd(&ls[c4+1], s1.y);
  atomicAdd(&ls[c4+2], s1.z); atomicAdd(&ls[c4+3], s1.w);
  atomicAdd(&ls[64+c4+0], s2.x); atomicAdd(&ls[64+c4+1], s2.y);
  atomicAdd(&ls[64+c4+2], s2.z); atomicAdd(&ls[64+c4+3], s2.w);
  __syncthreads();
  if (t < 128) atomicAdd(&gsum[t], ls[t]);
}

// final MLP head, single block of 128 threads
__global__ void k_head(const float* __restrict__ gs1, const float* __restrict__ gs2,
                       const float* __restrict__ xn1, const float* __restrict__ xn2,
                       const float* __restrict__ Wlin, const float* __restrict__ blin,
                       const float* __restrict__ Wc1, const float* __restrict__ bc1,
                       const float* __restrict__ Wc2, const float* __restrict__ bc2,
                       float* __restrict__ out){
  __shared__ float c1[80], c2[80], xcat[128], hb[16];
  int tid = threadIdx.x;
  const float invn = 1.f/(float)NN;
  if (tid < 64){ c1[tid] = gs1[tid]*invn; c2[tid] = gs2[tid]*invn; }
  else if (tid < 80){ c1[tid] = xn1[tid-64]; c2[tid] = xn2[tid-64]; }
  __syncthreads();
  if (tid < 64){
    float s = blin[tid];
    for (int k=0;k<80;k++) s += c1[k]*Wlin[k*64+tid];
    xcat[tid] = s;
  } else {
    int j = tid - 64;
    float s = blin[j];
    for (int k=0;k<80;k++) s += c2[k]*Wlin[k*64+j];
    xcat[tid] = s;
  }
  __syncthreads();
  if (tid < 16){
    float s = bc1[tid];
    for (int k=0;k<128;k++) s += xcat[k]*Wc1[k*16+tid];
    hb[tid] = fmaxf(s, 0.f);
  }
  __syncthreads();
  if (tid < 3){
    float s = bc2[tid];
    for (int k=0;k<16;k++) s += hb[k]*Wc2[k*3+tid];
    out[tid] = s;
  }
}

extern "C" void kernel_launch(void* const* d_in, const int* in_sizes, int n_in,
                              void* d_out, int out_size, void* d_ws, size_t ws_size,
                              hipStream_t stream){
  const float* x1  = (const float*)d_in[0];
  const float* x2  = (const float*)d_in[1];
  const int*   ei1 = (const int*)d_in[2];
  const int*   ei2 = (const int*)d_in[3];
  const float* xn1 = (const float*)d_in[4];
  const float* xn2 = (const float*)d_in[5];
  const float* ec1 = (const float*)d_in[6];
  const float* ec2 = (const float*)d_in[7];
  const float* W[3]    = {(const float*)d_in[8],  (const float*)d_in[14], (const float*)d_in[20]};
  const float* asrc[3] = {(const float*)d_in[9],  (const float*)d_in[15], (const float*)d_in[21]};
  const float* adst[3] = {(const float*)d_in[10], (const float*)d_in[16], (const float*)d_in[22]};
  const float* We[3]   = {(const float*)d_in[11], (const float*)d_in[17], (const float*)d_in[23]};
  const float* ae[3]   = {(const float*)d_in[12], (const float*)d_in[18], (const float*)d_in[24]};
  const float* bb[3]   = {(const float*)d_in[13], (const float*)d_in[19], (const float*)d_in[25]};
  const float* Wlin = (const float*)d_in[26];
  const float* blin = (const float*)d_in[27];
  const float* Wc1  = (const float*)d_in[28];
  const float* bc1  = (const float*)d_in[29];
  const float* Wc2  = (const float*)d_in[30];
  const float* bc2  = (const float*)d_in[31];
  float* out = (float*)d_out;

  // workspace: bufX fp32 [NT*128] (aliased as gstage during CSR build) |
  //            h16 bf16 [NT*128] | srt int2 [ET] | small
  char* wsb = (char*)d_ws;
  float*          bufX = (float*)wsb;                                        // 51.2 MB
  uint2*          gstage = (uint2*)wsb;                                      // 12.8 MB alias
  unsigned short* h16  = (unsigned short*)(wsb + (size_t)NT*128*4);          // 25.6 MB
  int2*           srt  = (int2*)(wsb + (size_t)NT*128*4 + (size_t)NT*128*2); // 13.6 MB
  float* hs   = (float*)(srt + ET);               // NT
  float* hd   = hs + NT;                          // NT
  int*   row_ptr = (int*)(hd + NT);               // NT+1
  int*   bcnt  = row_ptr + NT + 2;                // 512 (zeroed)
  int*   gcur  = bcnt + 512;                      // 512 (zeroed)
  float* gsum  = (float*)(gcur + 512);            // 128 (zeroed)
  int*   hbase = (int*)(gsum + 128);              // 513
  float* ce3   = (float*)(hbase + 513);           // 4

  const int* s1 = ei1, * d1 = ei1 + NE;
  const int* s2 = ei2, * d2 = ei2 + NE;

  hipMemsetAsync(bcnt, 0, (512+512+128)*sizeof(int), stream);  // bcnt|gcur|gsum
  k_ce3<<<1, 64, 0, stream>>>(We[0], ae[0], We[1], ae[1], We[2], ae[2], ce3);

  // bucketed CSR build
  k_hist<<<256, 256, 0, stream>>>(d1, d2, bcnt);
  k_hscan<<<1, 256, 0, stream>>>(bcnt, hbase, row_ptr);
  k_bin<<<(2*NE + BCH - 1)/BCH, 256, 0, stream>>>(s1, d1, ec1, s2, d2, ec2, hbase, gcur, gstage);
  k_bucket<<<NB, 256, 0, stream>>>(gstage, hbase, srt, row_ptr);

  // layer 0
  k_gemm7<<<(NT+7)/8, 256, 0, stream>>>(x1, x2, W[0], asrc[0], adst[0], h16, hs, hd, NT);
  k_aggregate<128><<<(NT+3)/4, 256, 0, stream>>>(h16, hs, hd, srt, row_ptr, ce3+0, bb[0], bufX, NT);
  // layer 1
  k_gemm<128,128><<<(NT+63)/64, 256, 0, stream>>>(bufX, W[1], asrc[1], adst[1], h16, hs, hd, NT);
  k_aggregate<128><<<(NT+3)/4, 256, 0, stream>>>(h16, hs, hd, srt, row_ptr, ce3+1, bb[1], bufX, NT);
  // layer 2
  k_gemm<128,64><<<(NT+63)/64, 256, 0, stream>>>(bufX, W[2], asrc[2], adst[2], h16, hs, hd, NT);
  k_aggregate<64><<<(NT+3)/4, 256, 0, stream>>>(h16, hs, hd, srt, row_ptr, ce3+2, bb[2], bufX, NT);

  k_colsum2<<<512, 256, 0, stream>>>(bufX, gsum, NT);
  k_head<<<1, 128, 0, stream>>>(gsum, gsum+64, xn1, xn2, Wlin, blin, Wc1, bc1, Wc2, bc2, out);
}

// Round 9
// 511.126 us; speedup vs baseline: 3.3442x; 1.0186x over previous
//
#include <hip/hip_runtime.h>
#include <math.h>

#define NN 50000
#define NE 800000
#define NT 100000           // merged nodes (two graphs)
#define ET (2*NE + NT)      // merged CSR entries incl self loops
#define NPB 256             // nodes per bucket
#define NB 391              // ceil(NT/NPB)
#define BCH 4096            // edges per k_bin chunk
#define BCAP 5120           // k_bucket LDS edge capacity (mean 4096, sigma 64)

// ---------- helpers ----------
static __device__ __forceinline__ float wave_max64(float v){
  #pragma unroll
  for(int off=32;off;off>>=1) v = fmaxf(v, __shfl_xor(v,off));
  return v;
}
static __device__ __forceinline__ float wave_sum64(float v){
  #pragma unroll
  for(int off=32;off;off>>=1) v += __shfl_xor(v,off);
  return v;
}
// bf16 pack/unpack (RNE)
static __device__ __forceinline__ unsigned short f2bf(float f){
  unsigned u = __float_as_uint(f);
  return (unsigned short)((u + 0x7FFFu + ((u>>16)&1u)) >> 16);
}
static __device__ __forceinline__ float bflo(unsigned v){ return __uint_as_float(v<<16); }
static __device__ __forceinline__ float bfhi(unsigned v){ return __uint_as_float(v & 0xFFFF0000u); }

// ---------- bucketed CSR build ----------
// pass 1: per-bucket edge histogram (LDS-privatized)
__global__ __launch_bounds__(256) void k_hist(const int* __restrict__ d1,
    const int* __restrict__ d2, int* __restrict__ bcnt){
  __shared__ int h[512];
  int t = threadIdx.x;
  h[t] = 0; h[t+256] = 0;
  __syncthreads();
  int stride = gridDim.x*256;
  for (int e = blockIdx.x*256 + t; e < NE; e += stride){
    atomicAdd(&h[d1[e]>>8], 1);
    atomicAdd(&h[(d2[e]+NN)>>8], 1);
  }
  __syncthreads();
  if (h[t])     atomicAdd(&bcnt[t],     h[t]);
  if (h[t+256]) atomicAdd(&bcnt[t+256], h[t+256]);
}

// pass 2: exclusive scan of bcnt[512] -> hbase; also row_ptr[NT]=ET
__global__ void k_hscan(const int* __restrict__ bcnt, int* __restrict__ hbase,
                        int* __restrict__ row_ptr){
  int t = threadIdx.x;           // 256 threads, each owns entries 2t,2t+1
  int a = bcnt[2*t], b2 = bcnt[2*t+1];
  int s = a + b2;
  int lane = t & 63, wv = t >> 6;
  int inc = s;
  #pragma unroll
  for (int off=1; off<64; off<<=1){ int u = __shfl_up(inc, off); if (lane>=off) inc += u; }
  __shared__ int wsum[4];
  if (lane==63) wsum[wv] = inc;
  __syncthreads();
  int woff = 0;
  #pragma unroll
  for (int w=0; w<4; ++w) if (w < wv) woff += wsum[w];
  int excl = woff + inc - s;
  hbase[2*t] = excl; hbase[2*t+1] = excl + a;
  if (t==0) row_ptr[NT] = ET;
}

// pass 3: block-local counting sort of 4096-edge chunks, coalesced flush to
// bucket-partitioned staging. pack = src | (dst&255)<<17
__global__ __launch_bounds__(256) void k_bin(const int* __restrict__ s1,
    const int* __restrict__ d1, const float* __restrict__ e1,
    const int* __restrict__ s2, const int* __restrict__ d2,
    const float* __restrict__ e2, const int* __restrict__ hbase,
    int* __restrict__ gcur, uint2* __restrict__ gstage){
  __shared__ int cnt[512], loff[512], cur[512], gbase_sh[512];
  __shared__ uint2 sdata[BCH];
  __shared__ unsigned short sbkt[BCH];
  __shared__ int wsum[4];
  int tid = threadIdx.x;
  int e0 = blockIdx.x*BCH;
  unsigned pack[16], eab[16];
  unsigned short bk[16];
  cnt[tid] = 0; cnt[tid+256] = 0; cur[tid] = 0; cur[tid+256] = 0;
  __syncthreads();
  #pragma unroll
  for (int u=0; u<16; ++u){
    int e = e0 + u*256 + tid;
    int b = NB; unsigned p = 0, ea = 0;
    if (e < 2*NE){
      int src, dst; float eav;
      if (e < NE){ src = s1[e]; dst = d1[e]; eav = e1[e]; }
      else { int e2i = e - NE; src = s2[e2i] + NN; dst = d2[e2i] + NN; eav = e2[e2i]; }
      b = dst >> 8;
      p = (unsigned)src | ((unsigned)(dst & 255) << 17);
      ea = __float_as_uint(eav);
    }
    bk[u] = (unsigned short)b; pack[u] = p; eab[u] = ea;
    atomicAdd(&cnt[b], 1);
  }
  __syncthreads();
  // exclusive scan cnt[512] -> loff[512]
  {
    int a = cnt[2*tid], b2 = cnt[2*tid+1];
    int s = a + b2;
    int lane = tid & 63, wv = tid >> 6;
    int inc = s;
    #pragma unroll
    for (int off=1; off<64; off<<=1){ int u = __shfl_up(inc, off); if (lane>=off) inc += u; }
    if (lane==63) wsum[wv] = inc;
    __syncthreads();
    int woff = 0;
    #pragma unroll
    for (int w=0; w<4; ++w) if (w < wv) woff += wsum[w];
    int excl = woff + inc - s;
    loff[2*tid] = excl; loff[2*tid+1] = excl + a;
  }
  // reserve global staging ranges (cnt is stable)
  if (tid < NB && cnt[tid] > 0)
    gbase_sh[tid] = hbase[tid] + atomicAdd(&gcur[tid], cnt[tid]);
  if (tid+256 < NB && cnt[tid+256] > 0)
    gbase_sh[tid+256] = hbase[tid+256] + atomicAdd(&gcur[tid+256], cnt[tid+256]);
  __syncthreads();
  // place into LDS, bucket-sorted
  #pragma unroll
  for (int u=0; u<16; ++u){
    int b = bk[u];
    int p = loff[b] + atomicAdd(&cur[b], 1);
    sdata[p] = make_uint2(pack[u], eab[u]);
    sbkt[p] = (unsigned short)b;
  }
  __syncthreads();
  // coalesced flush (runs per bucket are contiguous in LDS and in global)
  for (int k = tid; k < BCH; k += 256){
    int b = sbkt[k];
    if (b < NB) gstage[gbase_sh[b] + (k - loff[b])] = sdata[k];
  }
}

// pass 4: one block per bucket -> final CSR (row_ptr, srt incl self loops)
__global__ __launch_bounds__(256) void k_bucket(const uint2* __restrict__ gstage,
    const int* __restrict__ hbase, int2* __restrict__ srt, int* __restrict__ row_ptr){
  __shared__ uint2 sd[BCAP];
  __shared__ int deg[256], rbase[256], cur[256];
  __shared__ float easum[256];
  __shared__ int wsum[4];
  int b = blockIdx.x, t = threadIdx.x;
  int lo = b*NPB;
  int nloc = min(NPB, NT - lo);
  int est = hbase[b], ecnt = hbase[b+1] - est;
  bool inlds = (ecnt <= BCAP);
  deg[t] = 0; easum[t] = 0.f;
  __syncthreads();
  for (int k = t; k < ecnt; k += 256){
    uint2 v = gstage[est + k];
    if (inlds) sd[k] = v;
    int dl = v.x >> 17;
    atomicAdd(&deg[dl], 1);
    atomicAdd(&easum[dl], __uint_as_float(v.y));
  }
  __syncthreads();
  // exclusive scan of (deg+1) over nloc entries -> final CSR bases
  int dv = (t < nloc) ? deg[t] + 1 : 0;
  int lane = t & 63, wv = t >> 6;
  int inc = dv;
  #pragma unroll
  for (int off=1; off<64; off<<=1){ int u = __shfl_up(inc, off); if (lane>=off) inc += u; }
  if (lane==63) wsum[wv] = inc;
  __syncthreads();
  int woff = 0;
  #pragma unroll
  for (int w=0; w<4; ++w) if (w < wv) woff += wsum[w];
  int gb = est + lo + (woff + inc - dv);   // hbase[b] edges + lo self slots before
  if (t < nloc){
    row_ptr[lo + t] = gb;
    rbase[t] = gb;
    cur[t] = 1;
    float se = easum[t] / fmaxf((float)deg[t], 1.f);
    srt[gb] = make_int2(lo + t, __float_as_int(se));   // self loop
  }
  __syncthreads();
  for (int k = t; k < ecnt; k += 256){
    uint2 v = inlds ? sd[k] : gstage[est + k];
    int dl = v.x >> 17;
    int pos = rbase[dl] + atomicAdd(&cur[dl], 1);
    srt[pos] = make_int2((int)(v.x & 0x1FFFFu), (int)v.y);
  }
}

// ce[L] = dot(We_L[0,:], a_e_L), one launch
__global__ void k_ce3(const float* __restrict__ We0, const float* __restrict__ ae0,
                      const float* __restrict__ We1, const float* __restrict__ ae1,
                      const float* __restrict__ We2, const float* __restrict__ ae2,
                      float* __restrict__ ce3){
  int l = threadIdx.x;
  const float* We[3] = {We0, We1, We2};
  const float* ae[3] = {ae0, ae1, ae2};
  const int fo[3] = {128, 128, 64};
  for (int L = 0; L < 3; ++L){
    float s = 0.f;
    for (int c = l; c < fo[L]; c += 64) s += We[L][c]*ae[L][c];
    s = wave_sum64(s);
    if (l == 0) ce3[L] = s;
  }
}

// ---- register-tiled GEMM, h written as bf16, fused hs/hd epilogue ----
template<int K, int N>
__global__ __launch_bounds__(256) void k_gemm(const float* __restrict__ x,
    const float* __restrict__ W, const float* __restrict__ a_src,
    const float* __restrict__ a_dst, unsigned short* __restrict__ h16,
    float* __restrict__ hs, float* __restrict__ hd, int n){
  constexpr int KB  = 32;
  constexpr int CG  = N/4;
  constexpr int TY  = 256/CG;
  constexpr int RPT = 64/TY;
  __shared__ float Wl[KB][N];
  __shared__ float Xt[KB][64];
  int tid = threadIdx.x;
  int tx = tid % CG, ty = tid / CG;
  int r0 = blockIdx.x * 64;
  float acc[RPT][4] = {};
  for (int k0 = 0; k0 < K; k0 += KB){
    {
      const float4* src = (const float4*)(W + (size_t)k0*N);
      float4* dst = (float4*)(&Wl[0][0]);
      #pragma unroll
      for (int i = 0; i < KB*N/1024; ++i) dst[tid + i*256] = src[tid + i*256];
    }
    {
      int rr = tid >> 3, kk0 = (tid & 7) * 4;
      #pragma unroll
      for (int it = 0; it < 2; ++it){
        int r = rr + it*32;
        int gr = r0 + r;
        float4 v = (gr < n) ? *(const float4*)(x + (size_t)gr*K + k0 + kk0)
                            : make_float4(0.f,0.f,0.f,0.f);
        Xt[kk0+0][r] = v.x; Xt[kk0+1][r] = v.y; Xt[kk0+2][r] = v.z; Xt[kk0+3][r] = v.w;
      }
    }
    __syncthreads();
    #pragma unroll
    for (int kk = 0; kk < KB; ++kk){
      float4 wv = *(const float4*)(&Wl[kk][tx*4]);
      float xv[RPT];
      #pragma unroll
      for (int i = 0; i < RPT/4; ++i)
        *(float4*)&xv[i*4] = *(const float4*)(&Xt[kk][ty*RPT + i*4]);
      #pragma unroll
      for (int i=0;i<RPT;i++){
        acc[i][0] += xv[i]*wv.x; acc[i][1] += xv[i]*wv.y;
        acc[i][2] += xv[i]*wv.z; acc[i][3] += xv[i]*wv.w;
      }
    }
    __syncthreads();
  }
  #pragma unroll
  for (int i=0;i<RPT;i++){
    int gr = r0 + ty*RPT + i;
    if (gr < n){
      unsigned r0p = (unsigned)f2bf(acc[i][0]) | ((unsigned)f2bf(acc[i][1])<<16);
      unsigned r1p = (unsigned)f2bf(acc[i][2]) | ((unsigned)f2bf(acc[i][3])<<16);
      *(uint2*)(h16 + (size_t)gr*N + tx*4) = make_uint2(r0p, r1p);
    }
  }
  float as4[4], ad4[4];
  #pragma unroll
  for (int j=0;j<4;j++){ as4[j] = a_src[tx*4+j]; ad4[j] = a_dst[tx*4+j]; }
  #pragma unroll
  for (int i=0;i<RPT;i++){
    float ps = acc[i][0]*as4[0] + acc[i][1]*as4[1] + acc[i][2]*as4[2] + acc[i][3]*as4[3];
    float pd = acc[i][0]*ad4[0] + acc[i][1]*ad4[1] + acc[i][2]*ad4[2] + acc[i][3]*ad4[3];
    #pragma unroll
    for (int off=CG/2; off; off>>=1){ ps += __shfl_xor(ps, off); pd += __shfl_xor(pd, off); }
    int gr = r0 + ty*RPT + i;
    if (tx==0 && gr < n){ hs[gr] = ps; hd[gr] = pd; }
  }
}

// layer-1 GEMM: K=7, N=128, rows from x1 (r<NN) or x2
__global__ __launch_bounds__(256) void k_gemm7(const float* __restrict__ x1,
    const float* __restrict__ x2, const float* __restrict__ W,
    const float* __restrict__ a_src, const float* __restrict__ a_dst,
    unsigned short* __restrict__ h16, float* __restrict__ hs,
    float* __restrict__ hd, int n){
  __shared__ float Wl[7][128];
  int tid = threadIdx.x;
  for (int i = tid; i < 7*128; i += 256) ((float*)Wl)[i] = W[i];
  __syncthreads();
  int tx = tid & 31, ty = tid >> 5;
  int r = blockIdx.x*8 + ty;
  if (r >= n) return;
  const float* xr = (r < NN) ? (x1 + (size_t)r*7) : (x2 + (size_t)(r-NN)*7);
  float xv[7];
  #pragma unroll
  for (int k=0;k<7;k++) xv[k] = xr[k];
  float4 s = make_float4(0.f,0.f,0.f,0.f);
  #pragma unroll
  for (int k=0;k<7;k++){
    float4 wv = *(const float4*)(&Wl[k][tx*4]);
    s.x += xv[k]*wv.x; s.y += xv[k]*wv.y; s.z += xv[k]*wv.z; s.w += xv[k]*wv.w;
  }
  unsigned r0p = (unsigned)f2bf(s.x) | ((unsigned)f2bf(s.y)<<16);
  unsigned r1p = (unsigned)f2bf(s.z) | ((unsigned)f2bf(s.w)<<16);
  *(uint2*)(h16 + (size_t)r*128 + tx*4) = make_uint2(r0p, r1p);
  float ps = s.x*a_src[tx*4] + s.y*a_src[tx*4+1] + s.z*a_src[tx*4+2] + s.w*a_src[tx*4+3];
  float pd = s.x*a_dst[tx*4] + s.y*a_dst[tx*4+1] + s.z*a_dst[tx*4+2] + s.w*a_dst[tx*4+3];
  #pragma unroll
  for (int off=16; off; off>>=1){ ps += __shfl_xor(ps, off); pd += __shfl_xor(pd, off); }
  if (tx==0){ hs[r] = ps; hd[r] = pd; }
}

// Per-node fused: alpha -> online softmax -> wide bf16 gather -> +b -> ELU
// Gather: LPE lanes per edge, each lane loads dwordx4 (8 bf16 cols) ->
// EPS = 64/LPE edges per step, 2 steps in flight.
template<int FOUT>
__global__ __launch_bounds__(256) void k_aggregate(const unsigned short* __restrict__ h16,
    const float* __restrict__ hs, const float* __restrict__ hd,
    const int2* __restrict__ srt, const int* __restrict__ row_ptr,
    const float* __restrict__ ce_p, const float* __restrict__ b,
    float* __restrict__ xout, int n){
  constexpr int LPE = FOUT/8;        // lanes per edge (16 or 8)
  constexpr int EPS = 64/LPE;        // edges per step  (4 or 8)
  __shared__ float s_p[4][64];
  __shared__ int   s_s[4][64];
  int tid = threadIdx.x;
  int wv = tid >> 6, lane = tid & 63;
  int wid = (int)((blockIdx.x*256 + tid) >> 6);
  if (wid >= n) return;                 // uniform per wave
  float ce  = *ce_p;
  int beg = row_ptr[wid], end = row_ptr[wid+1];
  float hdn = hd[wid];
  int e_sub = lane / LPE;               // edge sub-slot
  int col8  = (lane % LPE) * 8;         // 8 columns per lane
  float m = -INFINITY, den = 0.f;
  float acc[8] = {0.f,0.f,0.f,0.f,0.f,0.f,0.f,0.f};
  for (int base = beg; base < end; base += 64){
    int slot = base + lane;
    float a = -INFINITY; int src = 0;
    if (slot < end){
      int2 pk = srt[slot];
      src = pk.x;
      a = hs[src] + hdn + __int_as_float(pk.y)*ce;
      a = (a > 0.f) ? a : 0.2f*a;                 // leaky_relu(0.2)
    }
    float cm = wave_max64(a);
    float mnew = fmaxf(m, cm);
    float scale = __expf(m - mnew);               // m==-inf -> 0
    den *= scale;
    #pragma unroll
    for (int u=0;u<8;u++) acc[u] *= scale;
    float p = __expf(a - mnew);                   // invalid lanes -> 0
    den += wave_sum64(p);
    s_p[wv][lane] = p; s_s[wv][lane] = src;
    asm volatile("s_waitcnt lgkmcnt(0)" ::: "memory");  // intra-wave LDS RAW fence
    int cnt = end - base; if (cnt > 64) cnt = 64;
    // invalid slots have p==0, so over-reading up to the 64 boundary is safe
    for (int j = 0; j < cnt; j += 2*EPS){
      int jj0 = j + e_sub, jj1 = j + EPS + e_sub;
      float p0 = s_p[wv][jj0];  int sj0 = s_s[wv][jj0];
      float p1 = s_p[wv][jj1];  int sj1 = s_s[wv][jj1];
      uint4 h0 = *(const uint4*)(h16 + (size_t)sj0*FOUT + col8);
      uint4 h1 = *(const uint4*)(h16 + (size_t)sj1*FOUT + col8);
      acc[0] += p0*bflo(h0.x); acc[1] += p0*bfhi(h0.x);
      acc[2] += p0*bflo(h0.y); acc[3] += p0*bfhi(h0.y);
      acc[4] += p0*bflo(h0.z); acc[5] += p0*bfhi(h0.z);
      acc[6] += p0*bflo(h0.w); acc[7] += p0*bfhi(h0.w);
      acc[0] += p1*bflo(h1.x); acc[1] += p1*bfhi(h1.x);
      acc[2] += p1*bflo(h1.y); acc[3] += p1*bfhi(h1.y);
      acc[4] += p1*bflo(h1.z); acc[5] += p1*bfhi(h1.z);
      acc[6] += p1*bflo(h1.w); acc[7] += p1*bfhi(h1.w);
    }
    m = mnew;
  }
  // reduce across edge sub-slot groups (lanes l, l^LPE, ..., l^32)
  #pragma unroll
  for (int off = LPE; off < 64; off <<= 1){
    #pragma unroll
    for (int u=0;u<8;u++) acc[u] += __shfl_xor(acc[u], off);
  }
  float inv = 1.f/den;
  if (lane < LPE){
    float4 b0 = *(const float4*)(b + col8);
    float4 b1 = *(const float4*)(b + col8 + 4);
    float4 o0, o1;
    o0.x = acc[0]*inv + b0.x; o0.y = acc[1]*inv + b0.y;
    o0.z = acc[2]*inv + b0.z; o0.w = acc[3]*inv + b0.w;
    o1.x = acc[4]*inv + b1.x; o1.y = acc[5]*inv + b1.y;
    o1.z = acc[6]*inv + b1.z; o1.w = acc[7]*inv + b1.w;
    o0.x = (o0.x > 0.f) ? o0.x : (__expf(o0.x) - 1.f);
    o0.y = (o0.y > 0.f) ? o0.y : (__expf(o0.y) - 1.f);
    o0.z = (o0.z > 0.f) ? o0.z : (__expf(o0.z) - 1.f);
    o0.w = (o0.w > 0.f) ? o0.w : (__expf(o0.w) - 1.f);
    o1.x = (o1.x > 0.f) ? o1.x : (__expf(o1.x) - 1.f);
    o1.y = (o1.y > 0.f) ? o1.y : (__expf(o1.y) - 1.f);
    o1.z = (o1.z > 0.f) ? o1.z : (__expf(o1.z) - 1.f);
    o1.w = (o1.w > 0.f) ? o1.w : (__expf(o1.w) - 1.f);
    *(float4*)(xout + (size_t)wid*FOUT + col8)     = o0;
    *(float4*)(xout + (size_t)wid*FOUT + col8 + 4) = o1;
  }
}

// column sums over merged x[n,64]: rows<NN -> gsum[0:64], else gsum[64:128]
// 256 threads: thread owns 4 cols (c4 = (t&15)*4), 16 rows per block-iter.
__global__ __launch_bounds__(256) void k_colsum2(const float* __restrict__ x,
    float* __restrict__ gsum, int n){
  __shared__ float ls[128];
  int t = threadIdx.x;
  if (t < 128) ls[t] = 0.f;
  __syncthreads();
  int c4 = (t & 15) * 4;
  int rsub = t >> 4;
  float4 s1 = make_float4(0.f,0.f,0.f,0.f), s2 = make_float4(0.f,0.f,0.f,0.f);
  for (int r = blockIdx.x*16 + rsub; r < n; r += gridDim.x*16){
    float4 v = *(const float4*)(x + (size_t)r*64 + c4);
    if (r < NN){ s1.x+=v.x; s1.y+=v.y; s1.z+=v.z; s1.w+=v.w; }
    else       { s2.x+=v.x; s2.y+=v.y; s2.z+=v.z; s2.w+=v.w; }
  }
  atomicAdd(&ls[c4+0], s1.x); atomicAdd(&ls[c4+1], s1.y);
  atomicAdd(&ls[c4+2], s1.z); atomicAdd(&ls[c4+3], s1.w);
  atomicAdd(&ls[64+c4+0], s2.x); atomicAdd(&ls[64+c4+1], s2.y);
  atomicAdd(&ls[64+c4+2], s2.z); atomicAdd(&ls[64+c4+3], s2.w);
  __syncthreads();
  if (t < 128) atomicAdd(&gsum[t], ls[t]);
}

// final MLP head, single block of 128 threads
__global__ void k_head(const float* __restrict__ gs1, const float* __restrict__ gs2,
                       const float* __restrict__ xn1, const float* __restrict__ xn2,
                       const float* __restrict__ Wlin, const float* __restrict__ blin,
                       const float* __restrict__ Wc1, const float* __restrict__ bc1,
                       const float* __restrict__ Wc2, const float* __restrict__ bc2,
                       float* __restrict__ out){
  __shared__ float c1[80], c2[80], xcat[128], hb[16];
  int tid = threadIdx.x;
  const float invn = 1.f/(float)NN;
  if (tid < 64){ c1[tid] = gs1[tid]*invn; c2[tid] = gs2[tid]*invn; }
  else if (tid < 80){ c1[tid] = xn1[tid-64]; c2[tid] = xn2[tid-64]; }
  __syncthreads();
  if (tid < 64){
    float s = blin[tid];
    for (int k=0;k<80;k++) s += c1[k]*Wlin[k*64+tid];
    xcat[tid] = s;
  } else {
    int j = tid - 64;
    float s = blin[j];
    for (int k=0;k<80;k++) s += c2[k]*Wlin[k*64+j];
    xcat[tid] = s;
  }
  __syncthreads();
  if (tid < 16){
    float s = bc1[tid];
    for (int k=0;k<128;k++) s += xcat[k]*Wc1[k*16+tid];
    hb[tid] = fmaxf(s, 0.f);
  }
  __syncthreads();
  if (tid < 3){
    float s = bc2[tid];
    for (int k=0;k<16;k++) s += hb[k]*Wc2[k*3+tid];
    out[tid] = s;
  }
}

extern "C" void kernel_launch(void* const* d_in, const int* in_sizes, int n_in,
                              void* d_out, int out_size, void* d_ws, size_t ws_size,
                              hipStream_t stream){
  const float* x1  = (const float*)d_in[0];
  const float* x2  = (const float*)d_in[1];
  const int*   ei1 = (const int*)d_in[2];
  const int*   ei2 = (const int*)d_in[3];
  const float* xn1 = (const float*)d_in[4];
  const float* xn2 = (const float*)d_in[5];
  const float* ec1 = (const float*)d_in[6];
  const float* ec2 = (const float*)d_in[7];
  const float* W[3]    = {(const float*)d_in[8],  (const float*)d_in[14], (const float*)d_in[20]};
  const float* asrc[3] = {(const float*)d_in[9],  (const float*)d_in[15], (const float*)d_in[21]};
  const float* adst[3] = {(const float*)d_in[10], (const float*)d_in[16], (const float*)d_in[22]};
  const float* We[3]   = {(const float*)d_in[11], (const float*)d_in[17], (const float*)d_in[23]};
  const float* ae[3]   = {(const float*)d_in[12], (const float*)d_in[18], (const float*)d_in[24]};
  const float* bb[3]   = {(const float*)d_in[13], (const float*)d_in[19], (const float*)d_in[25]};
  const float* Wlin = (const float*)d_in[26];
  const float* blin = (const float*)d_in[27];
  const float* Wc1  = (const float*)d_in[28];
  const float* bc1  = (const float*)d_in[29];
  const float* Wc2  = (const float*)d_in[30];
  const float* bc2  = (const float*)d_in[31];
  float* out = (float*)d_out;

  // workspace: bufX fp32 [NT*128] (aliased as gstage during CSR build) |
  //            h16 bf16 [NT*128] | srt int2 [ET] | small
  char* wsb = (char*)d_ws;
  float*          bufX = (float*)wsb;                                        // 51.2 MB
  uint2*          gstage = (uint2*)wsb;                                      // 12.8 MB alias
  unsigned short* h16  = (unsigned short*)(wsb + (size_t)NT*128*4);          // 25.6 MB
  int2*           srt  = (int2*)(wsb + (size_t)NT*128*4 + (size_t)NT*128*2); // 13.6 MB
  float* hs   = (float*)(srt + ET);               // NT
  float* hd   = hs + NT;                          // NT
  int*   row_ptr = (int*)(hd + NT);               // NT+1
  int*   bcnt  = row_ptr + NT + 2;                // 512 (zeroed)
  int*   gcur  = bcnt + 512;                      // 512 (zeroed)
  float* gsum  = (float*)(gcur + 512);            // 128 (zeroed)
  int*   hbase = (int*)(gsum + 128);              // 513
  float* ce3   = (float*)(hbase + 513);           // 4

  const int* s1 = ei1, * d1 = ei1 + NE;
  const int* s2 = ei2, * d2 = ei2 + NE;

  hipMemsetAsync(bcnt, 0, (512+512+128)*sizeof(int), stream);  // bcnt|gcur|gsum
  k_ce3<<<1, 64, 0, stream>>>(We[0], ae[0], We[1], ae[1], We[2], ae[2], ce3);

  // bucketed CSR build
  k_hist<<<256, 256, 0, stream>>>(d1, d2, bcnt);
  k_hscan<<<1, 256, 0, stream>>>(bcnt, hbase, row_ptr);
  k_bin<<<(2*NE + BCH - 1)/BCH, 256, 0, stream>>>(s1, d1, ec1, s2, d2, ec2, hbase, gcur, gstage);
  k_bucket<<<NB, 256, 0, stream>>>(gstage, hbase, srt, row_ptr);

  // layer 0
  k_gemm7<<<(NT+7)/8, 256, 0, stream>>>(x1, x2, W[0], asrc[0], adst[0], h16, hs, hd, NT);
  k_aggregate<128><<<(NT+3)/4, 256, 0, stream>>>(h16, hs, hd, srt, row_ptr, ce3+0, bb[0], bufX, NT);
  // layer 1
  k_gemm<128,128><<<(NT+63)/64, 256, 0, stream>>>(bufX, W[1], asrc[1], adst[1], h16, hs, hd, NT);
  k_aggregate<128><<<(NT+3)/4, 256, 0, stream>>>(h16, hs, hd, srt, row_ptr, ce3+1, bb[1], bufX, NT);
  // layer 2
  k_gemm<128,64><<<(NT+63)/64, 256, 0, stream>>>(bufX, W[2], asrc[2], adst[2], h16, hs, hd, NT);
  k_aggregate<64><<<(NT+3)/4, 256, 0, stream>>>(h16, hs, hd, srt, row_ptr, ce3+2, bb[2], bufX, NT);

  k_colsum2<<<512, 256, 0, stream>>>(bufX, gsum, NT);
  k_head<<<1, 128, 0, stream>>>(gsum, gsum+64, xn1, xn2, Wlin, blin, Wc1, bc1, Wc2, bc2, out);
}

// Round 10
// 475.422 us; speedup vs baseline: 3.5953x; 1.0751x over previous
//
#include <hip/hip_runtime.h>
#include <math.h>

#define NN 50000
#define NE 800000
#define NT 100000           // merged nodes (two graphs)
#define NTP 100032          // padded to 64-row multiple for MFMA gemm
#define ET (2*NE + NT)      // merged CSR entries incl self loops
#define NPB 256             // nodes per bucket
#define NB 391              // ceil(NT/NPB)
#define BCH 4096            // edges per k_bin chunk
#define BCAP 5120           // k_bucket LDS edge capacity

typedef __attribute__((ext_vector_type(8))) short bf16x8;
typedef __attribute__((ext_vector_type(4))) float f32x4;

// ---------- helpers ----------
static __device__ __forceinline__ float wave_max64(float v){
  #pragma unroll
  for(int off=32;off;off>>=1) v = fmaxf(v, __shfl_xor(v,off));
  return v;
}
static __device__ __forceinline__ float wave_sum64(float v){
  #pragma unroll
  for(int off=32;off;off>>=1) v += __shfl_xor(v,off);
  return v;
}
// bf16 pack/unpack (RNE)
static __device__ __forceinline__ unsigned short f2bf(float f){
  unsigned u = __float_as_uint(f);
  return (unsigned short)((u + 0x7FFFu + ((u>>16)&1u)) >> 16);
}
static __device__ __forceinline__ float bflo(unsigned v){ return __uint_as_float(v<<16); }
static __device__ __forceinline__ float bfhi(unsigned v){ return __uint_as_float(v & 0xFFFF0000u); }

// ---------- bucketed CSR build ----------
__global__ __launch_bounds__(256) void k_hist(const int* __restrict__ d1,
    const int* __restrict__ d2, int* __restrict__ bcnt){
  __shared__ int h[512];
  int t = threadIdx.x;
  h[t] = 0; h[t+256] = 0;
  __syncthreads();
  int stride = gridDim.x*256;
  for (int e = blockIdx.x*256 + t; e < NE; e += stride){
    atomicAdd(&h[d1[e]>>8], 1);
    atomicAdd(&h[(d2[e]+NN)>>8], 1);
  }
  __syncthreads();
  if (h[t])     atomicAdd(&bcnt[t],     h[t]);
  if (h[t+256]) atomicAdd(&bcnt[t+256], h[t+256]);
}

__global__ void k_hscan(const int* __restrict__ bcnt, int* __restrict__ hbase,
                        int* __restrict__ row_ptr){
  int t = threadIdx.x;
  int a = bcnt[2*t], b2 = bcnt[2*t+1];
  int s = a + b2;
  int lane = t & 63, wv = t >> 6;
  int inc = s;
  #pragma unroll
  for (int off=1; off<64; off<<=1){ int u = __shfl_up(inc, off); if (lane>=off) inc += u; }
  __shared__ int wsum[4];
  if (lane==63) wsum[wv] = inc;
  __syncthreads();
  int woff = 0;
  #pragma unroll
  for (int w=0; w<4; ++w) if (w < wv) woff += wsum[w];
  int excl = woff + inc - s;
  hbase[2*t] = excl; hbase[2*t+1] = excl + a;
  if (t==0) row_ptr[NT] = ET;
}

// pack = src | (dst&255)<<17
__global__ __launch_bounds__(256) void k_bin(const int* __restrict__ s1,
    const int* __restrict__ d1, const float* __restrict__ e1,
    const int* __restrict__ s2, const int* __restrict__ d2,
    const float* __restrict__ e2, const int* __restrict__ hbase,
    int* __restrict__ gcur, uint2* __restrict__ gstage){
  __shared__ int cnt[512], loff[512], cur[512], gbase_sh[512];
  __shared__ uint2 sdata[BCH];
  __shared__ unsigned short sbkt[BCH];
  __shared__ int wsum[4];
  int tid = threadIdx.x;
  int e0 = blockIdx.x*BCH;
  unsigned pack[16], eab[16];
  unsigned short bk[16];
  cnt[tid] = 0; cnt[tid+256] = 0; cur[tid] = 0; cur[tid+256] = 0;
  __syncthreads();
  #pragma unroll
  for (int u=0; u<16; ++u){
    int e = e0 + u*256 + tid;
    int b = NB; unsigned p = 0, ea = 0;
    if (e < 2*NE){
      int src, dst; float eav;
      if (e < NE){ src = s1[e]; dst = d1[e]; eav = e1[e]; }
      else { int e2i = e - NE; src = s2[e2i] + NN; dst = d2[e2i] + NN; eav = e2[e2i]; }
      b = dst >> 8;
      p = (unsigned)src | ((unsigned)(dst & 255) << 17);
      ea = __float_as_uint(eav);
    }
    bk[u] = (unsigned short)b; pack[u] = p; eab[u] = ea;
    atomicAdd(&cnt[b], 1);
  }
  __syncthreads();
  {
    int a = cnt[2*tid], b2 = cnt[2*tid+1];
    int s = a + b2;
    int lane = tid & 63, wv = tid >> 6;
    int inc = s;
    #pragma unroll
    for (int off=1; off<64; off<<=1){ int u = __shfl_up(inc, off); if (lane>=off) inc += u; }
    if (lane==63) wsum[wv] = inc;
    __syncthreads();
    int woff = 0;
    #pragma unroll
    for (int w=0; w<4; ++w) if (w < wv) woff += wsum[w];
    int excl = woff + inc - s;
    loff[2*tid] = excl; loff[2*tid+1] = excl + a;
  }
  if (tid < NB && cnt[tid] > 0)
    gbase_sh[tid] = hbase[tid] + atomicAdd(&gcur[tid], cnt[tid]);
  if (tid+256 < NB && cnt[tid+256] > 0)
    gbase_sh[tid+256] = hbase[tid+256] + atomicAdd(&gcur[tid+256], cnt[tid+256]);
  __syncthreads();
  #pragma unroll
  for (int u=0; u<16; ++u){
    int b = bk[u];
    int p = loff[b] + atomicAdd(&cur[b], 1);
    sdata[p] = make_uint2(pack[u], eab[u]);
    sbkt[p] = (unsigned short)b;
  }
  __syncthreads();
  for (int k = tid; k < BCH; k += 256){
    int b = sbkt[k];
    if (b < NB) gstage[gbase_sh[b] + (k - loff[b])] = sdata[k];
  }
}

__global__ __launch_bounds__(256) void k_bucket(const uint2* __restrict__ gstage,
    const int* __restrict__ hbase, int2* __restrict__ srt, int* __restrict__ row_ptr){
  __shared__ uint2 sd[BCAP];
  __shared__ int deg[256], rbase[256], cur[256];
  __shared__ float easum[256];
  __shared__ int wsum[4];
  int b = blockIdx.x, t = threadIdx.x;
  int lo = b*NPB;
  int nloc = min(NPB, NT - lo);
  int est = hbase[b], ecnt = hbase[b+1] - est;
  bool inlds = (ecnt <= BCAP);
  deg[t] = 0; easum[t] = 0.f;
  __syncthreads();
  for (int k = t; k < ecnt; k += 256){
    uint2 v = gstage[est + k];
    if (inlds) sd[k] = v;
    int dl = v.x >> 17;
    atomicAdd(&deg[dl], 1);
    atomicAdd(&easum[dl], __uint_as_float(v.y));
  }
  __syncthreads();
  int dv = (t < nloc) ? deg[t] + 1 : 0;
  int lane = t & 63, wv = t >> 6;
  int inc = dv;
  #pragma unroll
  for (int off=1; off<64; off<<=1){ int u = __shfl_up(inc, off); if (lane>=off) inc += u; }
  if (lane==63) wsum[wv] = inc;
  __syncthreads();
  int woff = 0;
  #pragma unroll
  for (int w=0; w<4; ++w) if (w < wv) woff += wsum[w];
  int gb = est + lo + (woff + inc - dv);
  if (t < nloc){
    row_ptr[lo + t] = gb;
    rbase[t] = gb;
    cur[t] = 1;
    float se = easum[t] / fmaxf((float)deg[t], 1.f);
    srt[gb] = make_int2(lo + t, __float_as_int(se));
  }
  __syncthreads();
  for (int k = t; k < ecnt; k += 256){
    uint2 v = inlds ? sd[k] : gstage[est + k];
    int dl = v.x >> 17;
    int pos = rbase[dl] + atomicAdd(&cur[dl], 1);
    srt[pos] = make_int2((int)(v.x & 0x1FFFFu), (int)v.y);
  }
}

// prep: ce[L] dots + W1/W2 -> bf16 transposed padded Wt[N][136]
__global__ __launch_bounds__(256) void k_prep(
    const float* __restrict__ We0, const float* __restrict__ ae0,
    const float* __restrict__ We1, const float* __restrict__ ae1,
    const float* __restrict__ We2, const float* __restrict__ ae2,
    float* __restrict__ ce3,
    const float* __restrict__ W1, const float* __restrict__ W2,
    unsigned short* __restrict__ Wt1, unsigned short* __restrict__ Wt2){
  int t = threadIdx.x;
  if (t < 64){
    const float* We[3] = {We0, We1, We2};
    const float* ae[3] = {ae0, ae1, ae2};
    const int fo[3] = {128, 128, 64};
    for (int L = 0; L < 3; ++L){
      float s = 0.f;
      for (int c = t; c < fo[L]; c += 64) s += We[L][c]*ae[L][c];
      s = wave_sum64(s);
      if (t == 0) ce3[L] = s;
    }
  }
  for (int i = t; i < 128*128; i += 256){
    int c = i >> 7, k = i & 127;
    Wt1[c*136 + k] = f2bf(W1[k*128 + c]);
  }
  for (int i = t; i < 64*128; i += 256){
    int c = i >> 7, k = i & 127;
    Wt2[c*136 + k] = f2bf(W2[k*64 + c]);
  }
}

// ---- MFMA GEMM: h[M,N] = x16[M,128] @ W[128,N] (bf16 in, fp32 acc) ----
// + fused hs/hd + bf16 h16 output. 4 waves, 64 rows/block, Wt staged in LDS.
template<int N>
__global__ __launch_bounds__(256) void k_gemm_mfma(
    const unsigned short* __restrict__ x16, const unsigned short* __restrict__ Wt,
    const float* __restrict__ a_src, const float* __restrict__ a_dst,
    unsigned short* __restrict__ h16, float* __restrict__ hs,
    float* __restrict__ hd, int n){
  constexpr int CT = N/16;            // col tiles
  __shared__ unsigned short Wl[N*136];
  int tid = threadIdx.x;
  for (int i = tid; i < N*136/8; i += 256)
    ((uint4*)Wl)[i] = ((const uint4*)Wt)[i];
  __syncthreads();
  int lane = tid & 63, w = tid >> 6;
  int arow = blockIdx.x*64 + w*16 + (lane & 15);
  int kb   = (lane >> 4) * 8;
  int rsafe = (arow < n) ? arow : (n-1);
  f32x4 acc[CT] = {};
  #pragma unroll
  for (int s = 0; s < 4; ++s){
    bf16x8 a = *(const bf16x8*)(x16 + (size_t)rsafe*128 + s*32 + kb);
    #pragma unroll
    for (int c = 0; c < CT; ++c){
      bf16x8 b = *(const bf16x8*)(&Wl[(c*16 + (lane&15))*136 + s*32 + kb]);
      acc[c] = __builtin_amdgcn_mfma_f32_16x16x32_bf16(a, b, acc[c], 0, 0, 0);
    }
  }
  // D: col = lane&15 (within tile), row_local = (lane>>4)*4 + j
  int drow = blockIdx.x*64 + w*16 + (lane>>4)*4;
  int dcol = lane & 15;
  float psv[4] = {0,0,0,0}, pdv[4] = {0,0,0,0};
  #pragma unroll
  for (int c = 0; c < CT; ++c){
    float as = a_src[c*16 + dcol], ad = a_dst[c*16 + dcol];
    #pragma unroll
    for (int j = 0; j < 4; ++j){
      float v = acc[c][j];
      if (drow + j < n) h16[(size_t)(drow+j)*N + c*16 + dcol] = f2bf(v);
      psv[j] += v*as; pdv[j] += v*ad;
    }
  }
  #pragma unroll
  for (int off = 1; off < 16; off <<= 1){
    #pragma unroll
    for (int j=0;j<4;j++){ psv[j] += __shfl_xor(psv[j], off); pdv[j] += __shfl_xor(pdv[j], off); }
  }
  if (dcol == 0){
    #pragma unroll
    for (int j=0;j<4;j++) if (drow+j < n){ hs[drow+j] = psv[j]; hd[drow+j] = pdv[j]; }
  }
}

// layer-1 GEMM: K=7, N=128, rows from x1 (r<NN) or x2; h16 + hs/hd out
__global__ __launch_bounds__(256) void k_gemm7(const float* __restrict__ x1,
    const float* __restrict__ x2, const float* __restrict__ W,
    const float* __restrict__ a_src, const float* __restrict__ a_dst,
    unsigned short* __restrict__ h16, float* __restrict__ hs,
    float* __restrict__ hd, int n){
  __shared__ float Wl[7][128];
  int tid = threadIdx.x;
  for (int i = tid; i < 7*128; i += 256) ((float*)Wl)[i] = W[i];
  __syncthreads();
  int tx = tid & 31, ty = tid >> 5;
  int r = blockIdx.x*8 + ty;
  if (r >= n) return;
  const float* xr = (r < NN) ? (x1 + (size_t)r*7) : (x2 + (size_t)(r-NN)*7);
  float xv[7];
  #pragma unroll
  for (int k=0;k<7;k++) xv[k] = xr[k];
  float4 s = make_float4(0.f,0.f,0.f,0.f);
  #pragma unroll
  for (int k=0;k<7;k++){
    float4 wv = *(const float4*)(&Wl[k][tx*4]);
    s.x += xv[k]*wv.x; s.y += xv[k]*wv.y; s.z += xv[k]*wv.z; s.w += xv[k]*wv.w;
  }
  unsigned r0p = (unsigned)f2bf(s.x) | ((unsigned)f2bf(s.y)<<16);
  unsigned r1p = (unsigned)f2bf(s.z) | ((unsigned)f2bf(s.w)<<16);
  *(uint2*)(h16 + (size_t)r*128 + tx*4) = make_uint2(r0p, r1p);
  float ps = s.x*a_src[tx*4] + s.y*a_src[tx*4+1] + s.z*a_src[tx*4+2] + s.w*a_src[tx*4+3];
  float pd = s.x*a_dst[tx*4] + s.y*a_dst[tx*4+1] + s.z*a_dst[tx*4+2] + s.w*a_dst[tx*4+3];
  #pragma unroll
  for (int off=16; off; off>>=1){ ps += __shfl_xor(ps, off); pd += __shfl_xor(pd, off); }
  if (tx==0){ hs[r] = ps; hd[r] = pd; }
}

// Per-node fused: alpha -> online softmax -> wide bf16 gather -> +b -> ELU
// OBF: write output as bf16 (feeds next MFMA gemm) else fp32.
template<int FOUT, bool OBF>
__global__ __launch_bounds__(256) void k_aggregate(const unsigned short* __restrict__ h16,
    const float* __restrict__ hs, const float* __restrict__ hd,
    const int2* __restrict__ srt, const int* __restrict__ row_ptr,
    const float* __restrict__ ce_p, const float* __restrict__ b,
    void* __restrict__ xout, int n){
  constexpr int LPE = FOUT/8;        // lanes per edge (16 or 8)
  constexpr int EPS = 64/LPE;        // edges per step  (4 or 8)
  __shared__ float s_p[4][64];
  __shared__ int   s_s[4][64];
  int tid = threadIdx.x;
  int wv = tid >> 6, lane = tid & 63;
  int wid = (int)((blockIdx.x*256 + tid) >> 6);
  if (wid >= n) return;
  float ce  = *ce_p;
  int beg = row_ptr[wid], end = row_ptr[wid+1];
  float hdn = hd[wid];
  int e_sub = lane / LPE;
  int col8  = (lane % LPE) * 8;
  float m = -INFINITY, den = 0.f;
  float acc[8] = {0.f,0.f,0.f,0.f,0.f,0.f,0.f,0.f};
  for (int base = beg; base < end; base += 64){
    int slot = base + lane;
    float a = -INFINITY; int src = 0;
    if (slot < end){
      int2 pk = srt[slot];
      src = pk.x;
      a = hs[src] + hdn + __int_as_float(pk.y)*ce;
      a = (a > 0.f) ? a : 0.2f*a;
    }
    float cm = wave_max64(a);
    float mnew = fmaxf(m, cm);
    float scale = __expf(m - mnew);
    den *= scale;
    #pragma unroll
    for (int u=0;u<8;u++) acc[u] *= scale;
    float p = __expf(a - mnew);
    den += wave_sum64(p);
    s_p[wv][lane] = p; s_s[wv][lane] = src;
    asm volatile("s_waitcnt lgkmcnt(0)" ::: "memory");
    int cnt = end - base; if (cnt > 64) cnt = 64;
    // p==0 beyond cnt, so rounding up to EPS granularity is safe
    for (int j = 0; j < cnt; j += EPS){
      int jj = j + e_sub;
      float p0 = s_p[wv][jj];  int sj = s_s[wv][jj];
      uint4 h0 = *(const uint4*)(h16 + (size_t)sj*FOUT + col8);
      acc[0] += p0*bflo(h0.x); acc[1] += p0*bfhi(h0.x);
      acc[2] += p0*bflo(h0.y); acc[3] += p0*bfhi(h0.y);
      acc[4] += p0*bflo(h0.z); acc[5] += p0*bfhi(h0.z);
      acc[6] += p0*bflo(h0.w); acc[7] += p0*bfhi(h0.w);
    }
    m = mnew;
  }
  #pragma unroll
  for (int off = LPE; off < 64; off <<= 1){
    #pragma unroll
    for (int u=0;u<8;u++) acc[u] += __shfl_xor(acc[u], off);
  }
  float inv = 1.f/den;
  if (lane < LPE){
    float o[8];
    #pragma unroll
    for (int u=0;u<8;u++){
      o[u] = acc[u]*inv + b[col8+u];
      o[u] = (o[u] > 0.f) ? o[u] : (__expf(o[u]) - 1.f);
    }
    if (OBF){
      uint4 pkd;
      pkd.x = (unsigned)f2bf(o[0]) | ((unsigned)f2bf(o[1])<<16);
      pkd.y = (unsigned)f2bf(o[2]) | ((unsigned)f2bf(o[3])<<16);
      pkd.z = (unsigned)f2bf(o[4]) | ((unsigned)f2bf(o[5])<<16);
      pkd.w = (unsigned)f2bf(o[6]) | ((unsigned)f2bf(o[7])<<16);
      *(uint4*)((unsigned short*)xout + (size_t)wid*FOUT + col8) = pkd;
    } else {
      float4 o0 = make_float4(o[0],o[1],o[2],o[3]);
      float4 o1 = make_float4(o[4],o[5],o[6],o[7]);
      *(float4*)((float*)xout + (size_t)wid*FOUT + col8)     = o0;
      *(float4*)((float*)xout + (size_t)wid*FOUT + col8 + 4) = o1;
    }
  }
}

// column sums over merged x[n,64] fp32
__global__ __launch_bounds__(256) void k_colsum2(const float* __restrict__ x,
    float* __restrict__ gsum, int n){
  __shared__ float ls[128];
  int t = threadIdx.x;
  if (t < 128) ls[t] = 0.f;
  __syncthreads();
  int c4 = (t & 15) * 4;
  int rsub = t >> 4;
  float4 s1 = make_float4(0.f,0.f,0.f,0.f), s2 = make_float4(0.f,0.f,0.f,0.f);
  for (int r = blockIdx.x*16 + rsub; r < n; r += gridDim.x*16){
    float4 v = *(const float4*)(x + (size_t)r*64 + c4);
    if (r < NN){ s1.x+=v.x; s1.y+=v.y; s1.z+=v.z; s1.w+=v.w; }
    else       { s2.x+=v.x; s2.y+=v.y; s2.z+=v.z; s2.w+=v.w; }
  }
  atomicAdd(&ls[c4+0], s1.x); atomicAdd(&ls[c4+1], s1.y);
  atomicAdd(&ls[c4+2], s1.z); atomicAdd(&ls[c4+3], s1.w);
  atomicAdd(&ls[64+c4+0], s2.x); atomicAdd(&ls[64+c4+1], s2.y);
  atomicAdd(&ls[64+c4+2], s2.z); atomicAdd(&ls[64+c4+3], s2.w);
  __syncthreads();
  if (t < 128) atomicAdd(&gsum[t], ls[t]);
}

// final MLP head
__global__ void k_head(const float* __restrict__ gs1, const float* __restrict__ gs2,
                       const float* __restrict__ xn1, const float* __restrict__ xn2,
                       const float* __restrict__ Wlin, const float* __restrict__ blin,
                       const float* __restrict__ Wc1, const float* __restrict__ bc1,
                       const float* __restrict__ Wc2, const float* __restrict__ bc2,
                       float* __restrict__ out){
  __shared__ float c1[80], c2[80], xcat[128], hb[16];
  int tid = threadIdx.x;
  const float invn = 1.f/(float)NN;
  if (tid < 64){ c1[tid] = gs1[tid]*invn; c2[tid] = gs2[tid]*invn; }
  else if (tid < 80){ c1[tid] = xn1[tid-64]; c2[tid] = xn2[tid-64]; }
  __syncthreads();
  if (tid < 64){
    float s = blin[tid];
    for (int k=0;k<80;k++) s += c1[k]*Wlin[k*64+tid];
    xcat[tid] = s;
  } else {
    int j = tid - 64;
    float s = blin[j];
    for (int k=0;k<80;k++) s += c2[k]*Wlin[k*64+j];
    xcat[tid] = s;
  }
  __syncthreads();
  if (tid < 16){
    float s = bc1[tid];
    for (int k=0;k<128;k++) s += xcat[k]*Wc1[k*16+tid];
    hb[tid] = fmaxf(s, 0.f);
  }
  __syncthreads();
  if (tid < 3){
    float s = bc2[tid];
    for (int k=0;k<16;k++) s += hb[k]*Wc2[k*3+tid];
    out[tid] = s;
  }
}

extern "C" void kernel_launch(void* const* d_in, const int* in_sizes, int n_in,
                              void* d_out, int out_size, void* d_ws, size_t ws_size,
                              hipStream_t stream){
  const float* x1  = (const float*)d_in[0];
  const float* x2  = (const float*)d_in[1];
  const int*   ei1 = (const int*)d_in[2];
  const int*   ei2 = (const int*)d_in[3];
  const float* xn1 = (const float*)d_in[4];
  const float* xn2 = (const float*)d_in[5];
  const float* ec1 = (const float*)d_in[6];
  const float* ec2 = (const float*)d_in[7];
  const float* W[3]    = {(const float*)d_in[8],  (const float*)d_in[14], (const float*)d_in[20]};
  const float* asrc[3] = {(const float*)d_in[9],  (const float*)d_in[15], (const float*)d_in[21]};
  const float* adst[3] = {(const float*)d_in[10], (const float*)d_in[16], (const float*)d_in[22]};
  const float* We[3]   = {(const float*)d_in[11], (const float*)d_in[17], (const float*)d_in[23]};
  const float* ae[3]   = {(const float*)d_in[12], (const float*)d_in[18], (const float*)d_in[24]};
  const float* bb[3]   = {(const float*)d_in[13], (const float*)d_in[19], (const float*)d_in[25]};
  const float* Wlin = (const float*)d_in[26];
  const float* blin = (const float*)d_in[27];
  const float* Wc1  = (const float*)d_in[28];
  const float* bc1  = (const float*)d_in[29];
  const float* Wc2  = (const float*)d_in[30];
  const float* bc2  = (const float*)d_in[31];
  float* out = (float*)d_out;

  // workspace: region0 (x16 bf16 [NTP*128] | gstage uint2 [1.6M] | bufX fp32 [NT*64])
  //            all time-disjoint; then h16, srt, small.
  char* wsb = (char*)d_ws;
  unsigned short* x16   = (unsigned short*)wsb;                  // 25.6 MB
  uint2*          gstage = (uint2*)wsb;                          // alias (CSR build)
  float*          bufX  = (float*)wsb;                           // alias (layer2 out)
  unsigned short* h16  = (unsigned short*)(wsb + (size_t)NTP*128*2);           // 25.6 MB
  int2*           srt  = (int2*)(wsb + (size_t)NTP*128*2 + (size_t)NT*128*2);  // 13.6 MB
  float* hs   = (float*)(srt + ET);               // NT
  float* hd   = hs + NT;                          // NT
  int*   row_ptr = (int*)(hd + NT);               // NT+2
  int*   bcnt  = row_ptr + NT + 2;                // 512 (zeroed)
  int*   gcur  = bcnt + 512;                      // 512 (zeroed)
  float* gsum  = (float*)(gcur + 512);            // 128 (zeroed)
  int*   hbase = (int*)(gsum + 128);              // 513
  float* ce3   = (float*)(hbase + 513);           // 4 (+pad)
  unsigned short* Wt1 = (unsigned short*)(ce3 + 8);   // 128*136
  unsigned short* Wt2 = Wt1 + 128*136;                // 64*136

  const int* s1 = ei1, * d1 = ei1 + NE;
  const int* s2 = ei2, * d2 = ei2 + NE;

  hipMemsetAsync(bcnt, 0, (512+512+128)*sizeof(int), stream);  // bcnt|gcur|gsum
  k_prep<<<1, 256, 0, stream>>>(We[0], ae[0], We[1], ae[1], We[2], ae[2], ce3,
                                W[1], W[2], Wt1, Wt2);

  // bucketed CSR build
  k_hist<<<256, 256, 0, stream>>>(d1, d2, bcnt);
  k_hscan<<<1, 256, 0, stream>>>(bcnt, hbase, row_ptr);
  k_bin<<<(2*NE + BCH - 1)/BCH, 256, 0, stream>>>(s1, d1, ec1, s2, d2, ec2, hbase, gcur, gstage);
  k_bucket<<<NB, 256, 0, stream>>>(gstage, hbase, srt, row_ptr);

  // layer 0: fp32 K=7 gemm -> h16 ; agg -> x16 (bf16)
  k_gemm7<<<(NT+7)/8, 256, 0, stream>>>(x1, x2, W[0], asrc[0], adst[0], h16, hs, hd, NT);
  k_aggregate<128,true><<<(NT+3)/4, 256, 0, stream>>>(h16, hs, hd, srt, row_ptr, ce3+0, bb[0], x16, NT);
  // layer 1: MFMA gemm (x16 @ Wt1) -> h16 ; agg -> x16
  k_gemm_mfma<128><<<(NT+63)/64, 256, 0, stream>>>(x16, Wt1, asrc[1], adst[1], h16, hs, hd, NT);
  k_aggregate<128,true><<<(NT+3)/4, 256, 0, stream>>>(h16, hs, hd, srt, row_ptr, ce3+1, bb[1], x16, NT);
  // layer 2: MFMA gemm (x16 @ Wt2) -> h16[64] ; agg -> bufX (fp32)
  k_gemm_mfma<64><<<(NT+63)/64, 256, 0, stream>>>(x16, Wt2, asrc[2], adst[2], h16, hs, hd, NT);
  k_aggregate<64,false><<<(NT+3)/4, 256, 0, stream>>>(h16, hs, hd, srt, row_ptr, ce3+2, bb[2], bufX, NT);

  k_colsum2<<<512, 256, 0, stream>>>(bufX, gsum, NT);
  k_head<<<1, 128, 0, stream>>>(gsum, gsum+64, xn1, xn2, Wlin, blin, Wc1, bc1, Wc2, bc2, out);
}

// Round 12
// 457.516 us; speedup vs baseline: 3.7360x; 1.0391x over previous
//
#include <hip/hip_runtime.h>
#include <math.h>

#define NN 50000
#define NE 800000
#define NT 100000           // merged nodes (two graphs)
#define NTP 100032          // padded rows for MFMA gemm
#define ET (2*NE + NT)      // merged CSR entries incl self loops
#define NPB 128             // nodes per bucket
#define NBK 782             // ceil(NT/NPB)
#define BCH 2048            // edges per k_bin chunk
#define BCAP 2816           // k_bucket LDS edge capacity (mean 2048, +17 sigma)

typedef __attribute__((ext_vector_type(8))) short bf16x8;
typedef __attribute__((ext_vector_type(4))) float f32x4;

// ---------- helpers ----------
static __device__ __forceinline__ float wave_max64(float v){
  #pragma unroll
  for(int off=32;off;off>>=1) v = fmaxf(v, __shfl_xor(v,off));
  return v;
}
static __device__ __forceinline__ float wave_sum64(float v){
  #pragma unroll
  for(int off=32;off;off>>=1) v += __shfl_xor(v,off);
  return v;
}
static __device__ __forceinline__ unsigned short f2bf(float f){
  unsigned u = __float_as_uint(f);
  return (unsigned short)((u + 0x7FFFu + ((u>>16)&1u)) >> 16);
}
static __device__ __forceinline__ float bflo(unsigned v){ return __uint_as_float(v<<16); }
static __device__ __forceinline__ float bfhi(unsigned v){ return __uint_as_float(v & 0xFFFF0000u); }

// ---------- bucketed CSR build (bucket = dst>>7) ----------
__global__ __launch_bounds__(256) void k_hist(const int* __restrict__ d1,
    const int* __restrict__ d2, int* __restrict__ bcnt){
  __shared__ int h[1024];
  int t = threadIdx.x;
  #pragma unroll
  for (int i=0;i<4;i++) h[t + i*256] = 0;
  __syncthreads();
  int stride = gridDim.x*256;
  for (int e = blockIdx.x*256 + t; e < NE; e += stride){
    atomicAdd(&h[d1[e]>>7], 1);
    atomicAdd(&h[(d2[e]+NN)>>7], 1);
  }
  __syncthreads();
  #pragma unroll
  for (int i=0;i<4;i++){
    int idx = t + i*256;
    if (h[idx]) atomicAdd(&bcnt[idx], h[idx]);
  }
}

// exclusive scan of bcnt[1024] -> hbase; row_ptr[NT]=ET
__global__ void k_hscan(const int* __restrict__ bcnt, int* __restrict__ hbase,
                        int* __restrict__ row_ptr){
  int t = threadIdx.x;
  int i0 = t*4;
  int c0=bcnt[i0], c1=bcnt[i0+1], c2=bcnt[i0+2], c3=bcnt[i0+3];
  int ts = c0+c1+c2+c3;
  int lane = t & 63, wv = t >> 6;
  int inc = ts;
  #pragma unroll
  for (int off=1; off<64; off<<=1){ int u = __shfl_up(inc, off); if (lane>=off) inc += u; }
  __shared__ int wsum[4];
  if (lane==63) wsum[wv] = inc;
  __syncthreads();
  int woff = 0;
  #pragma unroll
  for (int w=0; w<4; ++w) if (w < wv) woff += wsum[w];
  int run = woff + inc - ts;
  hbase[i0] = run; hbase[i0+1] = run+c0; hbase[i0+2] = run+c0+c1; hbase[i0+3] = run+c0+c1+c2;
  if (t==0) row_ptr[NT] = ET;
}

// block-local counting sort of 2048-edge chunks. pack = src | (dst&127)<<17
__global__ __launch_bounds__(256) void k_bin(const int* __restrict__ s1,
    const int* __restrict__ d1, const float* __restrict__ e1,
    const int* __restrict__ s2, const int* __restrict__ d2,
    const float* __restrict__ e2, const int* __restrict__ hbase,
    int* __restrict__ gcur, uint2* __restrict__ gstage){
  __shared__ int cnt[1024], loff[1024], cur[1024], gbase_sh[1024];
  __shared__ uint2 sdata[BCH];
  __shared__ unsigned short sbkt[BCH];
  __shared__ int wsum[4];
  int tid = threadIdx.x;
  int e0 = blockIdx.x*BCH;
  unsigned pack[8], eab[8];
  unsigned short bk[8];
  #pragma unroll
  for (int i=0;i<4;i++){ cnt[tid + i*256] = 0; cur[tid + i*256] = 0; }
  __syncthreads();
  #pragma unroll
  for (int u=0; u<8; ++u){
    int e = e0 + u*256 + tid;
    int b = NBK; unsigned p = 0, ea = 0;
    if (e < 2*NE){
      int src, dst; float eav;
      if (e < NE){ src = s1[e]; dst = d1[e]; eav = e1[e]; }
      else { int e2i = e - NE; src = s2[e2i] + NN; dst = d2[e2i] + NN; eav = e2[e2i]; }
      b = dst >> 7;
      p = (unsigned)src | ((unsigned)(dst & 127) << 17);
      ea = __float_as_uint(eav);
    }
    bk[u] = (unsigned short)b; pack[u] = p; eab[u] = ea;
    atomicAdd(&cnt[b], 1);
  }
  __syncthreads();
  // exclusive scan cnt[1024] -> loff[1024], 4 per thread
  {
    int i0 = tid*4;
    int c0=cnt[i0], c1=cnt[i0+1], c2=cnt[i0+2], c3=cnt[i0+3];
    int ts = c0+c1+c2+c3;
    int lane = tid & 63, wv = tid >> 6;
    int inc = ts;
    #pragma unroll
    for (int off=1; off<64; off<<=1){ int u = __shfl_up(inc, off); if (lane>=off) inc += u; }
    if (lane==63) wsum[wv] = inc;
    __syncthreads();
    int woff = 0;
    #pragma unroll
    for (int w=0; w<4; ++w) if (w < wv) woff += wsum[w];
    int run = woff + inc - ts;
    loff[i0] = run; loff[i0+1] = run+c0; loff[i0+2] = run+c0+c1; loff[i0+3] = run+c0+c1+c2;
  }
  // reserve global staging ranges
  for (int i = tid; i < NBK; i += 256)
    if (cnt[i] > 0) gbase_sh[i] = hbase[i] + atomicAdd(&gcur[i], cnt[i]);
  __syncthreads();
  // place into LDS, bucket-sorted
  #pragma unroll
  for (int u=0; u<8; ++u){
    int b = bk[u];
    int p = loff[b] + atomicAdd(&cur[b], 1);
    sdata[p] = make_uint2(pack[u], eab[u]);
    sbkt[p] = (unsigned short)b;
  }
  __syncthreads();
  // coalesced flush
  for (int k = tid; k < BCH; k += 256){
    int b = sbkt[k];
    if (b < NBK) gstage[gbase_sh[b] + (k - loff[b])] = sdata[k];
  }
}

// one block per bucket -> final CSR (row_ptr, srt incl self loops)
__global__ __launch_bounds__(256) void k_bucket(const uint2* __restrict__ gstage,
    const int* __restrict__ hbase, int2* __restrict__ srt, int* __restrict__ row_ptr){
  __shared__ uint2 sd[BCAP];
  __shared__ int deg[NPB], rbase[NPB], cur[NPB];
  __shared__ float easum[NPB];
  __shared__ int wsum[4];
  int b = blockIdx.x, t = threadIdx.x;
  int lo = b*NPB;
  int nloc = min(NPB, NT - lo);
  int est = hbase[b], ecnt = hbase[b+1] - est;
  bool inlds = (ecnt <= BCAP);
  if (t < NPB){ deg[t] = 0; easum[t] = 0.f; }
  __syncthreads();
  for (int k = t; k < ecnt; k += 256){
    uint2 v = gstage[est + k];
    if (inlds) sd[k] = v;
    int dl = v.x >> 17;
    atomicAdd(&deg[dl], 1);
    atomicAdd(&easum[dl], __uint_as_float(v.y));
  }
  __syncthreads();
  int dv = (t < nloc) ? deg[t] + 1 : 0;
  int lane = t & 63, wv = t >> 6;
  int inc = dv;
  #pragma unroll
  for (int off=1; off<64; off<<=1){ int u = __shfl_up(inc, off); if (lane>=off) inc += u; }
  if (lane==63) wsum[wv] = inc;
  __syncthreads();
  int woff = 0;
  #pragma unroll
  for (int w=0; w<4; ++w) if (w < wv) woff += wsum[w];
  int gb = est + lo + (woff + inc - dv);
  if (t < nloc){
    row_ptr[lo + t] = gb;
    rbase[t] = gb;
    cur[t] = 1;
    float se = easum[t] / fmaxf((float)deg[t], 1.f);
    srt[gb] = make_int2(lo + t, __float_as_int(se));
  }
  __syncthreads();
  for (int k = t; k < ecnt; k += 256){
    uint2 v = inlds ? sd[k] : gstage[est + k];
    int dl = v.x >> 17;
    int pos = rbase[dl] + atomicAdd(&cur[dl], 1);
    srt[pos] = make_int2((int)(v.x & 0x1FFFFu), (int)v.y);
  }
}

// prep: zero bcnt|gcur|gsum, ce[L] dots, W1/W2 -> bf16 transposed padded Wt[N][136]
__global__ __launch_bounds__(256) void k_prep(
    const float* __restrict__ We0, const float* __restrict__ ae0,
    const float* __restrict__ We1, const float* __restrict__ ae1,
    const float* __restrict__ We2, const float* __restrict__ ae2,
    float* __restrict__ ce3, int* __restrict__ zbase,
    const float* __restrict__ W1, const float* __restrict__ W2,
    unsigned short* __restrict__ Wt1, unsigned short* __restrict__ Wt2){
  int t = threadIdx.x;
  for (int i = t; i < 1024+1024+128; i += 256) zbase[i] = 0;
  if (t < 64){
    const float* We[3] = {We0, We1, We2};
    const float* ae[3] = {ae0, ae1, ae2};
    const int fo[3] = {128, 128, 64};
    for (int L = 0; L < 3; ++L){
      float s = 0.f;
      for (int c = t; c < fo[L]; c += 64) s += We[L][c]*ae[L][c];
      s = wave_sum64(s);
      if (t == 0) ce3[L] = s;
    }
  }
  for (int i = t; i < 128*128; i += 256){
    int c = i >> 7, k = i & 127;
    Wt1[c*136 + k] = f2bf(W1[k*128 + c]);
  }
  for (int i = t; i < 64*128; i += 256){
    int c = i >> 7, k = i & 127;
    Wt2[c*136 + k] = f2bf(W2[k*64 + c]);
  }
}

// ---- MFMA GEMM: h[M,N] = x16[M,128] @ W[128,N] + fused hs/hd + bf16 h16 ----
template<int N>
__global__ __launch_bounds__(256) void k_gemm_mfma(
    const unsigned short* __restrict__ x16, const unsigned short* __restrict__ Wt,
    const float* __restrict__ a_src, const float* __restrict__ a_dst,
    unsigned short* __restrict__ h16, float* __restrict__ hs,
    float* __restrict__ hd, int n){
  constexpr int CT = N/16;
  __shared__ unsigned short Wl[N*136];
  int tid = threadIdx.x;
  for (int i = tid; i < N*136/8; i += 256)
    ((uint4*)Wl)[i] = ((const uint4*)Wt)[i];
  __syncthreads();
  int lane = tid & 63, w = tid >> 6;
  int arow = blockIdx.x*64 + w*16 + (lane & 15);
  int kb   = (lane >> 4) * 8;
  int rsafe = (arow < n) ? arow : (n-1);
  f32x4 acc[CT] = {};
  #pragma unroll
  for (int s = 0; s < 4; ++s){
    bf16x8 a = *(const bf16x8*)(x16 + (size_t)rsafe*128 + s*32 + kb);
    #pragma unroll
    for (int c = 0; c < CT; ++c){
      bf16x8 b = *(const bf16x8*)(&Wl[(c*16 + (lane&15))*136 + s*32 + kb]);
      acc[c] = __builtin_amdgcn_mfma_f32_16x16x32_bf16(a, b, acc[c], 0, 0, 0);
    }
  }
  int drow = blockIdx.x*64 + w*16 + (lane>>4)*4;
  int dcol = lane & 15;
  float psv[4] = {0,0,0,0}, pdv[4] = {0,0,0,0};
  #pragma unroll
  for (int c = 0; c < CT; ++c){
    float as = a_src[c*16 + dcol], ad = a_dst[c*16 + dcol];
    #pragma unroll
    for (int j = 0; j < 4; ++j){
      float v = acc[c][j];
      if (drow + j < n) h16[(size_t)(drow+j)*N + c*16 + dcol] = f2bf(v);
      psv[j] += v*as; pdv[j] += v*ad;
    }
  }
  #pragma unroll
  for (int off = 1; off < 16; off <<= 1){
    #pragma unroll
    for (int j=0;j<4;j++){ psv[j] += __shfl_xor(psv[j], off); pdv[j] += __shfl_xor(pdv[j], off); }
  }
  if (dcol == 0){
    #pragma unroll
    for (int j=0;j<4;j++) if (drow+j < n){ hs[drow+j] = psv[j]; hd[drow+j] = pdv[j]; }
  }
}

// layer-1 GEMM: K=7, N=128
__global__ __launch_bounds__(256) void k_gemm7(const float* __restrict__ x1,
    const float* __restrict__ x2, const float* __restrict__ W,
    const float* __restrict__ a_src, const float* __restrict__ a_dst,
    unsigned short* __restrict__ h16, float* __restrict__ hs,
    float* __restrict__ hd, int n){
  __shared__ float Wl[7][128];
  int tid = threadIdx.x;
  for (int i = tid; i < 7*128; i += 256) ((float*)Wl)[i] = W[i];
  __syncthreads();
  int tx = tid & 31, ty = tid >> 5;
  int r = blockIdx.x*8 + ty;
  if (r >= n) return;
  const float* xr = (r < NN) ? (x1 + (size_t)r*7) : (x2 + (size_t)(r-NN)*7);
  float xv[7];
  #pragma unroll
  for (int k=0;k<7;k++) xv[k] = xr[k];
  float4 s = make_float4(0.f,0.f,0.f,0.f);
  #pragma unroll
  for (int k=0;k<7;k++){
    float4 wv = *(const float4*)(&Wl[k][tx*4]);
    s.x += xv[k]*wv.x; s.y += xv[k]*wv.y; s.z += xv[k]*wv.z; s.w += xv[k]*wv.w;
  }
  unsigned r0p = (unsigned)f2bf(s.x) | ((unsigned)f2bf(s.y)<<16);
  unsigned r1p = (unsigned)f2bf(s.z) | ((unsigned)f2bf(s.w)<<16);
  *(uint2*)(h16 + (size_t)r*128 + tx*4) = make_uint2(r0p, r1p);
  float ps = s.x*a_src[tx*4] + s.y*a_src[tx*4+1] + s.z*a_src[tx*4+2] + s.w*a_src[tx*4+3];
  float pd = s.x*a_dst[tx*4] + s.y*a_dst[tx*4+1] + s.z*a_dst[tx*4+2] + s.w*a_dst[tx*4+3];
  #pragma unroll
  for (int off=16; off; off>>=1){ ps += __shfl_xor(ps, off); pd += __shfl_xor(pd, off); }
  if (tx==0){ hs[r] = ps; hd[r] = pd; }
}

// Per-node fused: alpha -> online softmax -> wide bf16 gather (2-deep) -> +b -> ELU
template<int FOUT, bool OBF>
__global__ __launch_bounds__(256) void k_aggregate(const unsigned short* __restrict__ h16,
    const float* __restrict__ hs, const float* __restrict__ hd,
    const int2* __restrict__ srt, const int* __restrict__ row_ptr,
    const float* __restrict__ ce_p, const float* __restrict__ b,
    void* __restrict__ xout, int n){
  constexpr int LPE = FOUT/8;        // lanes per edge (16 or 8)
  constexpr int EPS = 64/LPE;        // edges per step  (4 or 8)
  __shared__ float s_p[4][64];
  __shared__ int   s_s[4][64];
  int tid = threadIdx.x;
  int wv = tid >> 6, lane = tid & 63;
  int wid = (int)((blockIdx.x*256 + tid) >> 6);
  if (wid >= n) return;
  float ce  = *ce_p;
  int beg = row_ptr[wid], end = row_ptr[wid+1];
  float hdn = hd[wid];
  int e_sub = lane / LPE;
  int col8  = (lane % LPE) * 8;
  float m = -INFINITY, den = 0.f;
  float acc[8] = {0.f,0.f,0.f,0.f,0.f,0.f,0.f,0.f};
  for (int base = beg; base < end; base += 64){
    int slot = base + lane;
    float a = -INFINITY; int src = 0;
    if (slot < end){
      int2 pk = srt[slot];
      src = pk.x;
      a = hs[src] + hdn + __int_as_float(pk.y)*ce;
      a = (a > 0.f) ? a : 0.2f*a;
    }
    float cm = wave_max64(a);
    float mnew = fmaxf(m, cm);
    float scale = __expf(m - mnew);
    den *= scale;
    #pragma unroll
    for (int u=0;u<8;u++) acc[u] *= scale;
    float p = __expf(a - mnew);
    den += wave_sum64(p);
    s_p[wv][lane] = p; s_s[wv][lane] = src;
    asm volatile("s_waitcnt lgkmcnt(0)" ::: "memory");
    int cnt = end - base; if (cnt > 64) cnt = 64;
    // p==0 beyond cnt -> rounding up is safe; 2 loads in flight per iter
    for (int j = 0; j < cnt; j += 2*EPS){
      int jj0 = j + e_sub, jj1 = j + EPS + e_sub;
      float p0 = s_p[wv][jj0];  int sj0 = s_s[wv][jj0];
      float p1 = s_p[wv][jj1];  int sj1 = s_s[wv][jj1];
      uint4 h0 = *(const uint4*)(h16 + (size_t)sj0*FOUT + col8);
      uint4 h1 = *(const uint4*)(h16 + (size_t)sj1*FOUT + col8);
      acc[0] += p0*bflo(h0.x); acc[1] += p0*bfhi(h0.x);
      acc[2] += p0*bflo(h0.y); acc[3] += p0*bfhi(h0.y);
      acc[4] += p0*bflo(h0.z); acc[5] += p0*bfhi(h0.z);
      acc[6] += p0*bflo(h0.w); acc[7] += p0*bfhi(h0.w);
      acc[0] += p1*bflo(h1.x); acc[1] += p1*bfhi(h1.x);
      acc[2] += p1*bflo(h1.y); acc[3] += p1*bfhi(h1.y);
      acc[4] += p1*bflo(h1.z); acc[5] += p1*bfhi(h1.z);
      acc[6] += p1*bflo(h1.w); acc[7] += p1*bfhi(h1.w);
    }
    m = mnew;
  }
  #pragma unroll
  for (int off = LPE; off < 64; off <<= 1){
    #pragma unroll
    for (int u=0;u<8;u++) acc[u] += __shfl_xor(acc[u], off);
  }
  float inv = 1.f/den;
  if (lane < LPE){
    float o[8];
    #pragma unroll
    for (int u=0;u<8;u++){
      o[u] = acc[u]*inv + b[col8+u];
      o[u] = (o[u] > 0.f) ? o[u] : (__expf(o[u]) - 1.f);
    }
    if (OBF){
      uint4 pkd;
      pkd.x = (unsigned)f2bf(o[0]) | ((unsigned)f2bf(o[1])<<16);
      pkd.y = (unsigned)f2bf(o[2]) | ((unsigned)f2bf(o[3])<<16);
      pkd.z = (unsigned)f2bf(o[4]) | ((unsigned)f2bf(o[5])<<16);
      pkd.w = (unsigned)f2bf(o[6]) | ((unsigned)f2bf(o[7])<<16);
      *(uint4*)((unsigned short*)xout + (size_t)wid*FOUT + col8) = pkd;
    } else {
      float4 o0 = make_float4(o[0],o[1],o[2],o[3]);
      float4 o1 = make_float4(o[4],o[5],o[6],o[7]);
      *(float4*)((float*)xout + (size_t)wid*FOUT + col8)     = o0;
      *(float4*)((float*)xout + (size_t)wid*FOUT + col8 + 4) = o1;
    }
  }
}

// column sums over merged x[n,64] fp32
__global__ __launch_bounds__(256) void k_colsum2(const float* __restrict__ x,
    float* __restrict__ gsum, int n){
  __shared__ float ls[128];
  int t = threadIdx.x;
  if (t < 128) ls[t] = 0.f;
  __syncthreads();
  int c4 = (t & 15) * 4;
  int rsub = t >> 4;
  float4 s1 = make_float4(0.f,0.f,0.f,0.f), s2 = make_float4(0.f,0.f,0.f,0.f);
  for (int r = blockIdx.x*16 + rsub; r < n; r += gridDim.x*16){
    float4 v = *(const float4*)(x + (size_t)r*64 + c4);
    if (r < NN){ s1.x+=v.x; s1.y+=v.y; s1.z+=v.z; s1.w+=v.w; }
    else       { s2.x+=v.x; s2.y+=v.y; s2.z+=v.z; s2.w+=v.w; }
  }
  atomicAdd(&ls[c4+0], s1.x); atomicAdd(&ls[c4+1], s1.y);
  atomicAdd(&ls[c4+2], s1.z); atomicAdd(&ls[c4+3], s1.w);
  atomicAdd(&ls[64+c4+0], s2.x); atomicAdd(&ls[64+c4+1], s2.y);
  atomicAdd(&ls[64+c4+2], s2.z); atomicAdd(&ls[64+c4+3], s2.w);
  __syncthreads();
  if (t < 128) atomicAdd(&gsum[t], ls[t]);
}

// final MLP head
__global__ void k_head(const float* __restrict__ gs1, const float* __restrict__ gs2,
                       const float* __restrict__ xn1, const float* __restrict__ xn2,
                       const float* __restrict__ Wlin, const float* __restrict__ blin,
                       const float* __restrict__ Wc1, const float* __restrict__ bc1,
                       const float* __restrict__ Wc2, const float* __restrict__ bc2,
                       float* __restrict__ out){
  __shared__ float c1[80], c2[80], xcat[128], hb[16];
  int tid = threadIdx.x;
  const float invn = 1.f/(float)NN;
  if (tid < 64){ c1[tid] = gs1[tid]*invn; c2[tid] = gs2[tid]*invn; }
  else if (tid < 80){ c1[tid] = xn1[tid-64]; c2[tid] = xn2[tid-64]; }
  __syncthreads();
  if (tid < 64){
    float s = blin[tid];
    for (int k=0;k<80;k++) s += c1[k]*Wlin[k*64+tid];
    xcat[tid] = s;
  } else {
    int j = tid - 64;
    float s = blin[j];
    for (int k=0;k<80;k++) s += c2[k]*Wlin[k*64+j];
    xcat[tid] = s;
  }
  __syncthreads();
  if (tid < 16){
    float s = bc1[tid];
    for (int k=0;k<128;k++) s += xcat[k]*Wc1[k*16+tid];
    hb[tid] = fmaxf(s, 0.f);
  }
  __syncthreads();
  if (tid < 3){
    float s = bc2[tid];
    for (int k=0;k<16;k++) s += hb[k]*Wc2[k*3+tid];
    out[tid] = s;
  }
}

extern "C" void kernel_launch(void* const* d_in, const int* in_sizes, int n_in,
                              void* d_out, int out_size, void* d_ws, size_t ws_size,
                              hipStream_t stream){
  const float* x1  = (const float*)d_in[0];
  const float* x2  = (const float*)d_in[1];
  const int*   ei1 = (const int*)d_in[2];
  const int*   ei2 = (const int*)d_in[3];
  const float* xn1 = (const float*)d_in[4];
  const float* xn2 = (const float*)d_in[5];
  const float* ec1 = (const float*)d_in[6];
  const float* ec2 = (const float*)d_in[7];
  const float* W[3]    = {(const float*)d_in[8],  (const float*)d_in[14], (const float*)d_in[20]};
  const float* asrc[3] = {(const float*)d_in[9],  (const float*)d_in[15], (const float*)d_in[21]};
  const float* adst[3] = {(const float*)d_in[10], (const float*)d_in[16], (const float*)d_in[22]};
  const float* We[3]   = {(const float*)d_in[11], (const float*)d_in[17], (const float*)d_in[23]};
  const float* ae[3]   = {(const float*)d_in[12], (const float*)d_in[18], (const float*)d_in[24]};
  const float* bb[3]   = {(const float*)d_in[13], (const float*)d_in[19], (const float*)d_in[25]};
  const float* Wlin = (const float*)d_in[26];
  const float* blin = (const float*)d_in[27];
  const float* Wc1  = (const float*)d_in[28];
  const float* bc1  = (const float*)d_in[29];
  const float* Wc2  = (const float*)d_in[30];
  const float* bc2  = (const float*)d_in[31];
  float* out = (float*)d_out;

  char* wsb = (char*)d_ws;
  unsigned short* x16   = (unsigned short*)wsb;                  // 25.6 MB (aliased below)
  uint2*          gstage = (uint2*)wsb;                          // alias (CSR build)
  float*          bufX  = (float*)wsb;                           // alias (layer2 out)
  unsigned short* h16  = (unsigned short*)(wsb + (size_t)NTP*128*2);
  int2*           srt  = (int2*)(wsb + (size_t)NTP*128*2 + (size_t)NT*128*2);
  float* hs   = (float*)(srt + ET);               // NT
  float* hd   = hs + NT;                          // NT
  int*   row_ptr = (int*)(hd + NT);               // NT+2
  int*   bcnt  = row_ptr + NT + 2;                // 1024 (zeroed in prep)
  int*   gcur  = bcnt + 1024;                     // 1024 (zeroed in prep)
  float* gsum  = (float*)(gcur + 1024);           // 128 (zeroed in prep)
  int*   hbase = (int*)(gsum + 128);              // 1024
  float* ce3   = (float*)(hbase + 1024);          // 4 (+pad)
  unsigned short* Wt1 = (unsigned short*)(ce3 + 8);   // 128*136
  unsigned short* Wt2 = Wt1 + 128*136;                // 64*136

  const int* s1 = ei1, * d1 = ei1 + NE;
  const int* s2 = ei2, * d2 = ei2 + NE;

  k_prep<<<1, 256, 0, stream>>>(We[0], ae[0], We[1], ae[1], We[2], ae[2], ce3,
                                bcnt, W[1], W[2], Wt1, Wt2);

  // bucketed CSR build
  k_hist<<<256, 256, 0, stream>>>(d1, d2, bcnt);
  k_hscan<<<1, 256, 0, stream>>>(bcnt, hbase, row_ptr);
  k_bin<<<(2*NE + BCH - 1)/BCH, 256, 0, stream>>>(s1, d1, ec1, s2, d2, ec2, hbase, gcur, gstage);
  k_bucket<<<NBK, 256, 0, stream>>>(gstage, hbase, srt, row_ptr);

  // layer 0
  k_gemm7<<<(NT+7)/8, 256, 0, stream>>>(x1, x2, W[0], asrc[0], adst[0], h16, hs, hd, NT);
  k_aggregate<128,true><<<(NT+3)/4, 256, 0, stream>>>(h16, hs, hd, srt, row_ptr, ce3+0, bb[0], x16, NT);
  // layer 1
  k_gemm_mfma<128><<<(NT+63)/64, 256, 0, stream>>>(x16, Wt1, asrc[1], adst[1], h16, hs, hd, NT);
  k_aggregate<128,true><<<(NT+3)/4, 256, 0, stream>>>(h16, hs, hd, srt, row_ptr, ce3+1, bb[1], x16, NT);
  // layer 2
  k_gemm_mfma<64><<<(NT+63)/64, 256, 0, stream>>>(x16, Wt2, asrc[2], adst[2], h16, hs, hd, NT);
  k_aggregate<64,false><<<(NT+3)/4, 256, 0, stream>>>(h16, hs, hd, srt, row_ptr, ce3+2, bb[2], bufX, NT);

  k_colsum2<<<512, 256, 0, stream>>>(bufX, gsum, NT);
  k_head<<<1, 128, 0, stream>>>(gsum, gsum+64, xn1, xn2, Wlin, blin, Wc1, bc1, Wc2, bc2, out);
}